// Round 1
// baseline (72746.423 us; speedup 1.0000x reference)
//
#include <hip/hip_runtime.h>
#include <cstdint>

#define SEQ     100
#define BATCH   2048
#define IN_DIM  64
#define MID_I   60
#define LATENT  20
#define V_MID   800
#define V_LAT   50
#define MID_O   800
#define OUT_DIM 512

constexpr int BM = 64, BN = 64, BK = 16;

// C[M,N] = A1[M,K1] @ W1[N,K1]^T + A2[M,K2] @ W2[N,K2]^T + b1 + b2
// Optional ReLU on A1 reads (for fc21 consuming relu(h1)) and on output.
template<bool RELU_A1, bool RELU_OUT>
__global__ __launch_bounds__(256)
void gemm2k(const float* __restrict__ A1, int K1,
            const float* __restrict__ A2, int K2,
            const float* __restrict__ W1, const float* __restrict__ W2,
            const float* __restrict__ b1, const float* __restrict__ b2,
            float* __restrict__ C, int M, int N)
{
    __shared__ float As[BK][BM + 1];
    __shared__ float Bs[BK][BN + 1];
    const int tx = threadIdx.x & 15;   // n-direction
    const int ty = threadIdx.x >> 4;   // m-direction
    const int n0 = blockIdx.x * BN;
    const int m0 = blockIdx.y * BM;

    float acc[4][4] = {};

    for (int src = 0; src < 2; ++src) {
        const float* A = src ? A2 : A1;
        const float* W = src ? W2 : W1;
        const int    K = src ? K2 : K1;
        if (A == nullptr || K == 0) continue;
        for (int k0 = 0; k0 < K; k0 += BK) {
            #pragma unroll
            for (int i = 0; i < 4; ++i) {
                int idx = threadIdx.x + i * 256;
                int k = idx & 15, m = idx >> 4;
                int gm = m0 + m, gk = k0 + k;
                float v = 0.f;
                if (gm < M && gk < K) v = A[(size_t)gm * K + gk];
                if (RELU_A1 && src == 0) v = fmaxf(v, 0.f);
                As[k][m] = v;
            }
            #pragma unroll
            for (int i = 0; i < 4; ++i) {
                int idx = threadIdx.x + i * 256;
                int k = idx & 15, n = idx >> 4;
                int gn = n0 + n, gk = k0 + k;
                float v = 0.f;
                if (gn < N && gk < K) v = W[(size_t)gn * K + gk];
                Bs[k][n] = v;
            }
            __syncthreads();
            #pragma unroll
            for (int kk = 0; kk < BK; ++kk) {
                float a[4], b[4];
                #pragma unroll
                for (int i = 0; i < 4; ++i) a[i] = As[kk][ty + i * 16];
                #pragma unroll
                for (int j = 0; j < 4; ++j) b[j] = Bs[kk][tx + j * 16];
                #pragma unroll
                for (int i = 0; i < 4; ++i)
                    #pragma unroll
                    for (int j = 0; j < 4; ++j)
                        acc[i][j] += a[i] * b[j];
            }
            __syncthreads();
        }
    }

    #pragma unroll
    for (int i = 0; i < 4; ++i) {
        int gm = m0 + ty + i * 16;
        if (gm >= M) continue;
        #pragma unroll
        for (int j = 0; j < 4; ++j) {
            int gn = n0 + tx + j * 16;
            if (gn >= N) continue;
            float v = acc[i][j];
            if (b1) v += b1[gn];
            if (b2) v += b2[gn];
            if (RELU_OUT) v = fmaxf(v, 0.f);
            C[(size_t)gm * N + gn] = v;
        }
    }
}

// gates layout: [B][4H] in PyTorch order i,f,g,o. In-place h/c update.
__global__ void lstm_pw(const float* __restrict__ gates,
                        float* __restrict__ h, float* __restrict__ c,
                        int H, float* __restrict__ out_copy)
{
    int idx = blockIdx.x * blockDim.x + threadIdx.x;
    if (idx >= BATCH * H) return;
    int b = idx / H;
    int j = idx - b * H;
    const float* g = gates + (size_t)b * 4 * H;
    float gi = g[j];
    float gf = g[H + j];
    float gg = g[2 * H + j];
    float go = g[3 * H + j];
    float si = 1.f / (1.f + expf(-gi));
    float sf = 1.f / (1.f + expf(-gf));
    float so = 1.f / (1.f + expf(-go));
    float cn = sf * c[idx] + si * tanhf(gg);
    float hn = so * tanhf(cn);
    c[idx] = cn;
    h[idx] = hn;
    if (out_copy) out_copy[idx] = hn;
}

// flat[b][l*SEQ + s] = out21[s][b][l]
__global__ void build_flat(const float* __restrict__ out21, float* __restrict__ flat)
{
    int idx = blockIdx.x * blockDim.x + threadIdx.x;
    if (idx >= SEQ * BATCH * LATENT) return;
    int l = idx % LATENT;
    int b = (idx / LATENT) % BATCH;
    int s = idx / (LATENT * BATCH);
    flat[(size_t)b * (LATENT * SEQ) + l * SEQ + s] = out21[idx];
}

extern "C" void kernel_launch(void* const* d_in, const int* in_sizes, int n_in,
                              void* d_out_v, int out_size, void* d_ws, size_t ws_size,
                              hipStream_t stream)
{
    const float* x        = (const float*)d_in[0];
    const float* fc1_wih  = (const float*)d_in[1];
    const float* fc1_whh  = (const float*)d_in[2];
    const float* fc1_bih  = (const float*)d_in[3];
    const float* fc1_bhh  = (const float*)d_in[4];
    const float* fc21_wih = (const float*)d_in[5];
    const float* fc21_whh = (const float*)d_in[6];
    const float* fc21_bih = (const float*)d_in[7];
    const float* fc21_bhh = (const float*)d_in[8];
    const float* lin1_w   = (const float*)d_in[9];
    const float* lin1_b   = (const float*)d_in[10];
    const float* lin2_w   = (const float*)d_in[11];
    const float* lin2_b   = (const float*)d_in[12];
    const float* idlin_w  = (const float*)d_in[13];
    const float* idlin_b  = (const float*)d_in[14];
    const float* down1_w  = (const float*)d_in[15];
    const float* down1_b  = (const float*)d_in[16];
    const float* down2_w  = (const float*)d_in[17];
    const float* down2_b  = (const float*)d_in[18];
    const float* l3_wih   = (const float*)d_in[19];
    const float* l3_whh   = (const float*)d_in[20];
    const float* l3_bih   = (const float*)d_in[21];
    const float* l3_bhh   = (const float*)d_in[22];
    const float* l4_wih   = (const float*)d_in[23];
    const float* l4_whh   = (const float*)d_in[24];
    const float* l4_bih   = (const float*)d_in[25];
    const float* l4_bhh   = (const float*)d_in[26];
    const float* l5_wih   = (const float*)d_in[27];
    const float* l5_whh   = (const float*)d_in[28];
    const float* l5_bih   = (const float*)d_in[29];
    const float* l5_bhh   = (const float*)d_in[30];
    float* out = (float*)d_out_v;

    float* ws = (float*)d_ws;
    size_t off = 0;
    auto alloc = [&](size_t n) { float* p = ws + off; off += n; return p; };

    float* gates  = alloc((size_t)BATCH * 4 * MID_O);   // max gate width = 3200 (l4)
    float* h_fc1  = alloc((size_t)BATCH * MID_I);
    float* c_fc1  = alloc((size_t)BATCH * MID_I);
    float* h_fc21 = alloc((size_t)BATCH * LATENT);
    float* c_fc21 = alloc((size_t)BATCH * LATENT);
    float* out21  = alloc((size_t)SEQ * BATCH * LATENT);
    float* flat   = alloc((size_t)BATCH * LATENT * SEQ);
    float* mu1    = alloc((size_t)BATCH * V_MID);
    float* mu     = alloc((size_t)BATCH * V_LAT);
    float* h_t    = alloc((size_t)BATCH * V_LAT);
    float* c_t    = alloc((size_t)BATCH * V_LAT);
    float* h2     = alloc((size_t)BATCH * MID_O);
    float* c2     = alloc((size_t)BATCH * MID_O);
    float* h3     = alloc((size_t)BATCH * OUT_DIM);
    float* c3     = alloc((size_t)BATCH * OUT_DIM);
    float* outb   = alloc((size_t)BATCH * LATENT);

    // zero encoder states (h_fc1..c_fc21 contiguous) and decoder l4/l5 states
    hipMemsetAsync(h_fc1, 0, (size_t)BATCH * (2 * MID_I + 2 * LATENT) * sizeof(float), stream);
    hipMemsetAsync(h2,    0, (size_t)BATCH * (2 * MID_O + 2 * OUT_DIM) * sizeof(float), stream);

    auto launch_gemm = [&](const float* A1, int K1, const float* A2, int K2,
                           const float* W1, const float* W2,
                           const float* b1, const float* b2,
                           float* C, int N, int mode /*0 plain, 1 reluA1, 2 reluOut*/) {
        dim3 grid((N + BN - 1) / BN, BATCH / BM), blk(256);
        if (mode == 1)
            gemm2k<true, false><<<grid, blk, 0, stream>>>(A1, K1, A2, K2, W1, W2, b1, b2, C, BATCH, N);
        else if (mode == 2)
            gemm2k<false, true><<<grid, blk, 0, stream>>>(A1, K1, A2, K2, W1, W2, b1, b2, C, BATCH, N);
        else
            gemm2k<false, false><<<grid, blk, 0, stream>>>(A1, K1, A2, K2, W1, W2, b1, b2, C, BATCH, N);
    };

    // ---------------- encoder ----------------
    for (int t = 0; t < SEQ; ++t) {
        launch_gemm(x + (size_t)t * BATCH * IN_DIM, IN_DIM, h_fc1, MID_I,
                    fc1_wih, fc1_whh, fc1_bih, fc1_bhh, gates, 4 * MID_I, 0);
        lstm_pw<<<(BATCH * MID_I + 255) / 256, 256, 0, stream>>>(gates, h_fc1, c_fc1, MID_I, nullptr);
        // fc21 consumes relu(h1)
        launch_gemm(h_fc1, MID_I, h_fc21, LATENT,
                    fc21_wih, fc21_whh, fc21_bih, fc21_bhh, gates, 4 * LATENT, 1);
        lstm_pw<<<(BATCH * LATENT + 255) / 256, 256, 0, stream>>>(
            gates, h_fc21, c_fc21, LATENT, out21 + (size_t)t * BATCH * LATENT);
    }

    build_flat<<<(SEQ * BATCH * LATENT + 255) / 256, 256, 0, stream>>>(out21, flat);
    launch_gemm(flat, LATENT * SEQ, nullptr, 0, lin1_w, nullptr, lin1_b, nullptr, mu1, V_MID, 2);
    launch_gemm(mu1, V_MID, nullptr, 0, lin2_w, nullptr, lin2_b, nullptr, mu, V_LAT, 2);

    // ---------------- decoder init ----------------
    hipMemcpyAsync(h_t, mu, (size_t)BATCH * V_LAT * sizeof(float),
                   hipMemcpyDeviceToDevice, stream);
    launch_gemm(mu, V_LAT, nullptr, 0, idlin_w, nullptr, idlin_b, nullptr, c_t, V_LAT, 0);
    launch_gemm(mu, V_LAT, nullptr, 0, down1_w, nullptr, down1_b, nullptr, outb, LATENT, 0);

    // ---------------- decoder scan ----------------
    for (int t = 0; t < SEQ; ++t) {
        launch_gemm(outb, LATENT, h_t, V_LAT,
                    l3_wih, l3_whh, l3_bih, l3_bhh, gates, 4 * V_LAT, 0);
        lstm_pw<<<(BATCH * V_LAT + 255) / 256, 256, 0, stream>>>(gates, h_t, c_t, V_LAT, nullptr);

        launch_gemm(h_t, V_LAT, h2, MID_O,
                    l4_wih, l4_whh, l4_bih, l4_bhh, gates, 4 * MID_O, 0);
        lstm_pw<<<(BATCH * MID_O + 255) / 256, 256, 0, stream>>>(gates, h2, c2, MID_O, nullptr);

        launch_gemm(h2, MID_O, h3, OUT_DIM,
                    l5_wih, l5_whh, l5_bih, l5_bhh, gates, 4 * OUT_DIM, 0);
        lstm_pw<<<(BATCH * OUT_DIM + 255) / 256, 256, 0, stream>>>(
            gates, h3, c3, OUT_DIM, out + (size_t)t * BATCH * OUT_DIM);

        launch_gemm(h3, OUT_DIM, nullptr, 0, down2_w, nullptr, down2_b, nullptr, outb, LATENT, 0);
    }

    hipMemcpyAsync(out + (size_t)SEQ * BATCH * OUT_DIM, mu,
                   (size_t)BATCH * V_LAT * sizeof(float),
                   hipMemcpyDeviceToDevice, stream);
}

// Round 2
// 16789.980 us; speedup vs baseline: 4.3327x; 4.3327x over previous
//
#include <hip/hip_runtime.h>
#include <cstdint>
#include <cstddef>

#define SEQ     100
#define BATCH   2048
#define IN_DIM  64
#define MID_I   60
#define LATENT  20
#define V_MID   800
#define V_LAT   50
#define MID_O   800
#define OUT_DIM 512

#define KP4  896    // [h_t pad to 64 | h2 pad to 832]
#define KP5  1344   // [h2 pad to 832 | h3 512]
#define KPL1 2048   // latent*seq 2000 padded

using f32x4  = __attribute__((ext_vector_type(4))) float;
using u16x8  = __attribute__((ext_vector_type(8))) unsigned short;
using bf16x8 = __attribute__((ext_vector_type(8))) __bf16;

__device__ __forceinline__ unsigned short f2bf(float x){
    unsigned u = __builtin_bit_cast(unsigned, x);
    u += 0x7FFFu + ((u >> 16) & 1u);
    return (unsigned short)(u >> 16);
}
__device__ __forceinline__ float bf2f(unsigned short b){
    unsigned u = ((unsigned)b) << 16; return __builtin_bit_cast(float, u);
}
__device__ __forceinline__ float sigm(float x){ return 1.f/(1.f+expf(-x)); }

// ---------------------------------------------------------------------------
// fp32 tiled GEMM (for small/skinny ops): C = A1@W1^T + A2@W2^T + b1 + b2
// ---------------------------------------------------------------------------
constexpr int BM = 64, BN = 64, BK = 16;
template<bool RELU_A1, bool RELU_OUT>
__global__ __launch_bounds__(256)
void gemm2k(const float* __restrict__ A1, int K1,
            const float* __restrict__ A2, int K2,
            const float* __restrict__ W1, const float* __restrict__ W2,
            const float* __restrict__ b1, const float* __restrict__ b2,
            float* __restrict__ C, int M, int N)
{
    __shared__ float As[BK][BM + 1];
    __shared__ float Bs[BK][BN + 1];
    const int tx = threadIdx.x & 15;
    const int ty = threadIdx.x >> 4;
    const int n0 = blockIdx.x * BN;
    const int m0 = blockIdx.y * BM;

    float acc[4][4] = {};

    for (int src = 0; src < 2; ++src) {
        const float* A = src ? A2 : A1;
        const float* W = src ? W2 : W1;
        const int    K = src ? K2 : K1;
        if (A == nullptr || K == 0) continue;
        for (int k0 = 0; k0 < K; k0 += BK) {
            #pragma unroll
            for (int i = 0; i < 4; ++i) {
                int idx = threadIdx.x + i * 256;
                int k = idx & 15, m = idx >> 4;
                int gm = m0 + m, gk = k0 + k;
                float v = 0.f;
                if (gm < M && gk < K) v = A[(size_t)gm * K + gk];
                if (RELU_A1 && src == 0) v = fmaxf(v, 0.f);
                As[k][m] = v;
            }
            #pragma unroll
            for (int i = 0; i < 4; ++i) {
                int idx = threadIdx.x + i * 256;
                int k = idx & 15, n = idx >> 4;
                int gn = n0 + n, gk = k0 + k;
                float v = 0.f;
                if (gn < N && gk < K) v = W[(size_t)gn * K + gk];
                Bs[k][n] = v;
            }
            __syncthreads();
            #pragma unroll
            for (int kk = 0; kk < BK; ++kk) {
                float a[4], b[4];
                #pragma unroll
                for (int i = 0; i < 4; ++i) a[i] = As[kk][ty + i * 16];
                #pragma unroll
                for (int j = 0; j < 4; ++j) b[j] = Bs[kk][tx + j * 16];
                #pragma unroll
                for (int i = 0; i < 4; ++i)
                    #pragma unroll
                    for (int j = 0; j < 4; ++j)
                        acc[i][j] += a[i] * b[j];
            }
            __syncthreads();
        }
    }

    #pragma unroll
    for (int i = 0; i < 4; ++i) {
        int gm = m0 + ty + i * 16;
        if (gm >= M) continue;
        #pragma unroll
        for (int j = 0; j < 4; ++j) {
            int gn = n0 + tx + j * 16;
            if (gn >= N) continue;
            float v = acc[i][j];
            if (b1) v += b1[gn];
            if (b2) v += b2[gn];
            if (RELU_OUT) v = fmaxf(v, 0.f);
            C[(size_t)gm * N + gn] = v;
        }
    }
}

// ---------------------------------------------------------------------------
// split-bf16 MFMA GEMM: C[m][n] = sum_k A[m][k]*B[n][k] + b1[n] + b2[n]
// 3-term: Ah*Bh + Ah*Bl + Al*Bh (fp32 accumulate) -> ~fp32 precision.
// M multiple of 128, Kp multiple of 32; N arbitrary (guarded).
// ---------------------------------------------------------------------------
constexpr int GBM = 128, GBN = 128, GBK = 32, LDSP = 40; // 40-elem padded rows

template<bool RELU_OUT>
__global__ __launch_bounds__(256)
void gemm_mfma3(const unsigned short* __restrict__ Ah, const unsigned short* __restrict__ Al,
                const unsigned short* __restrict__ Bh, const unsigned short* __restrict__ Bl,
                const float* __restrict__ b1, const float* __restrict__ b2,
                float* __restrict__ C, int N, int Kp)
{
    __shared__ __align__(16) unsigned short sAh[GBM][LDSP];
    __shared__ __align__(16) unsigned short sAl[GBM][LDSP];
    __shared__ __align__(16) unsigned short sBh[GBN][LDSP];
    __shared__ __align__(16) unsigned short sBl[GBN][LDSP];

    const int tid  = threadIdx.x;
    const int m0   = blockIdx.y * GBM;
    const int n0   = blockIdx.x * GBN;
    const int lane = tid & 63;
    const int wid  = tid >> 6;
    const int wr   = (wid >> 1) * 64;
    const int wc   = (wid & 1) * 64;
    const int fr   = lane & 15;
    const int fg   = lane >> 4;

    const int r1 = tid >> 2;           // 0..63
    const int r2 = r1 + 64;            // 64..127
    const int k8 = (tid & 3) << 3;     // 0,8,16,24

    f32x4 acc[4][4];
    #pragma unroll
    for (int i = 0; i < 4; ++i)
        #pragma unroll
        for (int j = 0; j < 4; ++j) acc[i][j] = (f32x4){0.f, 0.f, 0.f, 0.f};

    const u16x8 vz = {0,0,0,0,0,0,0,0};

    for (int k0 = 0; k0 < Kp; k0 += GBK) {
        const size_t a1 = (size_t)(m0 + r1) * Kp + k0 + k8;
        const size_t a2 = (size_t)(m0 + r2) * Kp + k0 + k8;
        u16x8 va1 = *reinterpret_cast<const u16x8*>(Ah + a1);
        u16x8 va2 = *reinterpret_cast<const u16x8*>(Ah + a2);
        u16x8 wa1 = *reinterpret_cast<const u16x8*>(Al + a1);
        u16x8 wa2 = *reinterpret_cast<const u16x8*>(Al + a2);
        const int gn1 = n0 + r1, gn2 = n0 + r2;
        const size_t bo1 = (size_t)gn1 * Kp + k0 + k8;
        const size_t bo2 = (size_t)gn2 * Kp + k0 + k8;
        u16x8 vb1 = vz, vb2 = vz, wb1 = vz, wb2 = vz;
        if (gn1 < N) { vb1 = *reinterpret_cast<const u16x8*>(Bh + bo1);
                       wb1 = *reinterpret_cast<const u16x8*>(Bl + bo1); }
        if (gn2 < N) { vb2 = *reinterpret_cast<const u16x8*>(Bh + bo2);
                       wb2 = *reinterpret_cast<const u16x8*>(Bl + bo2); }

        __syncthreads();   // previous iteration's fragment reads complete
        *reinterpret_cast<u16x8*>(&sAh[r1][k8]) = va1;
        *reinterpret_cast<u16x8*>(&sAh[r2][k8]) = va2;
        *reinterpret_cast<u16x8*>(&sAl[r1][k8]) = wa1;
        *reinterpret_cast<u16x8*>(&sAl[r2][k8]) = wa2;
        *reinterpret_cast<u16x8*>(&sBh[r1][k8]) = vb1;
        *reinterpret_cast<u16x8*>(&sBh[r2][k8]) = vb2;
        *reinterpret_cast<u16x8*>(&sBl[r1][k8]) = wb1;
        *reinterpret_cast<u16x8*>(&sBl[r2][k8]) = wb2;
        __syncthreads();

        bf16x8 ah[4], al[4];
        #pragma unroll
        for (int i = 0; i < 4; ++i) {
            ah[i] = __builtin_bit_cast(bf16x8,
                *reinterpret_cast<const u16x8*>(&sAh[wr + i*16 + fr][fg*8]));
            al[i] = __builtin_bit_cast(bf16x8,
                *reinterpret_cast<const u16x8*>(&sAl[wr + i*16 + fr][fg*8]));
        }
        #pragma unroll
        for (int j = 0; j < 4; ++j) {
            bf16x8 bh = __builtin_bit_cast(bf16x8,
                *reinterpret_cast<const u16x8*>(&sBh[wc + j*16 + fr][fg*8]));
            bf16x8 bl = __builtin_bit_cast(bf16x8,
                *reinterpret_cast<const u16x8*>(&sBl[wc + j*16 + fr][fg*8]));
            #pragma unroll
            for (int i = 0; i < 4; ++i) {
                acc[i][j] = __builtin_amdgcn_mfma_f32_16x16x32_bf16(ah[i], bh, acc[i][j], 0, 0, 0);
                acc[i][j] = __builtin_amdgcn_mfma_f32_16x16x32_bf16(ah[i], bl, acc[i][j], 0, 0, 0);
                acc[i][j] = __builtin_amdgcn_mfma_f32_16x16x32_bf16(al[i], bh, acc[i][j], 0, 0, 0);
            }
        }
    }

    #pragma unroll
    for (int i = 0; i < 4; ++i) {
        #pragma unroll
        for (int j = 0; j < 4; ++j) {
            int gc = n0 + wc + j*16 + fr;
            if (gc >= N) continue;
            float badd = (b1 ? b1[gc] : 0.f) + (b2 ? b2[gc] : 0.f);
            #pragma unroll
            for (int r = 0; r < 4; ++r) {
                int gr = m0 + wr + i*16 + fg*4 + r;
                float v = acc[i][j][r] + badd;
                if (RELU_OUT) v = fmaxf(v, 0.f);
                C[(size_t)gr * N + gc] = v;
            }
        }
    }
}

// ---------------------------------------------------------------------------
// weight split/pack kernels
// ---------------------------------------------------------------------------
__global__ void split_pack(const float* __restrict__ src, int total, int K, int Kp, int coff,
                           unsigned short* __restrict__ dh, unsigned short* __restrict__ dl)
{
    int idx = blockIdx.x * blockDim.x + threadIdx.x;
    if (idx >= total) return;
    int n = idx / K, k = idx - n * K;
    float x = src[idx];
    unsigned short h = f2bf(x);
    size_t d = (size_t)n * Kp + coff + k;
    dh[d] = h;
    dl[d] = f2bf(x - bf2f(h));
}

// lin1_w[800][2000] (col = l*100+s) -> [800][2048] (col = s*20+l)
__global__ void split_pack_lin1(const float* __restrict__ src,
                                unsigned short* __restrict__ dh, unsigned short* __restrict__ dl)
{
    int idx = blockIdx.x * blockDim.x + threadIdx.x;
    if (idx >= V_MID * LATENT * SEQ) return;
    int n = idx / (LATENT * SEQ), c = idx - n * (LATENT * SEQ);
    int l = c / SEQ, s = c - l * SEQ;
    float x = src[idx];
    unsigned short h = f2bf(x);
    size_t d = (size_t)n * KPL1 + s * LATENT + l;
    dh[d] = h;
    dl[d] = f2bf(x - bf2f(h));
}

// ---------------------------------------------------------------------------
// encoder recurrences (batch-parallel; whole chunk of timesteps in one kernel)
// ---------------------------------------------------------------------------
__global__ __launch_bounds__(256)
void enc_rec1(const float* __restrict__ xp, int T,
              const float* __restrict__ whh,           // [240][60]
              float* __restrict__ hbuf, float* __restrict__ cbuf,
              float* __restrict__ h1relu)              // [T][BATCH][60]
{
    __shared__ float Wt[60][240];
    __shared__ float hs[4][60];
    for (int idx = threadIdx.x; idx < 240 * 60; idx += 256) {
        int n = idx / 60, k = idx % 60;
        Wt[k][n] = whh[idx];
    }
    int wid = threadIdx.x >> 6, lane = threadIdx.x & 63;
    int b = blockIdx.x * 4 + wid;
    float h = 0.f, c = 0.f;
    if (lane < 60) {
        h = hbuf[(size_t)b * 60 + lane];
        c = cbuf[(size_t)b * 60 + lane];
        hs[wid][lane] = h;
    }
    __syncthreads();
    for (int t = 0; t < T; ++t) {
        if (lane < 60) {
            const float* xr = xp + ((size_t)t * BATCH + b) * 240;
            float gi = xr[lane], gf = xr[60 + lane], gg = xr[120 + lane], go = xr[180 + lane];
            for (int k = 0; k < 60; ++k) {
                float v = hs[wid][k];
                gi += v * Wt[k][lane];
                gf += v * Wt[k][60 + lane];
                gg += v * Wt[k][120 + lane];
                go += v * Wt[k][180 + lane];
            }
            float cn = sigm(gf) * c + sigm(gi) * tanhf(gg);
            float hn = sigm(go) * tanhf(cn);
            c = cn; h = hn;
            h1relu[((size_t)t * BATCH + b) * 60 + lane] = fmaxf(hn, 0.f);
        }
        __syncthreads();
        if (lane < 60) hs[wid][lane] = h;
        __syncthreads();
    }
    if (lane < 60) {
        hbuf[(size_t)b * 60 + lane] = h;
        cbuf[(size_t)b * 60 + lane] = c;
    }
}

__global__ __launch_bounds__(256)
void enc_rec21(const float* __restrict__ xp, int T, int t0,
               const float* __restrict__ whh,          // [80][20]
               float* __restrict__ hbuf, float* __restrict__ cbuf,
               unsigned short* __restrict__ fh, unsigned short* __restrict__ fl)
{
    __shared__ float Wt[20][80];
    __shared__ float hs[4][20];
    for (int idx = threadIdx.x; idx < 80 * 20; idx += 256) {
        int n = idx / 20, k = idx % 20;
        Wt[k][n] = whh[idx];
    }
    int wid = threadIdx.x >> 6, lane = threadIdx.x & 63;
    int b = blockIdx.x * 4 + wid;
    float h = 0.f, c = 0.f;
    if (lane < 20) {
        h = hbuf[(size_t)b * 20 + lane];
        c = cbuf[(size_t)b * 20 + lane];
        hs[wid][lane] = h;
    }
    __syncthreads();
    for (int t = 0; t < T; ++t) {
        if (lane < 20) {
            const float* xr = xp + ((size_t)t * BATCH + b) * 80;
            float gi = xr[lane], gf = xr[20 + lane], gg = xr[40 + lane], go = xr[60 + lane];
            for (int k = 0; k < 20; ++k) {
                float v = hs[wid][k];
                gi += v * Wt[k][lane];
                gf += v * Wt[k][20 + lane];
                gg += v * Wt[k][40 + lane];
                go += v * Wt[k][60 + lane];
            }
            float cn = sigm(gf) * c + sigm(gi) * tanhf(gg);
            float hn = sigm(go) * tanhf(cn);
            c = cn; h = hn;
            int col = (t0 + t) * 20 + lane;
            unsigned short hh = f2bf(hn);
            fh[(size_t)b * KPL1 + col] = hh;
            fl[(size_t)b * KPL1 + col] = f2bf(hn - bf2f(hh));
        }
        __syncthreads();
        if (lane < 20) hs[wid][lane] = h;
        __syncthreads();
    }
    if (lane < 20) {
        hbuf[(size_t)b * 20 + lane] = h;
        cbuf[(size_t)b * 20 + lane] = c;
    }
}

// ---------------------------------------------------------------------------
// decoder l3 cell fused (gemm 200x70 + pointwise + Act4 write)
// ---------------------------------------------------------------------------
__global__ __launch_bounds__(256)
void dec_l3(const float* __restrict__ outb,
            const float* __restrict__ wih,   // [200][20]
            const float* __restrict__ whh,   // [200][50]
            const float* __restrict__ bih, const float* __restrict__ bhh,
            float* __restrict__ h_t, float* __restrict__ c_t,
            unsigned short* __restrict__ a4h, unsigned short* __restrict__ a4l)
{
    __shared__ float Wt[70][200];
    __shared__ float xin[4][70];
    for (int idx = threadIdx.x; idx < 200 * 20; idx += 256) {
        int n = idx / 20, k = idx % 20;
        Wt[k][n] = wih[idx];
    }
    for (int idx = threadIdx.x; idx < 200 * 50; idx += 256) {
        int n = idx / 50, k = idx % 50;
        Wt[20 + k][n] = whh[idx];
    }
    int wid = threadIdx.x >> 6, lane = threadIdx.x & 63;
    int b = blockIdx.x * 4 + wid;
    if (lane < 20) xin[wid][lane]      = outb[(size_t)b * 20 + lane];
    if (lane < 50) xin[wid][20 + lane] = h_t[(size_t)b * 50 + lane];
    __syncthreads();
    if (lane < 50) {
        float gi = bih[lane] + bhh[lane];
        float gf = bih[50 + lane] + bhh[50 + lane];
        float gg = bih[100 + lane] + bhh[100 + lane];
        float go = bih[150 + lane] + bhh[150 + lane];
        for (int k = 0; k < 70; ++k) {
            float v = xin[wid][k];
            gi += v * Wt[k][lane];
            gf += v * Wt[k][50 + lane];
            gg += v * Wt[k][100 + lane];
            go += v * Wt[k][150 + lane];
        }
        float cold = c_t[(size_t)b * 50 + lane];
        float cn = sigm(gf) * cold + sigm(gi) * tanhf(gg);
        float hn = sigm(go) * tanhf(cn);
        c_t[(size_t)b * 50 + lane] = cn;
        h_t[(size_t)b * 50 + lane] = hn;
        unsigned short hh = f2bf(hn);
        a4h[(size_t)b * KP4 + lane] = hh;
        a4l[(size_t)b * KP4 + lane] = f2bf(hn - bf2f(hh));
    }
}

// l4 pointwise: gates4[B][3200] -> c2, h2 (bf16 hi/lo into Act4 & Act5)
__global__ void pw_l4(const float* __restrict__ g4, float* __restrict__ c2,
                      unsigned short* __restrict__ a4h, unsigned short* __restrict__ a4l,
                      unsigned short* __restrict__ a5h, unsigned short* __restrict__ a5l)
{
    int idx = blockIdx.x * blockDim.x + threadIdx.x;
    if (idx >= BATCH * MID_O) return;
    int b = idx / MID_O, j = idx - b * MID_O;
    const float* g = g4 + (size_t)b * 4 * MID_O;
    float cn = sigm(g[MID_O + j]) * c2[idx] + sigm(g[j]) * tanhf(g[2 * MID_O + j]);
    float hn = sigm(g[3 * MID_O + j]) * tanhf(cn);
    c2[idx] = cn;
    unsigned short hh = f2bf(hn), hl = f2bf(hn - bf2f(hh));
    a4h[(size_t)b * KP4 + 64 + j] = hh;
    a4l[(size_t)b * KP4 + 64 + j] = hl;
    a5h[(size_t)b * KP5 + j] = hh;
    a5l[(size_t)b * KP5 + j] = hl;
}

// l5 pointwise + output emit + down2 (outb for next step)
__global__ __launch_bounds__(256)
void pw_l5_down2(const float* __restrict__ g5, float* __restrict__ c3,
                 unsigned short* __restrict__ a5h, unsigned short* __restrict__ a5l,
                 float* __restrict__ out_t,
                 const float* __restrict__ w2, const float* __restrict__ b2,
                 float* __restrict__ outb)
{
    __shared__ float h3s[8][520];
    __shared__ float w2t[512][20];
    for (int idx = threadIdx.x; idx < 20 * 512; idx += 256) {
        int n = idx / 512, k = idx % 512;
        w2t[k][n] = w2[idx];
    }
    int b0 = blockIdx.x * 8;
    for (int e = threadIdx.x; e < 8 * 512; e += 256) {
        int r = e >> 9, j = e & 511;
        int b = b0 + r;
        const float* g = g5 + (size_t)b * 4 * OUT_DIM;
        size_t ci = (size_t)b * OUT_DIM + j;
        float cn = sigm(g[OUT_DIM + j]) * c3[ci] + sigm(g[j]) * tanhf(g[2 * OUT_DIM + j]);
        float hn = sigm(g[3 * OUT_DIM + j]) * tanhf(cn);
        c3[ci] = cn;
        h3s[r][j] = hn;
        out_t[ci] = hn;
        unsigned short hh = f2bf(hn);
        a5h[(size_t)b * KP5 + 832 + j] = hh;
        a5l[(size_t)b * KP5 + 832 + j] = f2bf(hn - bf2f(hh));
    }
    __syncthreads();
    for (int e = threadIdx.x; e < 8 * 20; e += 256) {
        int r = e / 20, n = e % 20;
        float s = b2[n];
        const float* hr = h3s[r];
        for (int k = 0; k < 512; ++k) s += hr[k] * w2t[k][n];
        outb[(size_t)(b0 + r) * 20 + n] = s;
    }
}

// ---------------------------------------------------------------------------
extern "C" void kernel_launch(void* const* d_in, const int* in_sizes, int n_in,
                              void* d_out_v, int out_size, void* d_ws, size_t ws_size,
                              hipStream_t stream)
{
    const float* x        = (const float*)d_in[0];
    const float* fc1_wih  = (const float*)d_in[1];
    const float* fc1_whh  = (const float*)d_in[2];
    const float* fc1_bih  = (const float*)d_in[3];
    const float* fc1_bhh  = (const float*)d_in[4];
    const float* fc21_wih = (const float*)d_in[5];
    const float* fc21_whh = (const float*)d_in[6];
    const float* fc21_bih = (const float*)d_in[7];
    const float* fc21_bhh = (const float*)d_in[8];
    const float* lin1_w   = (const float*)d_in[9];
    const float* lin1_b   = (const float*)d_in[10];
    const float* lin2_w   = (const float*)d_in[11];
    const float* lin2_b   = (const float*)d_in[12];
    const float* idlin_w  = (const float*)d_in[13];
    const float* idlin_b  = (const float*)d_in[14];
    const float* down1_w  = (const float*)d_in[15];
    const float* down1_b  = (const float*)d_in[16];
    const float* down2_w  = (const float*)d_in[17];
    const float* down2_b  = (const float*)d_in[18];
    const float* l3_wih   = (const float*)d_in[19];
    const float* l3_whh   = (const float*)d_in[20];
    const float* l3_bih   = (const float*)d_in[21];
    const float* l3_bhh   = (const float*)d_in[22];
    const float* l4_wih   = (const float*)d_in[23];
    const float* l4_whh   = (const float*)d_in[24];
    const float* l4_bih   = (const float*)d_in[25];
    const float* l4_bhh   = (const float*)d_in[26];
    const float* l5_wih   = (const float*)d_in[27];
    const float* l5_whh   = (const float*)d_in[28];
    const float* l5_bih   = (const float*)d_in[29];
    const float* l5_bhh   = (const float*)d_in[30];
    float* out = (float*)d_out_v;

    char* base = (char*)d_ws;
    size_t off = 0;
    auto alloc = [&](size_t bytes) -> void* {
        off = (off + 255) & ~(size_t)255;
        void* p = base + off;
        off += bytes;
        return p;
    };

    // --- ushort buffers that must start zeroed (padding) -- keep contiguous ---
    size_t us_begin = (off + 255) & ~(size_t)255;
    unsigned short* W4h = (unsigned short*)alloc((size_t)3200 * KP4 * 2);
    unsigned short* W4l = (unsigned short*)alloc((size_t)3200 * KP4 * 2);
    unsigned short* W5h = (unsigned short*)alloc((size_t)2048 * KP5 * 2);
    unsigned short* W5l = (unsigned short*)alloc((size_t)2048 * KP5 * 2);
    unsigned short* L1h = (unsigned short*)alloc((size_t)V_MID * KPL1 * 2);
    unsigned short* L1l = (unsigned short*)alloc((size_t)V_MID * KPL1 * 2);
    unsigned short* Fh  = (unsigned short*)alloc((size_t)BATCH * KPL1 * 2);
    unsigned short* Fl  = (unsigned short*)alloc((size_t)BATCH * KPL1 * 2);
    unsigned short* A4h = (unsigned short*)alloc((size_t)BATCH * KP4 * 2);
    unsigned short* A4l = (unsigned short*)alloc((size_t)BATCH * KP4 * 2);
    unsigned short* A5h = (unsigned short*)alloc((size_t)BATCH * KP5 * 2);
    unsigned short* A5l = (unsigned short*)alloc((size_t)BATCH * KP5 * 2);
    size_t us_end = off;

    // --- fp32 buffers needing zero init -- contiguous ---
    size_t fz_begin = (off + 255) & ~(size_t)255;
    float* c2   = (float*)alloc((size_t)BATCH * MID_O * 4);
    float* c3   = (float*)alloc((size_t)BATCH * OUT_DIM * 4);
    float* hb1  = (float*)alloc((size_t)BATCH * MID_I * 4);
    float* cb1  = (float*)alloc((size_t)BATCH * MID_I * 4);
    float* hb21 = (float*)alloc((size_t)BATCH * LATENT * 4);
    float* cb21 = (float*)alloc((size_t)BATCH * LATENT * 4);
    size_t fz_end = off;

    // --- no-init buffers ---
    float* gates = (float*)alloc((size_t)BATCH * 4 * MID_O * 4);   // shared l4/l5
    float* mu1   = (float*)alloc((size_t)BATCH * V_MID * 4);
    float* mu    = (float*)alloc((size_t)BATCH * V_LAT * 4);
    float* h_t   = (float*)alloc((size_t)BATCH * V_LAT * 4);
    float* c_t   = (float*)alloc((size_t)BATCH * V_LAT * 4);
    float* outb  = (float*)alloc((size_t)BATCH * LATENT * 4);
    const int CH = 20;
    float* xp1c  = (float*)alloc((size_t)CH * BATCH * 4 * MID_I * 4);
    float* h1rc  = (float*)alloc((size_t)CH * BATCH * MID_I * 4);
    float* xp21c = (float*)alloc((size_t)CH * BATCH * 4 * LATENT * 4);

    hipMemsetAsync(base + us_begin, 0, us_end - us_begin, stream);
    hipMemsetAsync(base + fz_begin, 0, fz_end - fz_begin, stream);

    // --- weight conversion (split-bf16 pack, concatenated along K) ---
    split_pack<<<(3200 * 50  + 255) / 256, 256, 0, stream>>>(l4_wih, 3200 * 50,  50,  KP4, 0,   W4h, W4l);
    split_pack<<<(3200 * 800 + 255) / 256, 256, 0, stream>>>(l4_whh, 3200 * 800, 800, KP4, 64,  W4h, W4l);
    split_pack<<<(2048 * 800 + 255) / 256, 256, 0, stream>>>(l5_wih, 2048 * 800, 800, KP5, 0,   W5h, W5l);
    split_pack<<<(2048 * 512 + 255) / 256, 256, 0, stream>>>(l5_whh, 2048 * 512, 512, KP5, 832, W5h, W5l);
    split_pack_lin1<<<(V_MID * LATENT * SEQ + 255) / 256, 256, 0, stream>>>(lin1_w, L1h, L1l);

    // ---------------- encoder (chunked) ----------------
    for (int c0 = 0; c0 < SEQ; c0 += CH) {
        {
            dim3 g((4 * MID_I + BN - 1) / BN, CH * BATCH / BM);
            gemm2k<false, false><<<g, 256, 0, stream>>>(
                x + (size_t)c0 * BATCH * IN_DIM, IN_DIM, nullptr, 0,
                fc1_wih, nullptr, fc1_bih, fc1_bhh, xp1c, CH * BATCH, 4 * MID_I);
        }
        enc_rec1<<<BATCH / 4, 256, 0, stream>>>(xp1c, CH, fc1_whh, hb1, cb1, h1rc);
        {
            dim3 g((4 * LATENT + BN - 1) / BN, CH * BATCH / BM);
            gemm2k<false, false><<<g, 256, 0, stream>>>(
                h1rc, MID_I, nullptr, 0,
                fc21_wih, nullptr, fc21_bih, fc21_bhh, xp21c, CH * BATCH, 4 * LATENT);
        }
        enc_rec21<<<BATCH / 4, 256, 0, stream>>>(xp21c, CH, c0, fc21_whh, hb21, cb21, Fh, Fl);
    }

    // lin1 (MFMA split) + lin2 (fp32)
    {
        dim3 g((V_MID + GBN - 1) / GBN, BATCH / GBM);
        gemm_mfma3<true><<<g, 256, 0, stream>>>(Fh, Fl, L1h, L1l, lin1_b, nullptr, mu1, V_MID, KPL1);
    }
    {
        dim3 g((V_LAT + BN - 1) / BN, BATCH / BM);
        gemm2k<false, true><<<g, 256, 0, stream>>>(mu1, V_MID, nullptr, 0,
            lin2_w, nullptr, lin2_b, nullptr, mu, BATCH, V_LAT);
    }

    // ---------------- decoder init ----------------
    hipMemcpyAsync(h_t, mu, (size_t)BATCH * V_LAT * 4, hipMemcpyDeviceToDevice, stream);
    {
        dim3 g(1, BATCH / BM);
        gemm2k<false, false><<<g, 256, 0, stream>>>(mu, V_LAT, nullptr, 0,
            idlin_w, nullptr, idlin_b, nullptr, c_t, BATCH, V_LAT);
        gemm2k<false, false><<<g, 256, 0, stream>>>(mu, V_LAT, nullptr, 0,
            down1_w, nullptr, down1_b, nullptr, outb, BATCH, LATENT);
    }

    // ---------------- decoder scan ----------------
    for (int t = 0; t < SEQ; ++t) {
        dec_l3<<<BATCH / 4, 256, 0, stream>>>(outb, l3_wih, l3_whh, l3_bih, l3_bhh,
                                              h_t, c_t, A4h, A4l);
        {
            dim3 g(4 * MID_O / GBN, BATCH / GBM);   // 25 x 16
            gemm_mfma3<false><<<g, 256, 0, stream>>>(A4h, A4l, W4h, W4l,
                l4_bih, l4_bhh, gates, 4 * MID_O, KP4);
        }
        pw_l4<<<(BATCH * MID_O + 255) / 256, 256, 0, stream>>>(gates, c2, A4h, A4l, A5h, A5l);
        {
            dim3 g(4 * OUT_DIM / GBN, BATCH / GBM); // 16 x 16
            gemm_mfma3<false><<<g, 256, 0, stream>>>(A5h, A5l, W5h, W5l,
                l5_bih, l5_bhh, gates, 4 * OUT_DIM, KP5);
        }
        pw_l5_down2<<<BATCH / 8, 256, 0, stream>>>(gates, c3, A5h, A5l,
            out + (size_t)t * BATCH * OUT_DIM, down2_w, down2_b, outb);
    }

    hipMemcpyAsync(out + (size_t)SEQ * BATCH * OUT_DIM, mu,
                   (size_t)BATCH * V_LAT * 4, hipMemcpyDeviceToDevice, stream);
}

// Round 3
// 14532.143 us; speedup vs baseline: 5.0059x; 1.1554x over previous
//
#include <hip/hip_runtime.h>
#include <cstdint>
#include <cstddef>

#define SEQ     100
#define BATCH   2048
#define IN_DIM  64
#define MID_I   60
#define LATENT  20
#define V_MID   800
#define V_LAT   50
#define MID_O   800
#define OUT_DIM 512

#define KP4  896    // [h_t pad 64 | h2 800 | pad to 896]
#define KP5  1344   // [h2 800 pad 832 | h3 512]
#define KPL1 2048   // latent*seq 2000 padded

using f32x4  = __attribute__((ext_vector_type(4))) float;
using u16x8  = __attribute__((ext_vector_type(8))) unsigned short;
using bf16x8 = __attribute__((ext_vector_type(8))) __bf16;

__device__ __forceinline__ unsigned short f2bf(float x){
    unsigned u = __builtin_bit_cast(unsigned, x);
    u += 0x7FFFu + ((u >> 16) & 1u);
    return (unsigned short)(u >> 16);
}
__device__ __forceinline__ float bf2f(unsigned short b){
    unsigned u = ((unsigned)b) << 16; return __builtin_bit_cast(float, u);
}
__device__ __forceinline__ float sigm(float x){ return 1.f/(1.f+expf(-x)); }

typedef const __attribute__((address_space(1))) unsigned int* gas_ptr;
typedef __attribute__((address_space(3))) unsigned int* las_ptr;
__device__ __forceinline__ void gld16(const unsigned short* g, char* l) {
    __builtin_amdgcn_global_load_lds((gas_ptr)g, (las_ptr)l, 16, 0, 0);
}

// ---------------------------------------------------------------------------
// fp32 tiled GEMM (encoder x-projections, lin2, decoder init)
// ---------------------------------------------------------------------------
constexpr int BM = 64, BN = 64, BK = 16;
template<bool RELU_A1, bool RELU_OUT>
__global__ __launch_bounds__(256)
void gemm2k(const float* __restrict__ A1, int K1,
            const float* __restrict__ A2, int K2,
            const float* __restrict__ W1, const float* __restrict__ W2,
            const float* __restrict__ b1, const float* __restrict__ b2,
            float* __restrict__ C, int M, int N)
{
    __shared__ float As[BK][BM + 1];
    __shared__ float Bs[BK][BN + 1];
    const int tx = threadIdx.x & 15;
    const int ty = threadIdx.x >> 4;
    const int n0 = blockIdx.x * BN;
    const int m0 = blockIdx.y * BM;

    float acc[4][4] = {};

    for (int src = 0; src < 2; ++src) {
        const float* A = src ? A2 : A1;
        const float* W = src ? W2 : W1;
        const int    K = src ? K2 : K1;
        if (A == nullptr || K == 0) continue;
        for (int k0 = 0; k0 < K; k0 += BK) {
            #pragma unroll
            for (int i = 0; i < 4; ++i) {
                int idx = threadIdx.x + i * 256;
                int k = idx & 15, m = idx >> 4;
                int gm = m0 + m, gk = k0 + k;
                float v = 0.f;
                if (gm < M && gk < K) v = A[(size_t)gm * K + gk];
                if (RELU_A1 && src == 0) v = fmaxf(v, 0.f);
                As[k][m] = v;
            }
            #pragma unroll
            for (int i = 0; i < 4; ++i) {
                int idx = threadIdx.x + i * 256;
                int k = idx & 15, n = idx >> 4;
                int gn = n0 + n, gk = k0 + k;
                float v = 0.f;
                if (gn < N && gk < K) v = W[(size_t)gn * K + gk];
                Bs[k][n] = v;
            }
            __syncthreads();
            #pragma unroll
            for (int kk = 0; kk < BK; ++kk) {
                float a[4], b[4];
                #pragma unroll
                for (int i = 0; i < 4; ++i) a[i] = As[kk][ty + i * 16];
                #pragma unroll
                for (int j = 0; j < 4; ++j) b[j] = Bs[kk][tx + j * 16];
                #pragma unroll
                for (int i = 0; i < 4; ++i)
                    #pragma unroll
                    for (int j = 0; j < 4; ++j)
                        acc[i][j] += a[i] * b[j];
            }
            __syncthreads();
        }
    }

    #pragma unroll
    for (int i = 0; i < 4; ++i) {
        int gm = m0 + ty + i * 16;
        if (gm >= M) continue;
        #pragma unroll
        for (int j = 0; j < 4; ++j) {
            int gn = n0 + tx + j * 16;
            if (gn >= N) continue;
            float v = acc[i][j];
            if (b1) v += b1[gn];
            if (b2) v += b2[gn];
            if (RELU_OUT) v = fmaxf(v, 0.f);
            C[(size_t)gm * N + gn] = v;
        }
    }
}

// ---------------------------------------------------------------------------
// split-bf16 MFMA GEMM with fused epilogue.
// MODE 0: plain store (bias + optional relu, col guard)   [lin1]
// MODE 1: LSTM pointwise, gate-interleaved cols (l4): writes c-state,
//         h -> (wh1,wl1)[st1,off1] and (wh2,wl2)[st2,off2]
// MODE 2: LSTM pointwise (l5): writes c-state, h -> (wh1,wl1)+out_t fp32
// A,B row-major [rows][Kp], 3-term: AhBh + AhBl + AlBh.
// ---------------------------------------------------------------------------
template<int MODE, bool RELU, bool NGUARD>
__global__ __launch_bounds__(256, 2)
void gemm_fused(const unsigned short* __restrict__ Ah, const unsigned short* __restrict__ Al,
                const unsigned short* __restrict__ Bh, const unsigned short* __restrict__ Bl,
                int Kp, int Nstore,
                const float* __restrict__ bi, const float* __restrict__ bh2,
                float* __restrict__ Cout,
                float* __restrict__ cstate, int H,
                unsigned short* __restrict__ wh1, unsigned short* __restrict__ wl1,
                int st1, int off1,
                unsigned short* __restrict__ wh2, unsigned short* __restrict__ wl2,
                int st2, int off2,
                float* __restrict__ out_t)
{
    __shared__ __align__(16) char smem[67584];
    const int tid  = threadIdx.x;
    const int lane = tid & 63;
    const int wid  = tid >> 6;
    const int m0   = blockIdx.y * 128;
    const int n0   = blockIdx.x * 128;
    const int wr   = (wid >> 1) << 6;
    const int wc   = (wid & 1) << 6;
    const int fr   = lane & 15;
    const int fg   = lane >> 4;
    const int slotR = ((fg ^ (fr & 3)) << 4);            // read slot (bytes)

    // staging: linear LDS dest, source slot pre-swizzled (involution)
    const int r0 = 32 * wid + (lane >> 2);
    const int sl = (((lane & 3) ^ ((lane >> 2) & 3)) << 3);  // elements
    const unsigned short* gA0h = Ah + (size_t)(m0 + r0)      * Kp + sl;
    const unsigned short* gA1h = Ah + (size_t)(m0 + r0 + 16) * Kp + sl;
    const unsigned short* gA0l = Al + (size_t)(m0 + r0)      * Kp + sl;
    const unsigned short* gA1l = Al + (size_t)(m0 + r0 + 16) * Kp + sl;
    const unsigned short* gB0h = Bh + (size_t)(n0 + r0)      * Kp + sl;
    const unsigned short* gB1h = Bh + (size_t)(n0 + r0 + 16) * Kp + sl;
    const unsigned short* gB0l = Bl + (size_t)(n0 + r0)      * Kp + sl;
    const unsigned short* gB1l = Bl + (size_t)(n0 + r0 + 16) * Kp + sl;
    char* lA0h = smem +     0 + (2 * wid    ) * 1024;
    char* lA1h = smem +     0 + (2 * wid + 1) * 1024;
    char* lA0l = smem +  8192 + (2 * wid    ) * 1024;
    char* lA1l = smem +  8192 + (2 * wid + 1) * 1024;
    char* lB0h = smem + 16384 + (2 * wid    ) * 1024;
    char* lB1h = smem + 16384 + (2 * wid + 1) * 1024;
    char* lB0l = smem + 24576 + (2 * wid    ) * 1024;
    char* lB1l = smem + 24576 + (2 * wid + 1) * 1024;

    f32x4 acc[4][4];
    #pragma unroll
    for (int i = 0; i < 4; ++i)
        #pragma unroll
        for (int j = 0; j < 4; ++j) acc[i][j] = (f32x4){0.f, 0.f, 0.f, 0.f};

    for (int k0 = 0; k0 < Kp; k0 += 32) {
        __syncthreads();
        gld16(gA0h + k0, lA0h); gld16(gA1h + k0, lA1h);
        gld16(gA0l + k0, lA0l); gld16(gA1l + k0, lA1l);
        gld16(gB0h + k0, lB0h); gld16(gB1h + k0, lB1h);
        gld16(gB0l + k0, lB0l); gld16(gB1l + k0, lB1l);
        __syncthreads();

        bf16x8 ah[4], al[4];
        #pragma unroll
        for (int i = 0; i < 4; ++i) {
            int ro = (wr + i * 16 + fr) * 64 + slotR;
            ah[i] = *(const bf16x8*)(smem +        ro);
            al[i] = *(const bf16x8*)(smem + 8192 + ro);
        }
        #pragma unroll
        for (int j = 0; j < 4; ++j) {
            int ro = (wc + j * 16 + fr) * 64 + slotR;
            bf16x8 fbh = *(const bf16x8*)(smem + 16384 + ro);
            bf16x8 fbl = *(const bf16x8*)(smem + 24576 + ro);
            #pragma unroll
            for (int i = 0; i < 4; ++i) {
                acc[i][j] = __builtin_amdgcn_mfma_f32_16x16x32_bf16(ah[i], fbh, acc[i][j], 0, 0, 0);
                acc[i][j] = __builtin_amdgcn_mfma_f32_16x16x32_bf16(ah[i], fbl, acc[i][j], 0, 0, 0);
                acc[i][j] = __builtin_amdgcn_mfma_f32_16x16x32_bf16(al[i], fbh, acc[i][j], 0, 0, 0);
            }
        }
    }

    if (MODE == 0) {
        #pragma unroll
        for (int j = 0; j < 4; ++j) {
            int gc = n0 + wc + j * 16 + fr;
            if (NGUARD && gc >= Nstore) continue;
            float badd = bi[gc];
            #pragma unroll
            for (int i = 0; i < 4; ++i)
                #pragma unroll
                for (int r = 0; r < 4; ++r) {
                    int gr = m0 + wr + i * 16 + fg * 4 + r;
                    float v = acc[i][j][r] + badd;
                    if (RELU) v = fmaxf(v, 0.f);
                    Cout[(size_t)gr * Nstore + gc] = v;
                }
        }
    } else {
        __syncthreads();
        float* gt = (float*)smem;               // [128][132]
        #pragma unroll
        for (int i = 0; i < 4; ++i)
            #pragma unroll
            for (int j = 0; j < 4; ++j) {
                int col = wc + j * 16 + fr;
                #pragma unroll
                for (int r = 0; r < 4; ++r)
                    gt[(wr + i * 16 + fg * 4 + r) * 132 + col] = acc[i][j][r];
            }
        __syncthreads();
        const int u0 = n0 >> 2;
        #pragma unroll
        for (int it = 0; it < 16; ++it) {
            int idx = it * 256 + tid;
            int row = idx >> 5, u = idx & 31;
            int gu = u0 + u, gr = m0 + row;
            const float* g = gt + row * 132 + u * 4;
            float gi = g[0] + bi[gu]         + bh2[gu];
            float gf = g[1] + bi[H + gu]     + bh2[H + gu];
            float gg = g[2] + bi[2 * H + gu] + bh2[2 * H + gu];
            float go = g[3] + bi[3 * H + gu] + bh2[3 * H + gu];
            size_t ci = (size_t)gr * H + gu;
            float cn = sigm(gf) * cstate[ci] + sigm(gi) * tanhf(gg);
            float hn = sigm(go) * tanhf(cn);
            cstate[ci] = cn;
            unsigned short hh = f2bf(hn), hl = f2bf(hn - bf2f(hh));
            wh1[(size_t)gr * st1 + off1 + gu] = hh;
            wl1[(size_t)gr * st1 + off1 + gu] = hl;
            if (MODE == 1) {
                wh2[(size_t)gr * st2 + off2 + gu] = hh;
                wl2[(size_t)gr * st2 + off2 + gu] = hl;
            }
            if (MODE == 2) out_t[(size_t)gr * OUT_DIM + gu] = hn;
        }
    }
}

// ---------------------------------------------------------------------------
// weight split/pack (optionally gate-interleaved rows: p = (n%HU)*4 + n/HU)
// ---------------------------------------------------------------------------
__global__ void split_pack(const float* __restrict__ src, int total, int K, int Kp,
                           int coff, int HU,
                           unsigned short* __restrict__ dh, unsigned short* __restrict__ dl)
{
    int idx = blockIdx.x * blockDim.x + threadIdx.x;
    if (idx >= total) return;
    int n = idx / K, k = idx - n * K;
    int p = HU ? ((n % HU) * 4 + n / HU) : n;
    float x = src[idx];
    unsigned short h = f2bf(x);
    size_t d = (size_t)p * Kp + coff + k;
    dh[d] = h;
    dl[d] = f2bf(x - bf2f(h));
}

// lin1_w[800][2000] (col = l*100+s) -> [800][2048] (col = s*20+l)
__global__ void split_pack_lin1(const float* __restrict__ src,
                                unsigned short* __restrict__ dh, unsigned short* __restrict__ dl)
{
    int idx = blockIdx.x * blockDim.x + threadIdx.x;
    if (idx >= V_MID * LATENT * SEQ) return;
    int n = idx / (LATENT * SEQ), c = idx - n * (LATENT * SEQ);
    int l = c / SEQ, s = c - l * SEQ;
    float x = src[idx];
    unsigned short h = f2bf(x);
    size_t d = (size_t)n * KPL1 + s * LATENT + l;
    dh[d] = h;
    dl[d] = f2bf(x - bf2f(h));
}

// ---------------------------------------------------------------------------
// encoder recurrences
// ---------------------------------------------------------------------------
__global__ __launch_bounds__(256)
void enc_rec1(const float* __restrict__ xp, int T,
              const float* __restrict__ whh,           // [240][60]
              float* __restrict__ hbuf, float* __restrict__ cbuf,
              float* __restrict__ h1relu)
{
    __shared__ float Wt[60][240];
    __shared__ float hs[4][60];
    for (int idx = threadIdx.x; idx < 240 * 60; idx += 256) {
        int n = idx / 60, k = idx % 60;
        Wt[k][n] = whh[idx];
    }
    int wid = threadIdx.x >> 6, lane = threadIdx.x & 63;
    int b = blockIdx.x * 4 + wid;
    float h = 0.f, c = 0.f;
    if (lane < 60) {
        h = hbuf[(size_t)b * 60 + lane];
        c = cbuf[(size_t)b * 60 + lane];
        hs[wid][lane] = h;
    }
    __syncthreads();
    for (int t = 0; t < T; ++t) {
        if (lane < 60) {
            const float* xr = xp + ((size_t)t * BATCH + b) * 240;
            float gi = xr[lane], gf = xr[60 + lane], gg = xr[120 + lane], go = xr[180 + lane];
            for (int k = 0; k < 60; ++k) {
                float v = hs[wid][k];
                gi += v * Wt[k][lane];
                gf += v * Wt[k][60 + lane];
                gg += v * Wt[k][120 + lane];
                go += v * Wt[k][180 + lane];
            }
            float cn = sigm(gf) * c + sigm(gi) * tanhf(gg);
            float hn = sigm(go) * tanhf(cn);
            c = cn; h = hn;
            h1relu[((size_t)t * BATCH + b) * 60 + lane] = fmaxf(hn, 0.f);
        }
        __syncthreads();
        if (lane < 60) hs[wid][lane] = h;
        __syncthreads();
    }
    if (lane < 60) {
        hbuf[(size_t)b * 60 + lane] = h;
        cbuf[(size_t)b * 60 + lane] = c;
    }
}

__global__ __launch_bounds__(256)
void enc_rec21(const float* __restrict__ xp, int T, int t0,
               const float* __restrict__ whh,          // [80][20]
               float* __restrict__ hbuf, float* __restrict__ cbuf,
               unsigned short* __restrict__ fh, unsigned short* __restrict__ fl)
{
    __shared__ float Wt[20][80];
    __shared__ float hs[4][20];
    for (int idx = threadIdx.x; idx < 80 * 20; idx += 256) {
        int n = idx / 20, k = idx % 20;
        Wt[k][n] = whh[idx];
    }
    int wid = threadIdx.x >> 6, lane = threadIdx.x & 63;
    int b = blockIdx.x * 4 + wid;
    float h = 0.f, c = 0.f;
    if (lane < 20) {
        h = hbuf[(size_t)b * 20 + lane];
        c = cbuf[(size_t)b * 20 + lane];
        hs[wid][lane] = h;
    }
    __syncthreads();
    for (int t = 0; t < T; ++t) {
        if (lane < 20) {
            const float* xr = xp + ((size_t)t * BATCH + b) * 80;
            float gi = xr[lane], gf = xr[20 + lane], gg = xr[40 + lane], go = xr[60 + lane];
            for (int k = 0; k < 20; ++k) {
                float v = hs[wid][k];
                gi += v * Wt[k][lane];
                gf += v * Wt[k][20 + lane];
                gg += v * Wt[k][40 + lane];
                go += v * Wt[k][60 + lane];
            }
            float cn = sigm(gf) * c + sigm(gi) * tanhf(gg);
            float hn = sigm(go) * tanhf(cn);
            c = cn; h = hn;
            int col = (t0 + t) * 20 + lane;
            unsigned short hh = f2bf(hn);
            fh[(size_t)b * KPL1 + col] = hh;
            fl[(size_t)b * KPL1 + col] = f2bf(hn - bf2f(hh));
        }
        __syncthreads();
        if (lane < 20) hs[wid][lane] = h;
        __syncthreads();
    }
    if (lane < 20) {
        hbuf[(size_t)b * 20 + lane] = h;
        cbuf[(size_t)b * 20 + lane] = c;
    }
}

// ---------------------------------------------------------------------------
// decoder l3 cell for t=0 (outb precomputed from down1)
// ---------------------------------------------------------------------------
__global__ __launch_bounds__(256)
void dec_l3(const float* __restrict__ outb,
            const float* __restrict__ wih,   // [200][20]
            const float* __restrict__ whh,   // [200][50]
            const float* __restrict__ bih, const float* __restrict__ bhh,
            float* __restrict__ h_t, float* __restrict__ c_t,
            unsigned short* __restrict__ a4h, unsigned short* __restrict__ a4l)
{
    __shared__ float Wt[70][200];
    __shared__ float xin[4][70];
    for (int idx = threadIdx.x; idx < 200 * 20; idx += 256) {
        int n = idx / 20, k = idx % 20;
        Wt[k][n] = wih[idx];
    }
    for (int idx = threadIdx.x; idx < 200 * 50; idx += 256) {
        int n = idx / 50, k = idx % 50;
        Wt[20 + k][n] = whh[idx];
    }
    int wid = threadIdx.x >> 6, lane = threadIdx.x & 63;
    int b = blockIdx.x * 4 + wid;
    if (lane < 20) xin[wid][lane]      = outb[(size_t)b * 20 + lane];
    if (lane < 50) xin[wid][20 + lane] = h_t[(size_t)b * 50 + lane];
    __syncthreads();
    if (lane < 50) {
        float gi = bih[lane] + bhh[lane];
        float gf = bih[50 + lane] + bhh[50 + lane];
        float gg = bih[100 + lane] + bhh[100 + lane];
        float go = bih[150 + lane] + bhh[150 + lane];
        for (int k = 0; k < 70; ++k) {
            float v = xin[wid][k];
            gi += v * Wt[k][lane];
            gf += v * Wt[k][50 + lane];
            gg += v * Wt[k][100 + lane];
            go += v * Wt[k][150 + lane];
        }
        float cold = c_t[(size_t)b * 50 + lane];
        float cn = sigm(gf) * cold + sigm(gi) * tanhf(gg);
        float hn = sigm(go) * tanhf(cn);
        c_t[(size_t)b * 50 + lane] = cn;
        h_t[(size_t)b * 50 + lane] = hn;
        unsigned short hh = f2bf(hn);
        a4h[(size_t)b * KP4 + lane] = hh;
        a4l[(size_t)b * KP4 + lane] = f2bf(hn - bf2f(hh));
    }
}

// ---------------------------------------------------------------------------
// fused down2 + l3 cell for t>=1: 8 batch rows per block
// ---------------------------------------------------------------------------
__global__ __launch_bounds__(256)
void dec_step3(const float* __restrict__ h3prev,       // [B][512] fp32
               const float* __restrict__ w2, const float* __restrict__ b2,
               const float* __restrict__ wih, const float* __restrict__ whh,
               const float* __restrict__ bih, const float* __restrict__ bhh,
               float* __restrict__ h_t, float* __restrict__ c_t,
               unsigned short* __restrict__ a4h, unsigned short* __restrict__ a4l)
{
    __shared__ float w2s[512][20];     // [k][n]
    __shared__ float W3[70][200];      // [k][gate*50+u]
    __shared__ float h3s[8][516];
    __shared__ float xb[8][72];        // [0..19]=outb, [20..69]=h_t
    const int tid = threadIdx.x;
    const int r0 = blockIdx.x * 8;

    for (int idx = tid; idx < 20 * 512; idx += 256) {
        int n = idx / 512, k = idx - n * 512;
        w2s[k][n] = w2[idx];
    }
    for (int idx = tid; idx < 200 * 20; idx += 256) {
        int n = idx / 20, k = idx - n * 20;
        W3[k][n] = wih[idx];
    }
    for (int idx = tid; idx < 200 * 50; idx += 256) {
        int n = idx / 50, k = idx - n * 50;
        W3[20 + k][n] = whh[idx];
    }
    for (int idx = tid; idx < 8 * 512; idx += 256) {
        int r = idx >> 9, k = idx & 511;
        h3s[r][k] = h3prev[(size_t)(r0 + r) * 512 + k];
    }
    for (int idx = tid; idx < 8 * 50; idx += 256) {
        int r = idx / 50, u = idx - (idx / 50) * 50;
        xb[r][20 + u] = h_t[(size_t)(r0 + r) * 50 + u];
    }
    __syncthreads();

    if (tid < 160) {                   // down2: 8 rows x 20 outputs
        int r = tid / 20, n = tid - (tid / 20) * 20;
        float s = b2[n];
        for (int k = 0; k < 512; ++k) s += h3s[r][k] * w2s[k][n];
        xb[r][n] = s;
    }
    __syncthreads();

    for (int e = tid; e < 400; e += 256) {   // l3 cell: 8 rows x 50 units
        int r = e / 50, u = e - (e / 50) * 50;
        float gi = bih[u] + bhh[u];
        float gf = bih[50 + u] + bhh[50 + u];
        float gg = bih[100 + u] + bhh[100 + u];
        float go = bih[150 + u] + bhh[150 + u];
        for (int k = 0; k < 70; ++k) {
            float v = xb[r][k];
            gi += v * W3[k][u];
            gf += v * W3[k][50 + u];
            gg += v * W3[k][100 + u];
            go += v * W3[k][150 + u];
        }
        size_t ci = (size_t)(r0 + r) * 50 + u;
        float cn = sigm(gf) * c_t[ci] + sigm(gi) * tanhf(gg);
        float hn = sigm(go) * tanhf(cn);
        c_t[ci] = cn;
        h_t[ci] = hn;
        unsigned short hh = f2bf(hn);
        a4h[(size_t)(r0 + r) * KP4 + u] = hh;
        a4l[(size_t)(r0 + r) * KP4 + u] = f2bf(hn - bf2f(hh));
    }
}

// ---------------------------------------------------------------------------
extern "C" void kernel_launch(void* const* d_in, const int* in_sizes, int n_in,
                              void* d_out_v, int out_size, void* d_ws, size_t ws_size,
                              hipStream_t stream)
{
    const float* x        = (const float*)d_in[0];
    const float* fc1_wih  = (const float*)d_in[1];
    const float* fc1_whh  = (const float*)d_in[2];
    const float* fc1_bih  = (const float*)d_in[3];
    const float* fc1_bhh  = (const float*)d_in[4];
    const float* fc21_wih = (const float*)d_in[5];
    const float* fc21_whh = (const float*)d_in[6];
    const float* fc21_bih = (const float*)d_in[7];
    const float* fc21_bhh = (const float*)d_in[8];
    const float* lin1_w   = (const float*)d_in[9];
    const float* lin1_b   = (const float*)d_in[10];
    const float* lin2_w   = (const float*)d_in[11];
    const float* lin2_b   = (const float*)d_in[12];
    const float* idlin_w  = (const float*)d_in[13];
    const float* idlin_b  = (const float*)d_in[14];
    const float* down1_w  = (const float*)d_in[15];
    const float* down1_b  = (const float*)d_in[16];
    const float* down2_w  = (const float*)d_in[17];
    const float* down2_b  = (const float*)d_in[18];
    const float* l3_wih   = (const float*)d_in[19];
    const float* l3_whh   = (const float*)d_in[20];
    const float* l3_bih   = (const float*)d_in[21];
    const float* l3_bhh   = (const float*)d_in[22];
    const float* l4_wih   = (const float*)d_in[23];
    const float* l4_whh   = (const float*)d_in[24];
    const float* l4_bih   = (const float*)d_in[25];
    const float* l4_bhh   = (const float*)d_in[26];
    const float* l5_wih   = (const float*)d_in[27];
    const float* l5_whh   = (const float*)d_in[28];
    const float* l5_bih   = (const float*)d_in[29];
    const float* l5_bhh   = (const float*)d_in[30];
    float* out = (float*)d_out_v;

    char* base = (char*)d_ws;
    size_t off = 0;
    auto alloc = [&](size_t bytes) -> void* {
        off = (off + 255) & ~(size_t)255;
        void* p = base + off;
        off += bytes;
        return p;
    };

    // --- zero-init ushort region ---
    size_t us_begin = (off + 255) & ~(size_t)255;
    unsigned short* W4h = (unsigned short*)alloc((size_t)3200 * KP4 * 2);
    unsigned short* W4l = (unsigned short*)alloc((size_t)3200 * KP4 * 2);
    unsigned short* W5h = (unsigned short*)alloc((size_t)2048 * KP5 * 2);
    unsigned short* W5l = (unsigned short*)alloc((size_t)2048 * KP5 * 2);
    unsigned short* L1h = (unsigned short*)alloc((size_t)896 * KPL1 * 2);
    unsigned short* L1l = (unsigned short*)alloc((size_t)896 * KPL1 * 2);
    unsigned short* Fh  = (unsigned short*)alloc((size_t)BATCH * KPL1 * 2);
    unsigned short* Fl  = (unsigned short*)alloc((size_t)BATCH * KPL1 * 2);
    unsigned short* A4h[2]; unsigned short* A4l[2];
    unsigned short* A5h[2]; unsigned short* A5l[2];
    for (int p = 0; p < 2; ++p) {
        A4h[p] = (unsigned short*)alloc((size_t)BATCH * KP4 * 2);
        A4l[p] = (unsigned short*)alloc((size_t)BATCH * KP4 * 2);
        A5h[p] = (unsigned short*)alloc((size_t)BATCH * KP5 * 2);
        A5l[p] = (unsigned short*)alloc((size_t)BATCH * KP5 * 2);
    }
    size_t us_end = off;

    // --- zero-init fp32 region ---
    size_t fz_begin = (off + 255) & ~(size_t)255;
    float* c2   = (float*)alloc((size_t)BATCH * MID_O * 4);
    float* c3   = (float*)alloc((size_t)BATCH * OUT_DIM * 4);
    float* hb1  = (float*)alloc((size_t)BATCH * MID_I * 4);
    float* cb1  = (float*)alloc((size_t)BATCH * MID_I * 4);
    float* hb21 = (float*)alloc((size_t)BATCH * LATENT * 4);
    float* cb21 = (float*)alloc((size_t)BATCH * LATENT * 4);
    size_t fz_end = off;

    // --- no-init buffers ---
    float* mu1   = (float*)alloc((size_t)BATCH * V_MID * 4);
    float* mu    = (float*)alloc((size_t)BATCH * V_LAT * 4);
    float* h_t   = (float*)alloc((size_t)BATCH * V_LAT * 4);
    float* c_t   = (float*)alloc((size_t)BATCH * V_LAT * 4);
    float* outb  = (float*)alloc((size_t)BATCH * LATENT * 4);
    const int CH = 20;
    float* xp1c  = (float*)alloc((size_t)CH * BATCH * 4 * MID_I * 4);
    float* h1rc  = (float*)alloc((size_t)CH * BATCH * MID_I * 4);
    float* xp21c = (float*)alloc((size_t)CH * BATCH * 4 * LATENT * 4);

    hipMemsetAsync(base + us_begin, 0, us_end - us_begin, stream);
    hipMemsetAsync(base + fz_begin, 0, fz_end - fz_begin, stream);

    // --- weight packing (gate-interleaved for l4/l5) ---
    split_pack<<<(3200 * 50  + 255) / 256, 256, 0, stream>>>(l4_wih, 3200 * 50,  50,  KP4, 0,   800, W4h, W4l);
    split_pack<<<(3200 * 800 + 255) / 256, 256, 0, stream>>>(l4_whh, 3200 * 800, 800, KP4, 64,  800, W4h, W4l);
    split_pack<<<(2048 * 800 + 255) / 256, 256, 0, stream>>>(l5_wih, 2048 * 800, 800, KP5, 0,   512, W5h, W5l);
    split_pack<<<(2048 * 512 + 255) / 256, 256, 0, stream>>>(l5_whh, 2048 * 512, 512, KP5, 832, 512, W5h, W5l);
    split_pack_lin1<<<(V_MID * LATENT * SEQ + 255) / 256, 256, 0, stream>>>(lin1_w, L1h, L1l);

    // ---------------- encoder ----------------
    for (int c0 = 0; c0 < SEQ; c0 += CH) {
        {
            dim3 g((4 * MID_I + BN - 1) / BN, CH * BATCH / BM);
            gemm2k<false, false><<<g, 256, 0, stream>>>(
                x + (size_t)c0 * BATCH * IN_DIM, IN_DIM, nullptr, 0,
                fc1_wih, nullptr, fc1_bih, fc1_bhh, xp1c, CH * BATCH, 4 * MID_I);
        }
        enc_rec1<<<BATCH / 4, 256, 0, stream>>>(xp1c, CH, fc1_whh, hb1, cb1, h1rc);
        {
            dim3 g((4 * LATENT + BN - 1) / BN, CH * BATCH / BM);
            gemm2k<false, false><<<g, 256, 0, stream>>>(
                h1rc, MID_I, nullptr, 0,
                fc21_wih, nullptr, fc21_bih, fc21_bhh, xp21c, CH * BATCH, 4 * LATENT);
        }
        enc_rec21<<<BATCH / 4, 256, 0, stream>>>(xp21c, CH, c0, fc21_whh, hb21, cb21, Fh, Fl);
    }

    // lin1 (MFMA, MODE0) + lin2 (fp32)
    {
        dim3 g(7, 16);
        gemm_fused<0, true, true><<<g, 256, 0, stream>>>(
            Fh, Fl, L1h, L1l, KPL1, V_MID, lin1_b, nullptr, mu1,
            nullptr, 0, nullptr, nullptr, 0, 0, nullptr, nullptr, 0, 0, nullptr);
    }
    {
        dim3 g((V_LAT + BN - 1) / BN, BATCH / BM);
        gemm2k<false, true><<<g, 256, 0, stream>>>(mu1, V_MID, nullptr, 0,
            lin2_w, nullptr, lin2_b, nullptr, mu, BATCH, V_LAT);
    }

    // ---------------- decoder init ----------------
    hipMemcpyAsync(h_t, mu, (size_t)BATCH * V_LAT * 4, hipMemcpyDeviceToDevice, stream);
    {
        dim3 g(1, BATCH / BM);
        gemm2k<false, false><<<g, 256, 0, stream>>>(mu, V_LAT, nullptr, 0,
            idlin_w, nullptr, idlin_b, nullptr, c_t, BATCH, V_LAT);
        gemm2k<false, false><<<g, 256, 0, stream>>>(mu, V_LAT, nullptr, 0,
            down1_w, nullptr, down1_b, nullptr, outb, BATCH, LATENT);
    }

    // ---------------- decoder scan ----------------
    for (int t = 0; t < SEQ; ++t) {
        const int p = t & 1;
        if (t == 0) {
            dec_l3<<<BATCH / 4, 256, 0, stream>>>(outb, l3_wih, l3_whh, l3_bih, l3_bhh,
                                                  h_t, c_t, A4h[0], A4l[0]);
        } else {
            dec_step3<<<BATCH / 8, 256, 0, stream>>>(
                out + (size_t)(t - 1) * BATCH * OUT_DIM,
                down2_w, down2_b, l3_wih, l3_whh, l3_bih, l3_bhh,
                h_t, c_t, A4h[p], A4l[p]);
        }
        {
            dim3 g(25, 16);
            gemm_fused<1, false, false><<<g, 256, 0, stream>>>(
                A4h[p], A4l[p], W4h, W4l, KP4, 4 * MID_O, l4_bih, l4_bhh, nullptr,
                c2, MID_O,
                A4h[p ^ 1], A4l[p ^ 1], KP4, 64,
                A5h[p], A5l[p], KP5, 0, nullptr);
        }
        {
            dim3 g(16, 16);
            gemm_fused<2, false, false><<<g, 256, 0, stream>>>(
                A5h[p], A5l[p], W5h, W5l, KP5, 4 * OUT_DIM, l5_bih, l5_bhh, nullptr,
                c3, OUT_DIM,
                A5h[p ^ 1], A5l[p ^ 1], KP5, 832,
                nullptr, nullptr, 0, 0,
                out + (size_t)t * BATCH * OUT_DIM);
        }
    }

    hipMemcpyAsync(out + (size_t)SEQ * BATCH * OUT_DIM, mu,
                   (size_t)BATCH * V_LAT * 4, hipMemcpyDeviceToDevice, stream);
}

// Round 4
// 11907.072 us; speedup vs baseline: 6.1095x; 1.2205x over previous
//
#include <hip/hip_runtime.h>
#include <cstdint>
#include <cstddef>

#define SEQ     100
#define BATCH   2048
#define IN_DIM  64
#define MID_I   60
#define LATENT  20
#define V_MID   800
#define V_LAT   50
#define MID_O   800
#define OUT_DIM 512

#define KP4  896    // [h_t pad 64 | h2 800 | pad to 896]
#define KP5  1344   // [h2 800 pad 832 | h3 512]
#define KPL1 2048   // latent*seq 2000 padded

using f32x4  = __attribute__((ext_vector_type(4))) float;
using u16x8  = __attribute__((ext_vector_type(8))) unsigned short;
using bf16x8 = __attribute__((ext_vector_type(8))) __bf16;
typedef _Float16 f16;
typedef _Float16 f16x8 __attribute__((ext_vector_type(8)));

__device__ __forceinline__ unsigned short f2bf(float x){
    unsigned u = __builtin_bit_cast(unsigned, x);
    u += 0x7FFFu + ((u >> 16) & 1u);
    return (unsigned short)(u >> 16);
}
__device__ __forceinline__ float bf2f(unsigned short b){
    unsigned u = ((unsigned)b) << 16; return __builtin_bit_cast(float, u);
}
__device__ __forceinline__ float sigm(float x){ return 1.f/(1.f+expf(-x)); }

typedef const __attribute__((address_space(1))) unsigned int* gas_ptr;
typedef __attribute__((address_space(3))) unsigned int* las_ptr;
__device__ __forceinline__ void gld16(const void* g, char* l) {
    __builtin_amdgcn_global_load_lds((gas_ptr)g, (las_ptr)l, 16, 0, 0);
}

// ---------------------------------------------------------------------------
// fp32 tiled GEMM (encoder x-projections, lin2, decoder init)
// ---------------------------------------------------------------------------
constexpr int BM = 64, BN = 64, BK = 16;
template<bool RELU_A1, bool RELU_OUT>
__global__ __launch_bounds__(256)
void gemm2k(const float* __restrict__ A1, int K1,
            const float* __restrict__ A2, int K2,
            const float* __restrict__ W1, const float* __restrict__ W2,
            const float* __restrict__ b1, const float* __restrict__ b2,
            float* __restrict__ C, int M, int N)
{
    __shared__ float As[BK][BM + 1];
    __shared__ float Bs[BK][BN + 1];
    const int tx = threadIdx.x & 15;
    const int ty = threadIdx.x >> 4;
    const int n0 = blockIdx.x * BN;
    const int m0 = blockIdx.y * BM;

    float acc[4][4] = {};

    for (int src = 0; src < 2; ++src) {
        const float* A = src ? A2 : A1;
        const float* W = src ? W2 : W1;
        const int    K = src ? K2 : K1;
        if (A == nullptr || K == 0) continue;
        for (int k0 = 0; k0 < K; k0 += BK) {
            #pragma unroll
            for (int i = 0; i < 4; ++i) {
                int idx = threadIdx.x + i * 256;
                int k = idx & 15, m = idx >> 4;
                int gm = m0 + m, gk = k0 + k;
                float v = 0.f;
                if (gm < M && gk < K) v = A[(size_t)gm * K + gk];
                if (RELU_A1 && src == 0) v = fmaxf(v, 0.f);
                As[k][m] = v;
            }
            #pragma unroll
            for (int i = 0; i < 4; ++i) {
                int idx = threadIdx.x + i * 256;
                int k = idx & 15, n = idx >> 4;
                int gn = n0 + n, gk = k0 + k;
                float v = 0.f;
                if (gn < N && gk < K) v = W[(size_t)gn * K + gk];
                Bs[k][n] = v;
            }
            __syncthreads();
            #pragma unroll
            for (int kk = 0; kk < BK; ++kk) {
                float a[4], b[4];
                #pragma unroll
                for (int i = 0; i < 4; ++i) a[i] = As[kk][ty + i * 16];
                #pragma unroll
                for (int j = 0; j < 4; ++j) b[j] = Bs[kk][tx + j * 16];
                #pragma unroll
                for (int i = 0; i < 4; ++i)
                    #pragma unroll
                    for (int j = 0; j < 4; ++j)
                        acc[i][j] += a[i] * b[j];
            }
            __syncthreads();
        }
    }

    #pragma unroll
    for (int i = 0; i < 4; ++i) {
        int gm = m0 + ty + i * 16;
        if (gm >= M) continue;
        #pragma unroll
        for (int j = 0; j < 4; ++j) {
            int gn = n0 + tx + j * 16;
            if (gn >= N) continue;
            float v = acc[i][j];
            if (b1) v += b1[gn];
            if (b2) v += b2[gn];
            if (RELU_OUT) v = fmaxf(v, 0.f);
            C[(size_t)gm * N + gn] = v;
        }
    }
}

// ---------------------------------------------------------------------------
// lin1: split-bf16 3-term MFMA GEMM, 128x128 tile, plain store + relu
// ---------------------------------------------------------------------------
__global__ __launch_bounds__(256, 2)
void gemm_lin1(const unsigned short* __restrict__ Ah, const unsigned short* __restrict__ Al,
               const unsigned short* __restrict__ Bh, const unsigned short* __restrict__ Bl,
               int Kp, int Nstore, const float* __restrict__ bi, float* __restrict__ Cout)
{
    __shared__ __align__(16) char smem[32768];
    const int tid  = threadIdx.x;
    const int lane = tid & 63;
    const int wid  = tid >> 6;
    const int m0   = blockIdx.y * 128;
    const int n0   = blockIdx.x * 128;
    const int wr   = (wid >> 1) << 6;
    const int wc   = (wid & 1) << 6;
    const int fr   = lane & 15;
    const int fg   = lane >> 4;
    const int slotR = ((fg ^ (fr & 3)) << 4);

    const int r0 = 32 * wid + (lane >> 2);
    const int sl = (((lane & 3) ^ ((lane >> 2) & 3)) << 3);
    const unsigned short* gA0h = Ah + (size_t)(m0 + r0)      * Kp + sl;
    const unsigned short* gA1h = Ah + (size_t)(m0 + r0 + 16) * Kp + sl;
    const unsigned short* gA0l = Al + (size_t)(m0 + r0)      * Kp + sl;
    const unsigned short* gA1l = Al + (size_t)(m0 + r0 + 16) * Kp + sl;
    const unsigned short* gB0h = Bh + (size_t)(n0 + r0)      * Kp + sl;
    const unsigned short* gB1h = Bh + (size_t)(n0 + r0 + 16) * Kp + sl;
    const unsigned short* gB0l = Bl + (size_t)(n0 + r0)      * Kp + sl;
    const unsigned short* gB1l = Bl + (size_t)(n0 + r0 + 16) * Kp + sl;
    char* lA0h = smem +     0 + (2 * wid    ) * 1024;
    char* lA1h = smem +     0 + (2 * wid + 1) * 1024;
    char* lA0l = smem +  8192 + (2 * wid    ) * 1024;
    char* lA1l = smem +  8192 + (2 * wid + 1) * 1024;
    char* lB0h = smem + 16384 + (2 * wid    ) * 1024;
    char* lB1h = smem + 16384 + (2 * wid + 1) * 1024;
    char* lB0l = smem + 24576 + (2 * wid    ) * 1024;
    char* lB1l = smem + 24576 + (2 * wid + 1) * 1024;

    f32x4 acc[4][4];
    #pragma unroll
    for (int i = 0; i < 4; ++i)
        #pragma unroll
        for (int j = 0; j < 4; ++j) acc[i][j] = (f32x4){0.f, 0.f, 0.f, 0.f};

    for (int k0 = 0; k0 < Kp; k0 += 32) {
        __syncthreads();
        gld16(gA0h + k0, lA0h); gld16(gA1h + k0, lA1h);
        gld16(gA0l + k0, lA0l); gld16(gA1l + k0, lA1l);
        gld16(gB0h + k0, lB0h); gld16(gB1h + k0, lB1h);
        gld16(gB0l + k0, lB0l); gld16(gB1l + k0, lB1l);
        __syncthreads();

        bf16x8 ah[4], al[4];
        #pragma unroll
        for (int i = 0; i < 4; ++i) {
            int ro = (wr + i * 16 + fr) * 64 + slotR;
            ah[i] = *(const bf16x8*)(smem +        ro);
            al[i] = *(const bf16x8*)(smem + 8192 + ro);
        }
        #pragma unroll
        for (int j = 0; j < 4; ++j) {
            int ro = (wc + j * 16 + fr) * 64 + slotR;
            bf16x8 fbh = *(const bf16x8*)(smem + 16384 + ro);
            bf16x8 fbl = *(const bf16x8*)(smem + 24576 + ro);
            #pragma unroll
            for (int i = 0; i < 4; ++i) {
                acc[i][j] = __builtin_amdgcn_mfma_f32_16x16x32_bf16(ah[i], fbh, acc[i][j], 0, 0, 0);
                acc[i][j] = __builtin_amdgcn_mfma_f32_16x16x32_bf16(ah[i], fbl, acc[i][j], 0, 0, 0);
                acc[i][j] = __builtin_amdgcn_mfma_f32_16x16x32_bf16(al[i], fbh, acc[i][j], 0, 0, 0);
            }
        }
    }

    #pragma unroll
    for (int j = 0; j < 4; ++j) {
        int gc = n0 + wc + j * 16 + fr;
        if (gc >= Nstore) continue;
        float badd = bi[gc];
        #pragma unroll
        for (int i = 0; i < 4; ++i)
            #pragma unroll
            for (int r = 0; r < 4; ++r) {
                int gr = m0 + wr + i * 16 + fg * 4 + r;
                float v = fmaxf(acc[i][j][r] + badd, 0.f);
                Cout[(size_t)gr * Nstore + gc] = v;
            }
    }
}

// ---------------------------------------------------------------------------
// decoder GEMM: fp16 2-term (A * Wh + A * Wl*2^-11), 256x128 tile, 8 waves,
// double-buffered global_load_lds staging, fused LSTM pointwise epilogue.
// Weights gate-interleaved (row p = (n%H)*4 + n/H) -> quad-lane transpose.
// MODE 1 = l4 (h -> wr1 and wr2), MODE 2 = l5 (h -> wr1 + fp32 out_t).
// ---------------------------------------------------------------------------
template<int MODE>
__global__ __launch_bounds__(512, 2)
void gemm_dec(const f16* __restrict__ A, const f16* __restrict__ Wh, const f16* __restrict__ Wl,
              int Kp, int NK, int H,
              const float* __restrict__ bp,     // permuted combined bias [H*4]
              float* __restrict__ cstate,
              f16* __restrict__ wr1, int st1, int off1,
              f16* __restrict__ wr2, int st2, int off2,
              float* __restrict__ out_t)
{
    __shared__ __align__(16) char smem[65536];
    const int tid  = threadIdx.x;
    const int lane = tid & 63;
    const int wid  = tid >> 6;
    const int m0   = blockIdx.y * 256;
    const int n0   = blockIdx.x * 128;
    const int wm   = wid >> 1;         // 0..3
    const int wn   = wid & 1;          // 0..1
    const int fr   = lane & 15;
    const int fg   = lane >> 4;
    const int swz  = (fg ^ (fr & 3) ^ ((fr >> 2) & 3)) * 16;  // byte offset

    // staging addressing (linear LDS dest, pre-swizzled global source)
    const int qsrc = (lane & 3) ^ ((lane >> 2) & 3) ^ ((lane >> 4) & 3);
    const size_t loff = (size_t)(lane >> 2) * Kp + qsrc * 8;
    const int rbA0 = 32 * wid, rbA1 = 32 * wid + 16, rbW = 16 * wid;
    const f16* srcA0 = A  + (size_t)(m0 + rbA0) * Kp + loff;
    const f16* srcA1 = A  + (size_t)(m0 + rbA1) * Kp + loff;
    const f16* srcWh = Wh + (size_t)(n0 + rbW) * Kp + loff;
    const f16* srcWl = Wl + (size_t)(n0 + rbW) * Kp + loff;

    f32x4 accH[4][4], accL[4][4];
    #pragma unroll
    for (int i = 0; i < 4; ++i)
        #pragma unroll
        for (int j = 0; j < 4; ++j) {
            accH[i][j] = (f32x4){0.f, 0.f, 0.f, 0.f};
            accL[i][j] = (f32x4){0.f, 0.f, 0.f, 0.f};
        }

    auto stage = [&](int buf, int t) {
        const int kb = t * 32;
        char* bb = smem + buf * 32768;
        gld16(srcA0 + kb, bb + rbA0 * 64);
        gld16(srcA1 + kb, bb + rbA1 * 64);
        gld16(srcWh + kb, bb + 16384 + rbW * 64);
        gld16(srcWl + kb, bb + 24576 + rbW * 64);
    };

    stage(0, 0);
    asm volatile("s_waitcnt vmcnt(0)" ::: "memory");
    __syncthreads();

    int cur = 0;
    for (int t = 0; t < NK; ++t) {
        if (t + 1 < NK) stage(cur ^ 1, t + 1);
        const char* bb = smem + cur * 32768;
        f16x8 af[4];
        #pragma unroll
        for (int i = 0; i < 4; ++i)
            af[i] = *(const f16x8*)(bb + (64 * wm + 16 * i + fr) * 64 + swz);
        #pragma unroll
        for (int j = 0; j < 4; ++j) {
            f16x8 vwh = *(const f16x8*)(bb + 16384 + (64 * wn + 16 * j + fr) * 64 + swz);
            f16x8 vwl = *(const f16x8*)(bb + 24576 + (64 * wn + 16 * j + fr) * 64 + swz);
            #pragma unroll
            for (int i = 0; i < 4; ++i) {
                accH[i][j] = __builtin_amdgcn_mfma_f32_16x16x32_f16(af[i], vwh, accH[i][j], 0, 0, 0);
                accL[i][j] = __builtin_amdgcn_mfma_f32_16x16x32_f16(af[i], vwl, accL[i][j], 0, 0, 0);
            }
        }
        asm volatile("s_waitcnt vmcnt(0)" ::: "memory");
        __syncthreads();
        cur ^= 1;
    }

    // -------- epilogue: quad-lane 4x4 transpose -> LSTM pointwise --------
    const float INV = 1.0f / 2048.0f;
    const int q   = lane & 3;
    const bool qb0 = (lane & 1) != 0;
    const bool qb1 = (lane & 2) != 0;
    const int ubase = (n0 >> 2) + 16 * wn;
    const f32x4* bp4 = (const f32x4*)bp;

    #pragma unroll
    for (int i = 0; i < 4; ++i) {
        #pragma unroll
        for (int j = 0; j < 4; ++j) {
            float v0 = accH[i][j][0] + accL[i][j][0] * INV;
            float v1 = accH[i][j][1] + accL[i][j][1] * INV;
            float v2 = accH[i][j][2] + accL[i][j][2] * INV;
            float v3 = accH[i][j][3] + accL[i][j][3] * INV;
            // stage A: swap lane-bit0 with reg-bit0
            {
                float s0 = qb0 ? v0 : v1;
                float s1 = qb0 ? v2 : v3;
                float r0 = __shfl_xor(s0, 1);
                float r1 = __shfl_xor(s1, 1);
                if (!qb0) { v1 = r0; v3 = r1; } else { v0 = r0; v2 = r1; }
            }
            // stage B: swap lane-bit1 with reg-bit1
            {
                float s0 = qb1 ? v0 : v2;
                float s1 = qb1 ? v1 : v3;
                float r0 = __shfl_xor(s0, 2);
                float r1 = __shfl_xor(s1, 2);
                if (!qb1) { v2 = r0; v3 = r1; } else { v0 = r0; v1 = r1; }
            }
            // now v0..v3 = gates i,f,g,o of (row, unit) for this lane
            const int unit = ubase + 4 * j + (fr >> 2);
            const int row  = m0 + 64 * wm + 16 * i + 4 * fg + q;
            f32x4 bv = bp4[unit];
            float gi = v0 + bv[0], gf = v1 + bv[1], gg = v2 + bv[2], go = v3 + bv[3];
            size_t ci = (size_t)row * H + unit;
            float cn = sigm(gf) * cstate[ci] + sigm(gi) * tanhf(gg);
            float hn = sigm(go) * tanhf(cn);
            cstate[ci] = cn;
            f16 hh = (f16)hn;
            wr1[(size_t)row * st1 + off1 + unit] = hh;
            if (MODE == 1) wr2[(size_t)row * st2 + off2 + unit] = hh;
            if (MODE == 2) out_t[(size_t)row * H + unit] = hn;
        }
    }
}

// ---------------------------------------------------------------------------
// packing kernels
// ---------------------------------------------------------------------------
// bf16 hi/lo (lin1 path)
__global__ void split_pack_lin1(const float* __restrict__ src,
                                unsigned short* __restrict__ dh, unsigned short* __restrict__ dl)
{
    int idx = blockIdx.x * blockDim.x + threadIdx.x;
    if (idx >= V_MID * LATENT * SEQ) return;
    int n = idx / (LATENT * SEQ), c = idx - n * (LATENT * SEQ);
    int l = c / SEQ, s = c - l * SEQ;
    float x = src[idx];
    unsigned short h = f2bf(x);
    size_t d = (size_t)n * KPL1 + s * LATENT + l;
    dh[d] = h;
    dl[d] = f2bf(x - bf2f(h));
}

// fp16 weight split, gate-interleaved rows p=(n%HU)*4+n/HU, lo scaled by 2^11
__global__ void split_pack_f16(const float* __restrict__ src, int total, int K, int Kp,
                               int coff, int HU,
                               f16* __restrict__ dh, f16* __restrict__ dl)
{
    int idx = blockIdx.x * blockDim.x + threadIdx.x;
    if (idx >= total) return;
    int n = idx / K, k = idx - n * K;
    int p = (n % HU) * 4 + n / HU;
    float x = src[idx];
    f16 h = (f16)x;
    size_t d = (size_t)p * Kp + coff + k;
    dh[d] = h;
    dl[d] = (f16)((x - (float)h) * 2048.0f);
}

// permuted combined bias: bp[u*4+g] = bih[g*H+u] + bhh[g*H+u]
__global__ void bias_pack(const float* __restrict__ bih, const float* __restrict__ bhh,
                          int H, float* __restrict__ bp)
{
    int idx = blockIdx.x * blockDim.x + threadIdx.x;
    if (idx >= 4 * H) return;
    int g = idx / H, u = idx - g * H;
    bp[u * 4 + g] = bih[idx] + bhh[idx];
}

// ---------------------------------------------------------------------------
// encoder recurrences
// ---------------------------------------------------------------------------
__global__ __launch_bounds__(256)
void enc_rec1(const float* __restrict__ xp, int T,
              const float* __restrict__ whh,           // [240][60]
              float* __restrict__ hbuf, float* __restrict__ cbuf,
              float* __restrict__ h1relu)
{
    __shared__ float Wt[60][240];
    __shared__ float hs[4][60];
    for (int idx = threadIdx.x; idx < 240 * 60; idx += 256) {
        int n = idx / 60, k = idx % 60;
        Wt[k][n] = whh[idx];
    }
    int wid = threadIdx.x >> 6, lane = threadIdx.x & 63;
    int b = blockIdx.x * 4 + wid;
    float h = 0.f, c = 0.f;
    if (lane < 60) {
        h = hbuf[(size_t)b * 60 + lane];
        c = cbuf[(size_t)b * 60 + lane];
        hs[wid][lane] = h;
    }
    __syncthreads();
    for (int t = 0; t < T; ++t) {
        if (lane < 60) {
            const float* xr = xp + ((size_t)t * BATCH + b) * 240;
            float gi = xr[lane], gf = xr[60 + lane], gg = xr[120 + lane], go = xr[180 + lane];
            for (int k = 0; k < 60; ++k) {
                float v = hs[wid][k];
                gi += v * Wt[k][lane];
                gf += v * Wt[k][60 + lane];
                gg += v * Wt[k][120 + lane];
                go += v * Wt[k][180 + lane];
            }
            float cn = sigm(gf) * c + sigm(gi) * tanhf(gg);
            float hn = sigm(go) * tanhf(cn);
            c = cn; h = hn;
            h1relu[((size_t)t * BATCH + b) * 60 + lane] = fmaxf(hn, 0.f);
        }
        __syncthreads();
        if (lane < 60) hs[wid][lane] = h;
        __syncthreads();
    }
    if (lane < 60) {
        hbuf[(size_t)b * 60 + lane] = h;
        cbuf[(size_t)b * 60 + lane] = c;
    }
}

__global__ __launch_bounds__(256)
void enc_rec21(const float* __restrict__ xp, int T, int t0,
               const float* __restrict__ whh,          // [80][20]
               float* __restrict__ hbuf, float* __restrict__ cbuf,
               unsigned short* __restrict__ fh, unsigned short* __restrict__ fl)
{
    __shared__ float Wt[20][80];
    __shared__ float hs[4][20];
    for (int idx = threadIdx.x; idx < 80 * 20; idx += 256) {
        int n = idx / 20, k = idx % 20;
        Wt[k][n] = whh[idx];
    }
    int wid = threadIdx.x >> 6, lane = threadIdx.x & 63;
    int b = blockIdx.x * 4 + wid;
    float h = 0.f, c = 0.f;
    if (lane < 20) {
        h = hbuf[(size_t)b * 20 + lane];
        c = cbuf[(size_t)b * 20 + lane];
        hs[wid][lane] = h;
    }
    __syncthreads();
    for (int t = 0; t < T; ++t) {
        if (lane < 20) {
            const float* xr = xp + ((size_t)t * BATCH + b) * 80;
            float gi = xr[lane], gf = xr[20 + lane], gg = xr[40 + lane], go = xr[60 + lane];
            for (int k = 0; k < 20; ++k) {
                float v = hs[wid][k];
                gi += v * Wt[k][lane];
                gf += v * Wt[k][20 + lane];
                gg += v * Wt[k][40 + lane];
                go += v * Wt[k][60 + lane];
            }
            float cn = sigm(gf) * c + sigm(gi) * tanhf(gg);
            float hn = sigm(go) * tanhf(cn);
            c = cn; h = hn;
            int col = (t0 + t) * 20 + lane;
            unsigned short hh = f2bf(hn);
            fh[(size_t)b * KPL1 + col] = hh;
            fl[(size_t)b * KPL1 + col] = f2bf(hn - bf2f(hh));
        }
        __syncthreads();
        if (lane < 20) hs[wid][lane] = h;
        __syncthreads();
    }
    if (lane < 20) {
        hbuf[(size_t)b * 20 + lane] = h;
        cbuf[(size_t)b * 20 + lane] = c;
    }
}

// ---------------------------------------------------------------------------
// decoder l3 cell for t=0
// ---------------------------------------------------------------------------
__global__ __launch_bounds__(256)
void dec_l3(const float* __restrict__ outb,
            const float* __restrict__ wih,   // [200][20]
            const float* __restrict__ whh,   // [200][50]
            const float* __restrict__ bih, const float* __restrict__ bhh,
            float* __restrict__ h_t, float* __restrict__ c_t,
            f16* __restrict__ a4)
{
    __shared__ float Wt[70][200];
    __shared__ float xin[4][70];
    for (int idx = threadIdx.x; idx < 200 * 20; idx += 256) {
        int n = idx / 20, k = idx % 20;
        Wt[k][n] = wih[idx];
    }
    for (int idx = threadIdx.x; idx < 200 * 50; idx += 256) {
        int n = idx / 50, k = idx % 50;
        Wt[20 + k][n] = whh[idx];
    }
    int wid = threadIdx.x >> 6, lane = threadIdx.x & 63;
    int b = blockIdx.x * 4 + wid;
    if (lane < 20) xin[wid][lane]      = outb[(size_t)b * 20 + lane];
    if (lane < 50) xin[wid][20 + lane] = h_t[(size_t)b * 50 + lane];
    __syncthreads();
    if (lane < 50) {
        float gi = bih[lane] + bhh[lane];
        float gf = bih[50 + lane] + bhh[50 + lane];
        float gg = bih[100 + lane] + bhh[100 + lane];
        float go = bih[150 + lane] + bhh[150 + lane];
        for (int k = 0; k < 70; ++k) {
            float v = xin[wid][k];
            gi += v * Wt[k][lane];
            gf += v * Wt[k][50 + lane];
            gg += v * Wt[k][100 + lane];
            go += v * Wt[k][150 + lane];
        }
        float cold = c_t[(size_t)b * 50 + lane];
        float cn = sigm(gf) * cold + sigm(gi) * tanhf(gg);
        float hn = sigm(go) * tanhf(cn);
        c_t[(size_t)b * 50 + lane] = cn;
        h_t[(size_t)b * 50 + lane] = hn;
        a4[(size_t)b * KP4 + lane] = (f16)hn;
    }
}

// ---------------------------------------------------------------------------
// fused down2 + l3 cell for t>=1: 8 batch rows per block
// ---------------------------------------------------------------------------
__global__ __launch_bounds__(256)
void dec_step3(const float* __restrict__ h3prev,       // [B][512] fp32
               const float* __restrict__ w2, const float* __restrict__ b2,
               const float* __restrict__ wih, const float* __restrict__ whh,
               const float* __restrict__ bih, const float* __restrict__ bhh,
               float* __restrict__ h_t, float* __restrict__ c_t,
               f16* __restrict__ a4)
{
    __shared__ float w2s[512][20];
    __shared__ float W3[70][200];
    __shared__ float h3s[8][516];
    __shared__ float xb[8][72];
    const int tid = threadIdx.x;
    const int r0 = blockIdx.x * 8;

    for (int idx = tid; idx < 20 * 512; idx += 256) {
        int n = idx / 512, k = idx - n * 512;
        w2s[k][n] = w2[idx];
    }
    for (int idx = tid; idx < 200 * 20; idx += 256) {
        int n = idx / 20, k = idx - n * 20;
        W3[k][n] = wih[idx];
    }
    for (int idx = tid; idx < 200 * 50; idx += 256) {
        int n = idx / 50, k = idx - n * 50;
        W3[20 + k][n] = whh[idx];
    }
    for (int idx = tid; idx < 8 * 512; idx += 256) {
        int r = idx >> 9, k = idx & 511;
        h3s[r][k] = h3prev[(size_t)(r0 + r) * 512 + k];
    }
    for (int idx = tid; idx < 8 * 50; idx += 256) {
        int r = idx / 50, u = idx - (idx / 50) * 50;
        xb[r][20 + u] = h_t[(size_t)(r0 + r) * 50 + u];
    }
    __syncthreads();

    if (tid < 160) {
        int r = tid / 20, n = tid - (tid / 20) * 20;
        float s = b2[n];
        for (int k = 0; k < 512; ++k) s += h3s[r][k] * w2s[k][n];
        xb[r][n] = s;
    }
    __syncthreads();

    for (int e = tid; e < 400; e += 256) {
        int r = e / 50, u = e - (e / 50) * 50;
        float gi = bih[u] + bhh[u];
        float gf = bih[50 + u] + bhh[50 + u];
        float gg = bih[100 + u] + bhh[100 + u];
        float go = bih[150 + u] + bhh[150 + u];
        for (int k = 0; k < 70; ++k) {
            float v = xb[r][k];
            gi += v * W3[k][u];
            gf += v * W3[k][50 + u];
            gg += v * W3[k][100 + u];
            go += v * W3[k][150 + u];
        }
        size_t ci = (size_t)(r0 + r) * 50 + u;
        float cn = sigm(gf) * c_t[ci] + sigm(gi) * tanhf(gg);
        float hn = sigm(go) * tanhf(cn);
        c_t[ci] = cn;
        h_t[ci] = hn;
        a4[(size_t)(r0 + r) * KP4 + u] = (f16)hn;
    }
}

// ---------------------------------------------------------------------------
extern "C" void kernel_launch(void* const* d_in, const int* in_sizes, int n_in,
                              void* d_out_v, int out_size, void* d_ws, size_t ws_size,
                              hipStream_t stream)
{
    const float* x        = (const float*)d_in[0];
    const float* fc1_wih  = (const float*)d_in[1];
    const float* fc1_whh  = (const float*)d_in[2];
    const float* fc1_bih  = (const float*)d_in[3];
    const float* fc1_bhh  = (const float*)d_in[4];
    const float* fc21_wih = (const float*)d_in[5];
    const float* fc21_whh = (const float*)d_in[6];
    const float* fc21_bih = (const float*)d_in[7];
    const float* fc21_bhh = (const float*)d_in[8];
    const float* lin1_w   = (const float*)d_in[9];
    const float* lin1_b   = (const float*)d_in[10];
    const float* lin2_w   = (const float*)d_in[11];
    const float* lin2_b   = (const float*)d_in[12];
    const float* idlin_w  = (const float*)d_in[13];
    const float* idlin_b  = (const float*)d_in[14];
    const float* down1_w  = (const float*)d_in[15];
    const float* down1_b  = (const float*)d_in[16];
    const float* down2_w  = (const float*)d_in[17];
    const float* down2_b  = (const float*)d_in[18];
    const float* l3_wih   = (const float*)d_in[19];
    const float* l3_whh   = (const float*)d_in[20];
    const float* l3_bih   = (const float*)d_in[21];
    const float* l3_bhh   = (const float*)d_in[22];
    const float* l4_wih   = (const float*)d_in[23];
    const float* l4_whh   = (const float*)d_in[24];
    const float* l4_bih   = (const float*)d_in[25];
    const float* l4_bhh   = (const float*)d_in[26];
    const float* l5_wih   = (const float*)d_in[27];
    const float* l5_whh   = (const float*)d_in[28];
    const float* l5_bih   = (const float*)d_in[29];
    const float* l5_bhh   = (const float*)d_in[30];
    float* out = (float*)d_out_v;

    char* base = (char*)d_ws;
    size_t off = 0;
    auto alloc = [&](size_t bytes) -> void* {
        off = (off + 255) & ~(size_t)255;
        void* p = base + off;
        off += bytes;
        return p;
    };

    // --- zero-init 16-bit region ---
    size_t us_begin = (off + 255) & ~(size_t)255;
    f16* W4h = (f16*)alloc((size_t)3200 * KP4 * 2);
    f16* W4l = (f16*)alloc((size_t)3200 * KP4 * 2);
    f16* W5h = (f16*)alloc((size_t)2048 * KP5 * 2);
    f16* W5l = (f16*)alloc((size_t)2048 * KP5 * 2);
    unsigned short* L1h = (unsigned short*)alloc((size_t)896 * KPL1 * 2);
    unsigned short* L1l = (unsigned short*)alloc((size_t)896 * KPL1 * 2);
    unsigned short* Fh  = (unsigned short*)alloc((size_t)BATCH * KPL1 * 2);
    unsigned short* Fl  = (unsigned short*)alloc((size_t)BATCH * KPL1 * 2);
    f16* A4[2]; f16* A5[2];
    for (int p = 0; p < 2; ++p) {
        A4[p] = (f16*)alloc((size_t)BATCH * KP4 * 2);
        A5[p] = (f16*)alloc((size_t)BATCH * KP5 * 2);
    }
    size_t us_end = off;

    // --- zero-init fp32 region ---
    size_t fz_begin = (off + 255) & ~(size_t)255;
    float* c2   = (float*)alloc((size_t)BATCH * MID_O * 4);
    float* c3   = (float*)alloc((size_t)BATCH * OUT_DIM * 4);
    float* hb1  = (float*)alloc((size_t)BATCH * MID_I * 4);
    float* cb1  = (float*)alloc((size_t)BATCH * MID_I * 4);
    float* hb21 = (float*)alloc((size_t)BATCH * LATENT * 4);
    float* cb21 = (float*)alloc((size_t)BATCH * LATENT * 4);
    size_t fz_end = off;

    // --- no-init buffers ---
    float* bp4   = (float*)alloc((size_t)4 * MID_O * 4);
    float* bp5   = (float*)alloc((size_t)4 * OUT_DIM * 4);
    float* mu1   = (float*)alloc((size_t)BATCH * V_MID * 4);
    float* mu    = (float*)alloc((size_t)BATCH * V_LAT * 4);
    float* h_t   = (float*)alloc((size_t)BATCH * V_LAT * 4);
    float* c_t   = (float*)alloc((size_t)BATCH * V_LAT * 4);
    float* outb  = (float*)alloc((size_t)BATCH * LATENT * 4);
    const int CH = 20;
    float* xp1c  = (float*)alloc((size_t)CH * BATCH * 4 * MID_I * 4);
    float* h1rc  = (float*)alloc((size_t)CH * BATCH * MID_I * 4);
    float* xp21c = (float*)alloc((size_t)CH * BATCH * 4 * LATENT * 4);

    hipMemsetAsync(base + us_begin, 0, us_end - us_begin, stream);
    hipMemsetAsync(base + fz_begin, 0, fz_end - fz_begin, stream);

    // --- weight/bias packing ---
    split_pack_f16<<<(3200 * 50  + 255) / 256, 256, 0, stream>>>(l4_wih, 3200 * 50,  50,  KP4, 0,   800, W4h, W4l);
    split_pack_f16<<<(3200 * 800 + 255) / 256, 256, 0, stream>>>(l4_whh, 3200 * 800, 800, KP4, 64,  800, W4h, W4l);
    split_pack_f16<<<(2048 * 800 + 255) / 256, 256, 0, stream>>>(l5_wih, 2048 * 800, 800, KP5, 0,   512, W5h, W5l);
    split_pack_f16<<<(2048 * 512 + 255) / 256, 256, 0, stream>>>(l5_whh, 2048 * 512, 512, KP5, 832, 512, W5h, W5l);
    split_pack_lin1<<<(V_MID * LATENT * SEQ + 255) / 256, 256, 0, stream>>>(lin1_w, L1h, L1l);
    bias_pack<<<(4 * MID_O   + 255) / 256, 256, 0, stream>>>(l4_bih, l4_bhh, MID_O,   bp4);
    bias_pack<<<(4 * OUT_DIM + 255) / 256, 256, 0, stream>>>(l5_bih, l5_bhh, OUT_DIM, bp5);

    // ---------------- encoder ----------------
    for (int c0 = 0; c0 < SEQ; c0 += CH) {
        {
            dim3 g((4 * MID_I + BN - 1) / BN, CH * BATCH / BM);
            gemm2k<false, false><<<g, 256, 0, stream>>>(
                x + (size_t)c0 * BATCH * IN_DIM, IN_DIM, nullptr, 0,
                fc1_wih, nullptr, fc1_bih, fc1_bhh, xp1c, CH * BATCH, 4 * MID_I);
        }
        enc_rec1<<<BATCH / 4, 256, 0, stream>>>(xp1c, CH, fc1_whh, hb1, cb1, h1rc);
        {
            dim3 g((4 * LATENT + BN - 1) / BN, CH * BATCH / BM);
            gemm2k<false, false><<<g, 256, 0, stream>>>(
                h1rc, MID_I, nullptr, 0,
                fc21_wih, nullptr, fc21_bih, fc21_bhh, xp21c, CH * BATCH, 4 * LATENT);
        }
        enc_rec21<<<BATCH / 4, 256, 0, stream>>>(xp21c, CH, c0, fc21_whh, hb21, cb21, Fh, Fl);
    }

    // lin1 (bf16 3-term MFMA) + lin2 (fp32)
    {
        dim3 g(7, 16);
        gemm_lin1<<<g, 256, 0, stream>>>(Fh, Fl, L1h, L1l, KPL1, V_MID, lin1_b, mu1);
    }
    {
        dim3 g((V_LAT + BN - 1) / BN, BATCH / BM);
        gemm2k<false, true><<<g, 256, 0, stream>>>(mu1, V_MID, nullptr, 0,
            lin2_w, nullptr, lin2_b, nullptr, mu, BATCH, V_LAT);
    }

    // ---------------- decoder init ----------------
    hipMemcpyAsync(h_t, mu, (size_t)BATCH * V_LAT * 4, hipMemcpyDeviceToDevice, stream);
    {
        dim3 g(1, BATCH / BM);
        gemm2k<false, false><<<g, 256, 0, stream>>>(mu, V_LAT, nullptr, 0,
            idlin_w, nullptr, idlin_b, nullptr, c_t, BATCH, V_LAT);
        gemm2k<false, false><<<g, 256, 0, stream>>>(mu, V_LAT, nullptr, 0,
            down1_w, nullptr, down1_b, nullptr, outb, BATCH, LATENT);
    }

    // ---------------- decoder scan ----------------
    for (int t = 0; t < SEQ; ++t) {
        const int p = t & 1;
        if (t == 0) {
            dec_l3<<<BATCH / 4, 256, 0, stream>>>(outb, l3_wih, l3_whh, l3_bih, l3_bhh,
                                                  h_t, c_t, A4[0]);
        } else {
            dec_step3<<<BATCH / 8, 256, 0, stream>>>(
                out + (size_t)(t - 1) * BATCH * OUT_DIM,
                down2_w, down2_b, l3_wih, l3_whh, l3_bih, l3_bhh,
                h_t, c_t, A4[p]);
        }
        {
            dim3 g(25, 8);   // N=3200 / 128, M=2048 / 256
            gemm_dec<1><<<g, 512, 0, stream>>>(
                A4[p], W4h, W4l, KP4, KP4 / 32, MID_O, bp4, c2,
                A4[p ^ 1], KP4, 64,
                A5[p], KP5, 0,
                nullptr);
        }
        {
            dim3 g(16, 8);   // N=2048 / 128, M=2048 / 256
            gemm_dec<2><<<g, 512, 0, stream>>>(
                A5[p], W5h, W5l, KP5, KP5 / 32, OUT_DIM, bp5, c3,
                A5[p ^ 1], KP5, 832,
                nullptr, 0, 0,
                out + (size_t)t * BATCH * OUT_DIM);
        }
    }

    hipMemcpyAsync(out + (size_t)SEQ * BATCH * OUT_DIM, mu,
                   (size_t)BATCH * V_LAT * 4, hipMemcpyDeviceToDevice, stream);
}

// Round 5
// 9878.330 us; speedup vs baseline: 7.3642x; 1.2054x over previous
//
#include <hip/hip_runtime.h>
#include <cstdint>
#include <cstddef>

#define SEQ     100
#define BATCH   2048
#define IN_DIM  64
#define MID_I   60
#define LATENT  20
#define V_MID   800
#define V_LAT   50
#define MID_O   800
#define OUT_DIM 512

#define KP4  896    // [h_t pad 64 | h2 800 | pad to 896]
#define KP5  1344   // [h2 800 pad 832 | h3 512]
#define KPL1 2048   // latent*seq 2000 padded

using f32x4  = __attribute__((ext_vector_type(4))) float;
using u16x8  = __attribute__((ext_vector_type(8))) unsigned short;
using bf16x8 = __attribute__((ext_vector_type(8))) __bf16;
typedef _Float16 f16;
typedef _Float16 f16x8 __attribute__((ext_vector_type(8)));

__device__ __forceinline__ unsigned short f2bf(float x){
    unsigned u = __builtin_bit_cast(unsigned, x);
    u += 0x7FFFu + ((u >> 16) & 1u);
    return (unsigned short)(u >> 16);
}
__device__ __forceinline__ float bf2f(unsigned short b){
    unsigned u = ((unsigned)b) << 16; return __builtin_bit_cast(float, u);
}
__device__ __forceinline__ float sigm(float x){ return 1.f/(1.f+expf(-x)); }

typedef const __attribute__((address_space(1))) unsigned int* gas_ptr;
typedef __attribute__((address_space(3))) unsigned int* las_ptr;
__device__ __forceinline__ void gld16(const void* g, char* l) {
    __builtin_amdgcn_global_load_lds((gas_ptr)g, (las_ptr)l, 16, 0, 0);
}

// ---------------------------------------------------------------------------
// fp32 tiled GEMM (encoder x-projections, lin2, decoder init)
// ---------------------------------------------------------------------------
constexpr int BM = 64, BN = 64, BK = 16;
template<bool RELU_A1, bool RELU_OUT>
__global__ __launch_bounds__(256)
void gemm2k(const float* __restrict__ A1, int K1,
            const float* __restrict__ A2, int K2,
            const float* __restrict__ W1, const float* __restrict__ W2,
            const float* __restrict__ b1, const float* __restrict__ b2,
            float* __restrict__ C, int M, int N)
{
    __shared__ float As[BK][BM + 1];
    __shared__ float Bs[BK][BN + 1];
    const int tx = threadIdx.x & 15;
    const int ty = threadIdx.x >> 4;
    const int n0 = blockIdx.x * BN;
    const int m0 = blockIdx.y * BM;

    float acc[4][4] = {};

    for (int src = 0; src < 2; ++src) {
        const float* A = src ? A2 : A1;
        const float* W = src ? W2 : W1;
        const int    K = src ? K2 : K1;
        if (A == nullptr || K == 0) continue;
        for (int k0 = 0; k0 < K; k0 += BK) {
            #pragma unroll
            for (int i = 0; i < 4; ++i) {
                int idx = threadIdx.x + i * 256;
                int k = idx & 15, m = idx >> 4;
                int gm = m0 + m, gk = k0 + k;
                float v = 0.f;
                if (gm < M && gk < K) v = A[(size_t)gm * K + gk];
                if (RELU_A1 && src == 0) v = fmaxf(v, 0.f);
                As[k][m] = v;
            }
            #pragma unroll
            for (int i = 0; i < 4; ++i) {
                int idx = threadIdx.x + i * 256;
                int k = idx & 15, n = idx >> 4;
                int gn = n0 + n, gk = k0 + k;
                float v = 0.f;
                if (gn < N && gk < K) v = W[(size_t)gn * K + gk];
                Bs[k][n] = v;
            }
            __syncthreads();
            #pragma unroll
            for (int kk = 0; kk < BK; ++kk) {
                float a[4], b[4];
                #pragma unroll
                for (int i = 0; i < 4; ++i) a[i] = As[kk][ty + i * 16];
                #pragma unroll
                for (int j = 0; j < 4; ++j) b[j] = Bs[kk][tx + j * 16];
                #pragma unroll
                for (int i = 0; i < 4; ++i)
                    #pragma unroll
                    for (int j = 0; j < 4; ++j)
                        acc[i][j] += a[i] * b[j];
            }
            __syncthreads();
        }
    }

    #pragma unroll
    for (int i = 0; i < 4; ++i) {
        int gm = m0 + ty + i * 16;
        if (gm >= M) continue;
        #pragma unroll
        for (int j = 0; j < 4; ++j) {
            int gn = n0 + tx + j * 16;
            if (gn >= N) continue;
            float v = acc[i][j];
            if (b1) v += b1[gn];
            if (b2) v += b2[gn];
            if (RELU_OUT) v = fmaxf(v, 0.f);
            C[(size_t)gm * N + gn] = v;
        }
    }
}

// ---------------------------------------------------------------------------
// lin1: split-bf16 3-term MFMA GEMM, 128x128 tile, plain store + relu
// ---------------------------------------------------------------------------
__global__ __launch_bounds__(256, 2)
void gemm_lin1(const unsigned short* __restrict__ Ah, const unsigned short* __restrict__ Al,
               const unsigned short* __restrict__ Bh, const unsigned short* __restrict__ Bl,
               int Kp, int Nstore, const float* __restrict__ bi, float* __restrict__ Cout)
{
    __shared__ __align__(16) char smem[32768];
    const int tid  = threadIdx.x;
    const int lane = tid & 63;
    const int wid  = tid >> 6;
    const int m0   = blockIdx.y * 128;
    const int n0   = blockIdx.x * 128;
    const int wr   = (wid >> 1) << 6;
    const int wc   = (wid & 1) << 6;
    const int fr   = lane & 15;
    const int fg   = lane >> 4;
    const int slotR = ((fg ^ (fr & 3)) << 4);

    const int r0 = 32 * wid + (lane >> 2);
    const int sl = (((lane & 3) ^ ((lane >> 2) & 3)) << 3);
    const unsigned short* gA0h = Ah + (size_t)(m0 + r0)      * Kp + sl;
    const unsigned short* gA1h = Ah + (size_t)(m0 + r0 + 16) * Kp + sl;
    const unsigned short* gA0l = Al + (size_t)(m0 + r0)      * Kp + sl;
    const unsigned short* gA1l = Al + (size_t)(m0 + r0 + 16) * Kp + sl;
    const unsigned short* gB0h = Bh + (size_t)(n0 + r0)      * Kp + sl;
    const unsigned short* gB1h = Bh + (size_t)(n0 + r0 + 16) * Kp + sl;
    const unsigned short* gB0l = Bl + (size_t)(n0 + r0)      * Kp + sl;
    const unsigned short* gB1l = Bl + (size_t)(n0 + r0 + 16) * Kp + sl;
    char* lA0h = smem +     0 + (2 * wid    ) * 1024;
    char* lA1h = smem +     0 + (2 * wid + 1) * 1024;
    char* lA0l = smem +  8192 + (2 * wid    ) * 1024;
    char* lA1l = smem +  8192 + (2 * wid + 1) * 1024;
    char* lB0h = smem + 16384 + (2 * wid    ) * 1024;
    char* lB1h = smem + 16384 + (2 * wid + 1) * 1024;
    char* lB0l = smem + 24576 + (2 * wid    ) * 1024;
    char* lB1l = smem + 24576 + (2 * wid + 1) * 1024;

    f32x4 acc[4][4];
    #pragma unroll
    for (int i = 0; i < 4; ++i)
        #pragma unroll
        for (int j = 0; j < 4; ++j) acc[i][j] = (f32x4){0.f, 0.f, 0.f, 0.f};

    for (int k0 = 0; k0 < Kp; k0 += 32) {
        __syncthreads();
        gld16(gA0h + k0, lA0h); gld16(gA1h + k0, lA1h);
        gld16(gA0l + k0, lA0l); gld16(gA1l + k0, lA1l);
        gld16(gB0h + k0, lB0h); gld16(gB1h + k0, lB1h);
        gld16(gB0l + k0, lB0l); gld16(gB1l + k0, lB1l);
        __syncthreads();

        bf16x8 ah[4], al[4];
        #pragma unroll
        for (int i = 0; i < 4; ++i) {
            int ro = (wr + i * 16 + fr) * 64 + slotR;
            ah[i] = *(const bf16x8*)(smem +        ro);
            al[i] = *(const bf16x8*)(smem + 8192 + ro);
        }
        #pragma unroll
        for (int j = 0; j < 4; ++j) {
            int ro = (wc + j * 16 + fr) * 64 + slotR;
            bf16x8 fbh = *(const bf16x8*)(smem + 16384 + ro);
            bf16x8 fbl = *(const bf16x8*)(smem + 24576 + ro);
            #pragma unroll
            for (int i = 0; i < 4; ++i) {
                acc[i][j] = __builtin_amdgcn_mfma_f32_16x16x32_bf16(ah[i], fbh, acc[i][j], 0, 0, 0);
                acc[i][j] = __builtin_amdgcn_mfma_f32_16x16x32_bf16(ah[i], fbl, acc[i][j], 0, 0, 0);
                acc[i][j] = __builtin_amdgcn_mfma_f32_16x16x32_bf16(al[i], fbh, acc[i][j], 0, 0, 0);
            }
        }
    }

    #pragma unroll
    for (int j = 0; j < 4; ++j) {
        int gc = n0 + wc + j * 16 + fr;
        if (gc >= Nstore) continue;
        float badd = bi[gc];
        #pragma unroll
        for (int i = 0; i < 4; ++i)
            #pragma unroll
            for (int r = 0; r < 4; ++r) {
                int gr = m0 + wr + i * 16 + fg * 4 + r;
                float v = fmaxf(acc[i][j][r] + badd, 0.f);
                Cout[(size_t)gr * Nstore + gc] = v;
            }
    }
}

// ---------------------------------------------------------------------------
// decoder GEMM: single fp16 MFMA, 256x128 tile, 8 waves, double-buffered
// global_load_lds staging, fused LSTM pointwise epilogue, XCD-aware swizzle.
// Weights gate-interleaved (row p = (n%H)*4 + n/H) -> quad-lane transpose.
// Grid = NBX*8 blocks (1-D). MODE 1 = l4, MODE 2 = l5.
// ---------------------------------------------------------------------------
template<int MODE>
__global__ __launch_bounds__(512, 4)
void gemm_dec(const f16* __restrict__ A, const f16* __restrict__ W,
              int Kp, int NK, int H, int NBX,
              const float* __restrict__ bp,     // permuted combined bias [H*4]
              float* __restrict__ cstate,
              f16* __restrict__ wr1, int st1, int off1,
              f16* __restrict__ wr2, int st2, int off2,
              float* __restrict__ out_t)
{
    __shared__ __align__(16) char smem[49152];
    // XCD-aware chunked swizzle: hardware XCD = blockIdx.x % 8; give each XCD
    // a contiguous chunk of bx-major logical order so its W-tiles stay L2-hot.
    const int q       = NBX;                           // nwg/8 = NBX (8 M-tiles)
    const int logical = (blockIdx.x & 7) * q + (blockIdx.x >> 3);
    const int bx = logical >> 3;
    const int by = logical & 7;
    const int m0 = by * 256;
    const int n0 = bx * 128;

    const int tid  = threadIdx.x;
    const int lane = tid & 63;
    const int wid  = tid >> 6;
    const int wm   = wid >> 1;         // 0..3
    const int wn   = wid & 1;          // 0..1
    const int fr   = lane & 15;
    const int fg   = lane >> 4;
    const int swz  = (fg ^ (fr & 3) ^ ((fr >> 2) & 3)) * 16;  // byte offset

    // staging addressing (linear LDS dest, pre-swizzled global source)
    const int qsrc = (lane & 3) ^ ((lane >> 2) & 3) ^ ((lane >> 4) & 3);
    const size_t loff = (size_t)(lane >> 2) * Kp + qsrc * 8;
    const int rbA0 = 32 * wid, rbA1 = 32 * wid + 16, rbW = 16 * wid;
    const f16* srcA0 = A + (size_t)(m0 + rbA0) * Kp + loff;
    const f16* srcA1 = A + (size_t)(m0 + rbA1) * Kp + loff;
    const f16* srcW  = W + (size_t)(n0 + rbW) * Kp + loff;

    f32x4 acc[4][4];
    #pragma unroll
    for (int i = 0; i < 4; ++i)
        #pragma unroll
        for (int j = 0; j < 4; ++j) acc[i][j] = (f32x4){0.f, 0.f, 0.f, 0.f};

    auto stage = [&](int buf, int t) {
        const int kb = t * 32;
        char* bb = smem + buf * 24576;
        gld16(srcA0 + kb, bb + rbA0 * 64);
        gld16(srcA1 + kb, bb + rbA1 * 64);
        gld16(srcW  + kb, bb + 16384 + rbW * 64);
    };

    stage(0, 0);
    asm volatile("s_waitcnt vmcnt(0)" ::: "memory");
    __syncthreads();

    int cur = 0;
    for (int t = 0; t < NK; ++t) {
        if (t + 1 < NK) stage(cur ^ 1, t + 1);
        const char* bb = smem + cur * 24576;
        f16x8 af[4];
        #pragma unroll
        for (int i = 0; i < 4; ++i)
            af[i] = *(const f16x8*)(bb + (64 * wm + 16 * i + fr) * 64 + swz);
        #pragma unroll
        for (int j = 0; j < 4; ++j) {
            f16x8 vw = *(const f16x8*)(bb + 16384 + (64 * wn + 16 * j + fr) * 64 + swz);
            #pragma unroll
            for (int i = 0; i < 4; ++i)
                acc[i][j] = __builtin_amdgcn_mfma_f32_16x16x32_f16(af[i], vw, acc[i][j], 0, 0, 0);
        }
        asm volatile("s_waitcnt vmcnt(0)" ::: "memory");
        __syncthreads();
        cur ^= 1;
    }

    // -------- epilogue: quad-lane 4x4 transpose -> LSTM pointwise --------
    const int q4  = lane & 3;
    const bool qb0 = (lane & 1) != 0;
    const bool qb1 = (lane & 2) != 0;
    const int ubase = (n0 >> 2) + 16 * wn;
    const f32x4* bp4 = (const f32x4*)bp;

    #pragma unroll
    for (int i = 0; i < 4; ++i) {
        #pragma unroll
        for (int j = 0; j < 4; ++j) {
            float v0 = acc[i][j][0];
            float v1 = acc[i][j][1];
            float v2 = acc[i][j][2];
            float v3 = acc[i][j][3];
            // stage A: swap lane-bit0 with reg-bit0
            {
                float s0 = qb0 ? v0 : v1;
                float s1 = qb0 ? v2 : v3;
                float r0 = __shfl_xor(s0, 1);
                float r1 = __shfl_xor(s1, 1);
                if (!qb0) { v1 = r0; v3 = r1; } else { v0 = r0; v2 = r1; }
            }
            // stage B: swap lane-bit1 with reg-bit1
            {
                float s0 = qb1 ? v0 : v2;
                float s1 = qb1 ? v1 : v3;
                float r0 = __shfl_xor(s0, 2);
                float r1 = __shfl_xor(s1, 2);
                if (!qb1) { v2 = r0; v3 = r1; } else { v0 = r0; v1 = r1; }
            }
            // now v0..v3 = gates i,f,g,o of (row, unit) for this lane
            const int unit = ubase + 4 * j + (fr >> 2);
            const int row  = m0 + 64 * wm + 16 * i + 4 * fg + q4;
            f32x4 bv = bp4[unit];
            float gi = v0 + bv[0], gf = v1 + bv[1], gg = v2 + bv[2], go = v3 + bv[3];
            size_t ci = (size_t)row * H + unit;
            float cn = sigm(gf) * cstate[ci] + sigm(gi) * tanhf(gg);
            float hn = sigm(go) * tanhf(cn);
            cstate[ci] = cn;
            f16 hh = (f16)hn;
            wr1[(size_t)row * st1 + off1 + unit] = hh;
            if (MODE == 1) wr2[(size_t)row * st2 + off2 + unit] = hh;
            if (MODE == 2) out_t[(size_t)row * H + unit] = hn;
        }
    }
}

// ---------------------------------------------------------------------------
// packing kernels
// ---------------------------------------------------------------------------
// bf16 hi/lo (lin1 path)
__global__ void split_pack_lin1(const float* __restrict__ src,
                                unsigned short* __restrict__ dh, unsigned short* __restrict__ dl)
{
    int idx = blockIdx.x * blockDim.x + threadIdx.x;
    if (idx >= V_MID * LATENT * SEQ) return;
    int n = idx / (LATENT * SEQ), c = idx - n * (LATENT * SEQ);
    int l = c / SEQ, s = c - l * SEQ;
    float x = src[idx];
    unsigned short h = f2bf(x);
    size_t d = (size_t)n * KPL1 + s * LATENT + l;
    dh[d] = h;
    dl[d] = f2bf(x - bf2f(h));
}

// fp16 weight pack, gate-interleaved rows p=(n%HU)*4+n/HU
__global__ void pack_f16(const float* __restrict__ src, int total, int K, int Kp,
                         int coff, int HU, f16* __restrict__ dh)
{
    int idx = blockIdx.x * blockDim.x + threadIdx.x;
    if (idx >= total) return;
    int n = idx / K, k = idx - n * K;
    int p = (n % HU) * 4 + n / HU;
    dh[(size_t)p * Kp + coff + k] = (f16)src[idx];
}

// permuted combined bias: bp[u*4+g] = bih[g*H+u] + bhh[g*H+u]
__global__ void bias_pack(const float* __restrict__ bih, const float* __restrict__ bhh,
                          int H, float* __restrict__ bp)
{
    int idx = blockIdx.x * blockDim.x + threadIdx.x;
    if (idx >= 4 * H) return;
    int g = idx / H, u = idx - g * H;
    bp[u * 4 + g] = bih[idx] + bhh[idx];
}

// ---------------------------------------------------------------------------
// encoder recurrences
// ---------------------------------------------------------------------------
__global__ __launch_bounds__(256)
void enc_rec1(const float* __restrict__ xp, int T,
              const float* __restrict__ whh,           // [240][60]
              float* __restrict__ hbuf, float* __restrict__ cbuf,
              float* __restrict__ h1relu)
{
    __shared__ float Wt[60][240];
    __shared__ float hs[4][60];
    for (int idx = threadIdx.x; idx < 240 * 60; idx += 256) {
        int n = idx / 60, k = idx % 60;
        Wt[k][n] = whh[idx];
    }
    int wid = threadIdx.x >> 6, lane = threadIdx.x & 63;
    int b = blockIdx.x * 4 + wid;
    float h = 0.f, c = 0.f;
    if (lane < 60) {
        h = hbuf[(size_t)b * 60 + lane];
        c = cbuf[(size_t)b * 60 + lane];
        hs[wid][lane] = h;
    }
    __syncthreads();
    for (int t = 0; t < T; ++t) {
        if (lane < 60) {
            const float* xr = xp + ((size_t)t * BATCH + b) * 240;
            float gi = xr[lane], gf = xr[60 + lane], gg = xr[120 + lane], go = xr[180 + lane];
            for (int k = 0; k < 60; ++k) {
                float v = hs[wid][k];
                gi += v * Wt[k][lane];
                gf += v * Wt[k][60 + lane];
                gg += v * Wt[k][120 + lane];
                go += v * Wt[k][180 + lane];
            }
            float cn = sigm(gf) * c + sigm(gi) * tanhf(gg);
            float hn = sigm(go) * tanhf(cn);
            c = cn; h = hn;
            h1relu[((size_t)t * BATCH + b) * 60 + lane] = fmaxf(hn, 0.f);
        }
        __syncthreads();
        if (lane < 60) hs[wid][lane] = h;
        __syncthreads();
    }
    if (lane < 60) {
        hbuf[(size_t)b * 60 + lane] = h;
        cbuf[(size_t)b * 60 + lane] = c;
    }
}

__global__ __launch_bounds__(256)
void enc_rec21(const float* __restrict__ xp, int T, int t0,
               const float* __restrict__ whh,          // [80][20]
               float* __restrict__ hbuf, float* __restrict__ cbuf,
               unsigned short* __restrict__ fh, unsigned short* __restrict__ fl)
{
    __shared__ float Wt[20][80];
    __shared__ float hs[4][20];
    for (int idx = threadIdx.x; idx < 80 * 20; idx += 256) {
        int n = idx / 20, k = idx % 20;
        Wt[k][n] = whh[idx];
    }
    int wid = threadIdx.x >> 6, lane = threadIdx.x & 63;
    int b = blockIdx.x * 4 + wid;
    float h = 0.f, c = 0.f;
    if (lane < 20) {
        h = hbuf[(size_t)b * 20 + lane];
        c = cbuf[(size_t)b * 20 + lane];
        hs[wid][lane] = h;
    }
    __syncthreads();
    for (int t = 0; t < T; ++t) {
        if (lane < 20) {
            const float* xr = xp + ((size_t)t * BATCH + b) * 80;
            float gi = xr[lane], gf = xr[20 + lane], gg = xr[40 + lane], go = xr[60 + lane];
            for (int k = 0; k < 20; ++k) {
                float v = hs[wid][k];
                gi += v * Wt[k][lane];
                gf += v * Wt[k][20 + lane];
                gg += v * Wt[k][40 + lane];
                go += v * Wt[k][60 + lane];
            }
            float cn = sigm(gf) * c + sigm(gi) * tanhf(gg);
            float hn = sigm(go) * tanhf(cn);
            c = cn; h = hn;
            int col = (t0 + t) * 20 + lane;
            unsigned short hh = f2bf(hn);
            fh[(size_t)b * KPL1 + col] = hh;
            fl[(size_t)b * KPL1 + col] = f2bf(hn - bf2f(hh));
        }
        __syncthreads();
        if (lane < 20) hs[wid][lane] = h;
        __syncthreads();
    }
    if (lane < 20) {
        hbuf[(size_t)b * 20 + lane] = h;
        cbuf[(size_t)b * 20 + lane] = c;
    }
}

// ---------------------------------------------------------------------------
// decoder l3 cell for t=0
// ---------------------------------------------------------------------------
__global__ __launch_bounds__(256)
void dec_l3(const float* __restrict__ outb,
            const float* __restrict__ wih,   // [200][20]
            const float* __restrict__ whh,   // [200][50]
            const float* __restrict__ bih, const float* __restrict__ bhh,
            float* __restrict__ h_t, float* __restrict__ c_t,
            f16* __restrict__ a4)
{
    __shared__ float Wt[70][200];
    __shared__ float xin[4][70];
    for (int idx = threadIdx.x; idx < 200 * 20; idx += 256) {
        int n = idx / 20, k = idx % 20;
        Wt[k][n] = wih[idx];
    }
    for (int idx = threadIdx.x; idx < 200 * 50; idx += 256) {
        int n = idx / 50, k = idx % 50;
        Wt[20 + k][n] = whh[idx];
    }
    int wid = threadIdx.x >> 6, lane = threadIdx.x & 63;
    int b = blockIdx.x * 4 + wid;
    if (lane < 20) xin[wid][lane]      = outb[(size_t)b * 20 + lane];
    if (lane < 50) xin[wid][20 + lane] = h_t[(size_t)b * 50 + lane];
    __syncthreads();
    if (lane < 50) {
        float gi = bih[lane] + bhh[lane];
        float gf = bih[50 + lane] + bhh[50 + lane];
        float gg = bih[100 + lane] + bhh[100 + lane];
        float go = bih[150 + lane] + bhh[150 + lane];
        for (int k = 0; k < 70; ++k) {
            float v = xin[wid][k];
            gi += v * Wt[k][lane];
            gf += v * Wt[k][50 + lane];
            gg += v * Wt[k][100 + lane];
            go += v * Wt[k][150 + lane];
        }
        float cold = c_t[(size_t)b * 50 + lane];
        float cn = sigm(gf) * cold + sigm(gi) * tanhf(gg);
        float hn = sigm(go) * tanhf(cn);
        c_t[(size_t)b * 50 + lane] = cn;
        h_t[(size_t)b * 50 + lane] = hn;
        a4[(size_t)b * KP4 + lane] = (f16)hn;
    }
}

// ---------------------------------------------------------------------------
// fused down2 + l3 cell for t>=1: 8 batch rows per block
// ---------------------------------------------------------------------------
__global__ __launch_bounds__(256)
void dec_step3(const float* __restrict__ h3prev,       // [B][512] fp32
               const float* __restrict__ w2, const float* __restrict__ b2,
               const float* __restrict__ wih, const float* __restrict__ whh,
               const float* __restrict__ bih, const float* __restrict__ bhh,
               float* __restrict__ h_t, float* __restrict__ c_t,
               f16* __restrict__ a4)
{
    __shared__ float w2s[512][20];
    __shared__ float W3[70][200];
    __shared__ float h3s[8][516];
    __shared__ float xb[8][72];
    const int tid = threadIdx.x;
    const int r0 = blockIdx.x * 8;

    for (int idx = tid; idx < 20 * 512; idx += 256) {
        int n = idx / 512, k = idx - n * 512;
        w2s[k][n] = w2[idx];
    }
    for (int idx = tid; idx < 200 * 20; idx += 256) {
        int n = idx / 20, k = idx - n * 20;
        W3[k][n] = wih[idx];
    }
    for (int idx = tid; idx < 200 * 50; idx += 256) {
        int n = idx / 50, k = idx - n * 50;
        W3[20 + k][n] = whh[idx];
    }
    for (int idx = tid; idx < 8 * 512; idx += 256) {
        int r = idx >> 9, k = idx & 511;
        h3s[r][k] = h3prev[(size_t)(r0 + r) * 512 + k];
    }
    for (int idx = tid; idx < 8 * 50; idx += 256) {
        int r = idx / 50, u = idx - (idx / 50) * 50;
        xb[r][20 + u] = h_t[(size_t)(r0 + r) * 50 + u];
    }
    __syncthreads();

    if (tid < 160) {
        int r = tid / 20, n = tid - (tid / 20) * 20;
        float s = b2[n];
        for (int k = 0; k < 512; ++k) s += h3s[r][k] * w2s[k][n];
        xb[r][n] = s;
    }
    __syncthreads();

    for (int e = tid; e < 400; e += 256) {
        int r = e / 50, u = e - (e / 50) * 50;
        float gi = bih[u] + bhh[u];
        float gf = bih[50 + u] + bhh[50 + u];
        float gg = bih[100 + u] + bhh[100 + u];
        float go = bih[150 + u] + bhh[150 + u];
        for (int k = 0; k < 70; ++k) {
            float v = xb[r][k];
            gi += v * W3[k][u];
            gf += v * W3[k][50 + u];
            gg += v * W3[k][100 + u];
            go += v * W3[k][150 + u];
        }
        size_t ci = (size_t)(r0 + r) * 50 + u;
        float cn = sigm(gf) * c_t[ci] + sigm(gi) * tanhf(gg);
        float hn = sigm(go) * tanhf(cn);
        c_t[ci] = cn;
        h_t[ci] = hn;
        a4[(size_t)(r0 + r) * KP4 + u] = (f16)hn;
    }
}

// ---------------------------------------------------------------------------
extern "C" void kernel_launch(void* const* d_in, const int* in_sizes, int n_in,
                              void* d_out_v, int out_size, void* d_ws, size_t ws_size,
                              hipStream_t stream)
{
    const float* x        = (const float*)d_in[0];
    const float* fc1_wih  = (const float*)d_in[1];
    const float* fc1_whh  = (const float*)d_in[2];
    const float* fc1_bih  = (const float*)d_in[3];
    const float* fc1_bhh  = (const float*)d_in[4];
    const float* fc21_wih = (const float*)d_in[5];
    const float* fc21_whh = (const float*)d_in[6];
    const float* fc21_bih = (const float*)d_in[7];
    const float* fc21_bhh = (const float*)d_in[8];
    const float* lin1_w   = (const float*)d_in[9];
    const float* lin1_b   = (const float*)d_in[10];
    const float* lin2_w   = (const float*)d_in[11];
    const float* lin2_b   = (const float*)d_in[12];
    const float* idlin_w  = (const float*)d_in[13];
    const float* idlin_b  = (const float*)d_in[14];
    const float* down1_w  = (const float*)d_in[15];
    const float* down1_b  = (const float*)d_in[16];
    const float* down2_w  = (const float*)d_in[17];
    const float* down2_b  = (const float*)d_in[18];
    const float* l3_wih   = (const float*)d_in[19];
    const float* l3_whh   = (const float*)d_in[20];
    const float* l3_bih   = (const float*)d_in[21];
    const float* l3_bhh   = (const float*)d_in[22];
    const float* l4_wih   = (const float*)d_in[23];
    const float* l4_whh   = (const float*)d_in[24];
    const float* l4_bih   = (const float*)d_in[25];
    const float* l4_bhh   = (const float*)d_in[26];
    const float* l5_wih   = (const float*)d_in[27];
    const float* l5_whh   = (const float*)d_in[28];
    const float* l5_bih   = (const float*)d_in[29];
    const float* l5_bhh   = (const float*)d_in[30];
    float* out = (float*)d_out_v;

    char* base = (char*)d_ws;
    size_t off = 0;
    auto alloc = [&](size_t bytes) -> void* {
        off = (off + 255) & ~(size_t)255;
        void* p = base + off;
        off += bytes;
        return p;
    };

    // --- zero-init 16-bit region ---
    size_t us_begin = (off + 255) & ~(size_t)255;
    f16* W4h = (f16*)alloc((size_t)3200 * KP4 * 2);
    f16* W5h = (f16*)alloc((size_t)2048 * KP5 * 2);
    unsigned short* L1h = (unsigned short*)alloc((size_t)896 * KPL1 * 2);
    unsigned short* L1l = (unsigned short*)alloc((size_t)896 * KPL1 * 2);
    unsigned short* Fh  = (unsigned short*)alloc((size_t)BATCH * KPL1 * 2);
    unsigned short* Fl  = (unsigned short*)alloc((size_t)BATCH * KPL1 * 2);
    f16* A4[2]; f16* A5[2];
    for (int p = 0; p < 2; ++p) {
        A4[p] = (f16*)alloc((size_t)BATCH * KP4 * 2);
        A5[p] = (f16*)alloc((size_t)BATCH * KP5 * 2);
    }
    size_t us_end = off;

    // --- zero-init fp32 region ---
    size_t fz_begin = (off + 255) & ~(size_t)255;
    float* c2   = (float*)alloc((size_t)BATCH * MID_O * 4);
    float* c3   = (float*)alloc((size_t)BATCH * OUT_DIM * 4);
    float* hb1  = (float*)alloc((size_t)BATCH * MID_I * 4);
    float* cb1  = (float*)alloc((size_t)BATCH * MID_I * 4);
    float* hb21 = (float*)alloc((size_t)BATCH * LATENT * 4);
    float* cb21 = (float*)alloc((size_t)BATCH * LATENT * 4);
    size_t fz_end = off;

    // --- no-init buffers ---
    float* bp4   = (float*)alloc((size_t)4 * MID_O * 4);
    float* bp5   = (float*)alloc((size_t)4 * OUT_DIM * 4);
    float* mu1   = (float*)alloc((size_t)BATCH * V_MID * 4);
    float* mu    = (float*)alloc((size_t)BATCH * V_LAT * 4);
    float* h_t   = (float*)alloc((size_t)BATCH * V_LAT * 4);
    float* c_t   = (float*)alloc((size_t)BATCH * V_LAT * 4);
    float* outb  = (float*)alloc((size_t)BATCH * LATENT * 4);
    const int CH = 20;
    float* xp1c  = (float*)alloc((size_t)CH * BATCH * 4 * MID_I * 4);
    float* h1rc  = (float*)alloc((size_t)CH * BATCH * MID_I * 4);
    float* xp21c = (float*)alloc((size_t)CH * BATCH * 4 * LATENT * 4);

    hipMemsetAsync(base + us_begin, 0, us_end - us_begin, stream);
    hipMemsetAsync(base + fz_begin, 0, fz_end - fz_begin, stream);

    // --- weight/bias packing ---
    pack_f16<<<(3200 * 50  + 255) / 256, 256, 0, stream>>>(l4_wih, 3200 * 50,  50,  KP4, 0,   800, W4h);
    pack_f16<<<(3200 * 800 + 255) / 256, 256, 0, stream>>>(l4_whh, 3200 * 800, 800, KP4, 64,  800, W4h);
    pack_f16<<<(2048 * 800 + 255) / 256, 256, 0, stream>>>(l5_wih, 2048 * 800, 800, KP5, 0,   512, W5h);
    pack_f16<<<(2048 * 512 + 255) / 256, 256, 0, stream>>>(l5_whh, 2048 * 512, 512, KP5, 832, 512, W5h);
    split_pack_lin1<<<(V_MID * LATENT * SEQ + 255) / 256, 256, 0, stream>>>(lin1_w, L1h, L1l);
    bias_pack<<<(4 * MID_O   + 255) / 256, 256, 0, stream>>>(l4_bih, l4_bhh, MID_O,   bp4);
    bias_pack<<<(4 * OUT_DIM + 255) / 256, 256, 0, stream>>>(l5_bih, l5_bhh, OUT_DIM, bp5);

    // ---------------- encoder ----------------
    for (int c0 = 0; c0 < SEQ; c0 += CH) {
        {
            dim3 g((4 * MID_I + BN - 1) / BN, CH * BATCH / BM);
            gemm2k<false, false><<<g, 256, 0, stream>>>(
                x + (size_t)c0 * BATCH * IN_DIM, IN_DIM, nullptr, 0,
                fc1_wih, nullptr, fc1_bih, fc1_bhh, xp1c, CH * BATCH, 4 * MID_I);
        }
        enc_rec1<<<BATCH / 4, 256, 0, stream>>>(xp1c, CH, fc1_whh, hb1, cb1, h1rc);
        {
            dim3 g((4 * LATENT + BN - 1) / BN, CH * BATCH / BM);
            gemm2k<false, false><<<g, 256, 0, stream>>>(
                h1rc, MID_I, nullptr, 0,
                fc21_wih, nullptr, fc21_bih, fc21_bhh, xp21c, CH * BATCH, 4 * LATENT);
        }
        enc_rec21<<<BATCH / 4, 256, 0, stream>>>(xp21c, CH, c0, fc21_whh, hb21, cb21, Fh, Fl);
    }

    // lin1 (bf16 3-term MFMA) + lin2 (fp32)
    {
        dim3 g(7, 16);
        gemm_lin1<<<g, 256, 0, stream>>>(Fh, Fl, L1h, L1l, KPL1, V_MID, lin1_b, mu1);
    }
    {
        dim3 g((V_LAT + BN - 1) / BN, BATCH / BM);
        gemm2k<false, true><<<g, 256, 0, stream>>>(mu1, V_MID, nullptr, 0,
            lin2_w, nullptr, lin2_b, nullptr, mu, BATCH, V_LAT);
    }

    // ---------------- decoder init ----------------
    hipMemcpyAsync(h_t, mu, (size_t)BATCH * V_LAT * 4, hipMemcpyDeviceToDevice, stream);
    {
        dim3 g(1, BATCH / BM);
        gemm2k<false, false><<<g, 256, 0, stream>>>(mu, V_LAT, nullptr, 0,
            idlin_w, nullptr, idlin_b, nullptr, c_t, BATCH, V_LAT);
        gemm2k<false, false><<<g, 256, 0, stream>>>(mu, V_LAT, nullptr, 0,
            down1_w, nullptr, down1_b, nullptr, outb, BATCH, LATENT);
    }

    // ---------------- decoder scan ----------------
    for (int t = 0; t < SEQ; ++t) {
        const int p = t & 1;
        if (t == 0) {
            dec_l3<<<BATCH / 4, 256, 0, stream>>>(outb, l3_wih, l3_whh, l3_bih, l3_bhh,
                                                  h_t, c_t, A4[0]);
        } else {
            dec_step3<<<BATCH / 8, 256, 0, stream>>>(
                out + (size_t)(t - 1) * BATCH * OUT_DIM,
                down2_w, down2_b, l3_wih, l3_whh, l3_bih, l3_bhh,
                h_t, c_t, A4[p]);
        }
        {
            // N=3200 -> 25 col-tiles, 8 row-tiles
            gemm_dec<1><<<dim3(200), 512, 0, stream>>>(
                A4[p], W4h, KP4, KP4 / 32, MID_O, 25, bp4, c2,
                A4[p ^ 1], KP4, 64,
                A5[p], KP5, 0,
                nullptr);
        }
        {
            // N=2048 -> 16 col-tiles, 8 row-tiles
            gemm_dec<2><<<dim3(128), 512, 0, stream>>>(
                A5[p], W5h, KP5, KP5 / 32, OUT_DIM, 16, bp5, c3,
                A5[p ^ 1], KP5, 832,
                nullptr, 0, 0,
                out + (size_t)t * BATCH * OUT_DIM);
        }
    }

    hipMemcpyAsync(out + (size_t)SEQ * BATCH * OUT_DIM, mu,
                   (size_t)BATCH * V_LAT * 4, hipMemcpyDeviceToDevice, stream);
}

// Round 6
// 8883.629 us; speedup vs baseline: 8.1888x; 1.1120x over previous
//
#include <hip/hip_runtime.h>
#include <cstdint>
#include <cstddef>

#define SEQ     100
#define BATCH   2048
#define IN_DIM  64
#define MID_I   60
#define LATENT  20
#define V_MID   800
#define V_LAT   50
#define MID_O   800
#define OUT_DIM 512

#define KP4  896    // [h_t pad 64 | h2 800 | pad to 896]
#define KP5  1344   // [h2 800 pad 832 | h3 512]
#define KPL1 2048   // latent*seq 2000 padded

using f32x4  = __attribute__((ext_vector_type(4))) float;
using u16x8  = __attribute__((ext_vector_type(8))) unsigned short;
using bf16x8 = __attribute__((ext_vector_type(8))) __bf16;
typedef _Float16 f16;
typedef _Float16 f16x8 __attribute__((ext_vector_type(8)));

__device__ __forceinline__ unsigned short f2bf(float x){
    unsigned u = __builtin_bit_cast(unsigned, x);
    u += 0x7FFFu + ((u >> 16) & 1u);
    return (unsigned short)(u >> 16);
}
__device__ __forceinline__ float bf2f(unsigned short b){
    unsigned u = ((unsigned)b) << 16; return __builtin_bit_cast(float, u);
}
__device__ __forceinline__ float sigm(float x){ return 1.f/(1.f+expf(-x)); }

typedef const __attribute__((address_space(1))) unsigned int* gas_ptr;
typedef __attribute__((address_space(3))) unsigned int* las_ptr;
__device__ __forceinline__ void gld16(const void* g, char* l) {
    __builtin_amdgcn_global_load_lds((gas_ptr)g, (las_ptr)l, 16, 0, 0);
}

// ---------------------------------------------------------------------------
// fp32 tiled GEMM (encoder x-projections, lin2, decoder init)
// ---------------------------------------------------------------------------
constexpr int BM = 64, BN = 64, BK = 16;
template<bool RELU_A1, bool RELU_OUT>
__global__ __launch_bounds__(256)
void gemm2k(const float* __restrict__ A1, int K1,
            const float* __restrict__ A2, int K2,
            const float* __restrict__ W1, const float* __restrict__ W2,
            const float* __restrict__ b1, const float* __restrict__ b2,
            float* __restrict__ C, int M, int N)
{
    __shared__ float As[BK][BM + 1];
    __shared__ float Bs[BK][BN + 1];
    const int tx = threadIdx.x & 15;
    const int ty = threadIdx.x >> 4;
    const int n0 = blockIdx.x * BN;
    const int m0 = blockIdx.y * BM;

    float acc[4][4] = {};

    for (int src = 0; src < 2; ++src) {
        const float* A = src ? A2 : A1;
        const float* W = src ? W2 : W1;
        const int    K = src ? K2 : K1;
        if (A == nullptr || K == 0) continue;
        for (int k0 = 0; k0 < K; k0 += BK) {
            #pragma unroll
            for (int i = 0; i < 4; ++i) {
                int idx = threadIdx.x + i * 256;
                int k = idx & 15, m = idx >> 4;
                int gm = m0 + m, gk = k0 + k;
                float v = 0.f;
                if (gm < M && gk < K) v = A[(size_t)gm * K + gk];
                if (RELU_A1 && src == 0) v = fmaxf(v, 0.f);
                As[k][m] = v;
            }
            #pragma unroll
            for (int i = 0; i < 4; ++i) {
                int idx = threadIdx.x + i * 256;
                int k = idx & 15, n = idx >> 4;
                int gn = n0 + n, gk = k0 + k;
                float v = 0.f;
                if (gn < N && gk < K) v = W[(size_t)gn * K + gk];
                Bs[k][n] = v;
            }
            __syncthreads();
            #pragma unroll
            for (int kk = 0; kk < BK; ++kk) {
                float a[4], b[4];
                #pragma unroll
                for (int i = 0; i < 4; ++i) a[i] = As[kk][ty + i * 16];
                #pragma unroll
                for (int j = 0; j < 4; ++j) b[j] = Bs[kk][tx + j * 16];
                #pragma unroll
                for (int i = 0; i < 4; ++i)
                    #pragma unroll
                    for (int j = 0; j < 4; ++j)
                        acc[i][j] += a[i] * b[j];
            }
            __syncthreads();
        }
    }

    #pragma unroll
    for (int i = 0; i < 4; ++i) {
        int gm = m0 + ty + i * 16;
        if (gm >= M) continue;
        #pragma unroll
        for (int j = 0; j < 4; ++j) {
            int gn = n0 + tx + j * 16;
            if (gn >= N) continue;
            float v = acc[i][j];
            if (b1) v += b1[gn];
            if (b2) v += b2[gn];
            if (RELU_OUT) v = fmaxf(v, 0.f);
            C[(size_t)gm * N + gn] = v;
        }
    }
}

// ---------------------------------------------------------------------------
// lin1: split-bf16 3-term MFMA GEMM, 128x128 tile, plain store + relu
// ---------------------------------------------------------------------------
__global__ __launch_bounds__(256, 2)
void gemm_lin1(const unsigned short* __restrict__ Ah, const unsigned short* __restrict__ Al,
               const unsigned short* __restrict__ Bh, const unsigned short* __restrict__ Bl,
               int Kp, int Nstore, const float* __restrict__ bi, float* __restrict__ Cout)
{
    __shared__ __align__(16) char smem[32768];
    const int tid  = threadIdx.x;
    const int lane = tid & 63;
    const int wid  = tid >> 6;
    const int m0   = blockIdx.y * 128;
    const int n0   = blockIdx.x * 128;
    const int wr   = (wid >> 1) << 6;
    const int wc   = (wid & 1) << 6;
    const int fr   = lane & 15;
    const int fg   = lane >> 4;
    const int slotR = ((fg ^ (fr & 3)) << 4);

    const int r0 = 32 * wid + (lane >> 2);
    const int sl = (((lane & 3) ^ ((lane >> 2) & 3)) << 3);
    const unsigned short* gA0h = Ah + (size_t)(m0 + r0)      * Kp + sl;
    const unsigned short* gA1h = Ah + (size_t)(m0 + r0 + 16) * Kp + sl;
    const unsigned short* gA0l = Al + (size_t)(m0 + r0)      * Kp + sl;
    const unsigned short* gA1l = Al + (size_t)(m0 + r0 + 16) * Kp + sl;
    const unsigned short* gB0h = Bh + (size_t)(n0 + r0)      * Kp + sl;
    const unsigned short* gB1h = Bh + (size_t)(n0 + r0 + 16) * Kp + sl;
    const unsigned short* gB0l = Bl + (size_t)(n0 + r0)      * Kp + sl;
    const unsigned short* gB1l = Bl + (size_t)(n0 + r0 + 16) * Kp + sl;
    char* lA0h = smem +     0 + (2 * wid    ) * 1024;
    char* lA1h = smem +     0 + (2 * wid + 1) * 1024;
    char* lA0l = smem +  8192 + (2 * wid    ) * 1024;
    char* lA1l = smem +  8192 + (2 * wid + 1) * 1024;
    char* lB0h = smem + 16384 + (2 * wid    ) * 1024;
    char* lB1h = smem + 16384 + (2 * wid + 1) * 1024;
    char* lB0l = smem + 24576 + (2 * wid    ) * 1024;
    char* lB1l = smem + 24576 + (2 * wid + 1) * 1024;

    f32x4 acc[4][4];
    #pragma unroll
    for (int i = 0; i < 4; ++i)
        #pragma unroll
        for (int j = 0; j < 4; ++j) acc[i][j] = (f32x4){0.f, 0.f, 0.f, 0.f};

    for (int k0 = 0; k0 < Kp; k0 += 32) {
        __syncthreads();
        gld16(gA0h + k0, lA0h); gld16(gA1h + k0, lA1h);
        gld16(gA0l + k0, lA0l); gld16(gA1l + k0, lA1l);
        gld16(gB0h + k0, lB0h); gld16(gB1h + k0, lB1h);
        gld16(gB0l + k0, lB0l); gld16(gB1l + k0, lB1l);
        __syncthreads();

        bf16x8 ah[4], al[4];
        #pragma unroll
        for (int i = 0; i < 4; ++i) {
            int ro = (wr + i * 16 + fr) * 64 + slotR;
            ah[i] = *(const bf16x8*)(smem +        ro);
            al[i] = *(const bf16x8*)(smem + 8192 + ro);
        }
        #pragma unroll
        for (int j = 0; j < 4; ++j) {
            int ro = (wc + j * 16 + fr) * 64 + slotR;
            bf16x8 fbh = *(const bf16x8*)(smem + 16384 + ro);
            bf16x8 fbl = *(const bf16x8*)(smem + 24576 + ro);
            #pragma unroll
            for (int i = 0; i < 4; ++i) {
                acc[i][j] = __builtin_amdgcn_mfma_f32_16x16x32_bf16(ah[i], fbh, acc[i][j], 0, 0, 0);
                acc[i][j] = __builtin_amdgcn_mfma_f32_16x16x32_bf16(ah[i], fbl, acc[i][j], 0, 0, 0);
                acc[i][j] = __builtin_amdgcn_mfma_f32_16x16x32_bf16(al[i], fbh, acc[i][j], 0, 0, 0);
            }
        }
    }

    #pragma unroll
    for (int j = 0; j < 4; ++j) {
        int gc = n0 + wc + j * 16 + fr;
        if (gc >= Nstore) continue;
        float badd = bi[gc];
        #pragma unroll
        for (int i = 0; i < 4; ++i)
            #pragma unroll
            for (int r = 0; r < 4; ++r) {
                int gr = m0 + wr + i * 16 + fg * 4 + r;
                float v = fmaxf(acc[i][j][r] + badd, 0.f);
                Cout[(size_t)gr * Nstore + gc] = v;
            }
    }
}

// ---------------------------------------------------------------------------
// decoder GEMM: fp16 MFMA, 128x128 tile, 4 waves, 3-buffer counted-vmcnt
// pipeline (raw s_barrier, never drains in-flight prefetch), fused LSTM
// pointwise epilogue, XCD-chunked block swizzle.
// Weights gate-interleaved (row p = (n%H)*4 + n/H) -> quad-lane transpose.
// Grid = NBX*16 blocks (1-D). MODE 1 = l4, MODE 2 = l5.
// ---------------------------------------------------------------------------
template<int MODE>
__global__ __launch_bounds__(256, 3)
void gemm_dec(const f16* __restrict__ A, const f16* __restrict__ W,
              int Kp, int NK, int H, int NBX,
              const float* __restrict__ bp,     // permuted combined bias [H*4]
              float* __restrict__ cstate,
              f16* __restrict__ wr1, int st1, int off1,
              f16* __restrict__ wr2, int st2, int off2,
              float* __restrict__ out_t)
{
    __shared__ __align__(16) char smem[49152];   // 3 buffers x (A 8K + W 8K)
    const int qq      = NBX * 2;                 // blocks per XCD
    const int logical = (blockIdx.x & 7) * qq + (blockIdx.x >> 3);
    const int bx = logical >> 4;
    const int by = logical & 15;
    const int m0 = by * 128;
    const int n0 = bx * 128;

    const int tid  = threadIdx.x;
    const int lane = tid & 63;
    const int wid  = tid >> 6;         // 0..3
    const int wm   = wid >> 1;         // 0..1
    const int wn   = wid & 1;          // 0..1
    const int fr   = lane & 15;
    const int fg   = lane >> 4;
    // read-side swizzle slot (bytes): s = fg ^ (row&3) ^ ((row>>2)&1), row%16==fr
    const int swz  = (fg ^ (fr & 3) ^ ((fr >> 2) & 1)) * 16;

    // staging: each wave stages 32 A-rows and 32 W-rows (2 gld16 calls each).
    // linear LDS dest; global source chunk pre-swizzled with the same mask.
    const int rbase = 32 * wid;
    const int lrow  = lane >> 2;
    const int chnk  = (lane & 3) ^ ((lane >> 2) & 3) ^ ((lane >> 4) & 1);
    const f16* sA0 = A + (size_t)(m0 + rbase + lrow)      * Kp + chnk * 8;
    const f16* sA1 = A + (size_t)(m0 + rbase + 16 + lrow) * Kp + chnk * 8;
    const f16* sW0 = W + (size_t)(n0 + rbase + lrow)      * Kp + chnk * 8;
    const f16* sW1 = W + (size_t)(n0 + rbase + 16 + lrow) * Kp + chnk * 8;

    f32x4 acc[4][4];
    #pragma unroll
    for (int i = 0; i < 4; ++i)
        #pragma unroll
        for (int j = 0; j < 4; ++j) acc[i][j] = (f32x4){0.f, 0.f, 0.f, 0.f};

    auto stage = [&](int t, int buf) {
        const int kb = t * 32;
        char* bb = smem + buf * 16384;
        gld16(sA0 + kb, bb + rbase * 64);
        gld16(sA1 + kb, bb + (rbase + 16) * 64);
        gld16(sW0 + kb, bb + 8192 + rbase * 64);
        gld16(sW1 + kb, bb + 8192 + (rbase + 16) * 64);
    };

    stage(0, 0);
    stage(1, 1);

    int buf = 0;
    for (int t = 0; t < NK; ++t) {
        if (t + 1 < NK) asm volatile("s_waitcnt vmcnt(4)" ::: "memory");
        else            asm volatile("s_waitcnt vmcnt(0)" ::: "memory");
        __builtin_amdgcn_s_barrier();
        if (t + 2 < NK) stage(t + 2, (buf + 2) % 3);
        const char* bb = smem + buf * 16384;
        f16x8 af[4];
        #pragma unroll
        for (int i = 0; i < 4; ++i)
            af[i] = *(const f16x8*)(bb + (64 * wm + 16 * i + fr) * 64 + swz);
        #pragma unroll
        for (int j = 0; j < 4; ++j) {
            f16x8 vw = *(const f16x8*)(bb + 8192 + (64 * wn + 16 * j + fr) * 64 + swz);
            #pragma unroll
            for (int i = 0; i < 4; ++i)
                acc[i][j] = __builtin_amdgcn_mfma_f32_16x16x32_f16(af[i], vw, acc[i][j], 0, 0, 0);
        }
        buf = (buf + 1) % 3;
    }

    // -------- epilogue: quad-lane 4x4 transpose -> LSTM pointwise --------
    const int q4  = lane & 3;
    const bool qb0 = (lane & 1) != 0;
    const bool qb1 = (lane & 2) != 0;
    const int ubase = (n0 >> 2) + 16 * wn;
    const f32x4* bp4 = (const f32x4*)bp;

    #pragma unroll
    for (int i = 0; i < 4; ++i) {
        #pragma unroll
        for (int j = 0; j < 4; ++j) {
            float v0 = acc[i][j][0];
            float v1 = acc[i][j][1];
            float v2 = acc[i][j][2];
            float v3 = acc[i][j][3];
            // stage A: swap lane-bit0 with reg-bit0
            {
                float s0 = qb0 ? v0 : v1;
                float s1 = qb0 ? v2 : v3;
                float r0 = __shfl_xor(s0, 1);
                float r1 = __shfl_xor(s1, 1);
                if (!qb0) { v1 = r0; v3 = r1; } else { v0 = r0; v2 = r1; }
            }
            // stage B: swap lane-bit1 with reg-bit1
            {
                float s0 = qb1 ? v0 : v2;
                float s1 = qb1 ? v1 : v3;
                float r0 = __shfl_xor(s0, 2);
                float r1 = __shfl_xor(s1, 2);
                if (!qb1) { v2 = r0; v3 = r1; } else { v0 = r0; v1 = r1; }
            }
            // v0..v3 = gates i,f,g,o of (row, unit) for this lane
            const int unit = ubase + 4 * j + (fr >> 2);
            const int row  = m0 + 64 * wm + 16 * i + 4 * fg + q4;
            f32x4 bv = bp4[unit];
            float gi = v0 + bv[0], gf = v1 + bv[1], gg = v2 + bv[2], go = v3 + bv[3];
            size_t ci = (size_t)row * H + unit;
            float cn = sigm(gf) * cstate[ci] + sigm(gi) * tanhf(gg);
            float hn = sigm(go) * tanhf(cn);
            cstate[ci] = cn;
            f16 hh = (f16)hn;
            wr1[(size_t)row * st1 + off1 + unit] = hh;
            if (MODE == 1) wr2[(size_t)row * st2 + off2 + unit] = hh;
            if (MODE == 2) out_t[(size_t)row * H + unit] = hn;
        }
    }
}

// ---------------------------------------------------------------------------
// packing kernels
// ---------------------------------------------------------------------------
__global__ void split_pack_lin1(const float* __restrict__ src,
                                unsigned short* __restrict__ dh, unsigned short* __restrict__ dl)
{
    int idx = blockIdx.x * blockDim.x + threadIdx.x;
    if (idx >= V_MID * LATENT * SEQ) return;
    int n = idx / (LATENT * SEQ), c = idx - n * (LATENT * SEQ);
    int l = c / SEQ, s = c - l * SEQ;
    float x = src[idx];
    unsigned short h = f2bf(x);
    size_t d = (size_t)n * KPL1 + s * LATENT + l;
    dh[d] = h;
    dl[d] = f2bf(x - bf2f(h));
}

// fp16 weight pack, gate-interleaved rows p=(n%HU)*4+n/HU
__global__ void pack_f16(const float* __restrict__ src, int total, int K, int Kp,
                         int coff, int HU, f16* __restrict__ dh)
{
    int idx = blockIdx.x * blockDim.x + threadIdx.x;
    if (idx >= total) return;
    int n = idx / K, k = idx - n * K;
    int p = (n % HU) * 4 + n / HU;
    dh[(size_t)p * Kp + coff + k] = (f16)src[idx];
}

// permuted combined bias: bp[u*4+g] = bih[g*H+u] + bhh[g*H+u]
__global__ void bias_pack(const float* __restrict__ bih, const float* __restrict__ bhh,
                          int H, float* __restrict__ bp)
{
    int idx = blockIdx.x * blockDim.x + threadIdx.x;
    if (idx >= 4 * H) return;
    int g = idx / H, u = idx - g * H;
    bp[u * 4 + g] = bih[idx] + bhh[idx];
}

// ---------------------------------------------------------------------------
// encoder recurrences
// ---------------------------------------------------------------------------
__global__ __launch_bounds__(256)
void enc_rec1(const float* __restrict__ xp, int T,
              const float* __restrict__ whh,           // [240][60]
              float* __restrict__ hbuf, float* __restrict__ cbuf,
              float* __restrict__ h1relu)
{
    __shared__ float Wt[60][240];
    __shared__ float hs[4][60];
    for (int idx = threadIdx.x; idx < 240 * 60; idx += 256) {
        int n = idx / 60, k = idx % 60;
        Wt[k][n] = whh[idx];
    }
    int wid = threadIdx.x >> 6, lane = threadIdx.x & 63;
    int b = blockIdx.x * 4 + wid;
    float h = 0.f, c = 0.f;
    if (lane < 60) {
        h = hbuf[(size_t)b * 60 + lane];
        c = cbuf[(size_t)b * 60 + lane];
        hs[wid][lane] = h;
    }
    __syncthreads();
    for (int t = 0; t < T; ++t) {
        if (lane < 60) {
            const float* xr = xp + ((size_t)t * BATCH + b) * 240;
            float gi = xr[lane], gf = xr[60 + lane], gg = xr[120 + lane], go = xr[180 + lane];
            for (int k = 0; k < 60; ++k) {
                float v = hs[wid][k];
                gi += v * Wt[k][lane];
                gf += v * Wt[k][60 + lane];
                gg += v * Wt[k][120 + lane];
                go += v * Wt[k][180 + lane];
            }
            float cn = sigm(gf) * c + sigm(gi) * tanhf(gg);
            float hn = sigm(go) * tanhf(cn);
            c = cn; h = hn;
            h1relu[((size_t)t * BATCH + b) * 60 + lane] = fmaxf(hn, 0.f);
        }
        __syncthreads();
        if (lane < 60) hs[wid][lane] = h;
        __syncthreads();
    }
    if (lane < 60) {
        hbuf[(size_t)b * 60 + lane] = h;
        cbuf[(size_t)b * 60 + lane] = c;
    }
}

__global__ __launch_bounds__(256)
void enc_rec21(const float* __restrict__ xp, int T, int t0,
               const float* __restrict__ whh,          // [80][20]
               float* __restrict__ hbuf, float* __restrict__ cbuf,
               unsigned short* __restrict__ fh, unsigned short* __restrict__ fl)
{
    __shared__ float Wt[20][80];
    __shared__ float hs[4][20];
    for (int idx = threadIdx.x; idx < 80 * 20; idx += 256) {
        int n = idx / 20, k = idx % 20;
        Wt[k][n] = whh[idx];
    }
    int wid = threadIdx.x >> 6, lane = threadIdx.x & 63;
    int b = blockIdx.x * 4 + wid;
    float h = 0.f, c = 0.f;
    if (lane < 20) {
        h = hbuf[(size_t)b * 20 + lane];
        c = cbuf[(size_t)b * 20 + lane];
        hs[wid][lane] = h;
    }
    __syncthreads();
    for (int t = 0; t < T; ++t) {
        if (lane < 20) {
            const float* xr = xp + ((size_t)t * BATCH + b) * 80;
            float gi = xr[lane], gf = xr[20 + lane], gg = xr[40 + lane], go = xr[60 + lane];
            for (int k = 0; k < 20; ++k) {
                float v = hs[wid][k];
                gi += v * Wt[k][lane];
                gf += v * Wt[k][20 + lane];
                gg += v * Wt[k][40 + lane];
                go += v * Wt[k][60 + lane];
            }
            float cn = sigm(gf) * c + sigm(gi) * tanhf(gg);
            float hn = sigm(go) * tanhf(cn);
            c = cn; h = hn;
            int col = (t0 + t) * 20 + lane;
            unsigned short hh = f2bf(hn);
            fh[(size_t)b * KPL1 + col] = hh;
            fl[(size_t)b * KPL1 + col] = f2bf(hn - bf2f(hh));
        }
        __syncthreads();
        if (lane < 20) hs[wid][lane] = h;
        __syncthreads();
    }
    if (lane < 20) {
        hbuf[(size_t)b * 20 + lane] = h;
        cbuf[(size_t)b * 20 + lane] = c;
    }
}

// ---------------------------------------------------------------------------
// decoder l3 cell for t=0
// ---------------------------------------------------------------------------
__global__ __launch_bounds__(256)
void dec_l3(const float* __restrict__ outb,
            const float* __restrict__ wih,   // [200][20]
            const float* __restrict__ whh,   // [200][50]
            const float* __restrict__ bih, const float* __restrict__ bhh,
            float* __restrict__ h_t, float* __restrict__ c_t,
            f16* __restrict__ a4)
{
    __shared__ float Wt[70][200];
    __shared__ float xin[4][70];
    for (int idx = threadIdx.x; idx < 200 * 20; idx += 256) {
        int n = idx / 20, k = idx % 20;
        Wt[k][n] = wih[idx];
    }
    for (int idx = threadIdx.x; idx < 200 * 50; idx += 256) {
        int n = idx / 50, k = idx % 50;
        Wt[20 + k][n] = whh[idx];
    }
    int wid = threadIdx.x >> 6, lane = threadIdx.x & 63;
    int b = blockIdx.x * 4 + wid;
    if (lane < 20) xin[wid][lane]      = outb[(size_t)b * 20 + lane];
    if (lane < 50) xin[wid][20 + lane] = h_t[(size_t)b * 50 + lane];
    __syncthreads();
    if (lane < 50) {
        float gi = bih[lane] + bhh[lane];
        float gf = bih[50 + lane] + bhh[50 + lane];
        float gg = bih[100 + lane] + bhh[100 + lane];
        float go = bih[150 + lane] + bhh[150 + lane];
        for (int k = 0; k < 70; ++k) {
            float v = xin[wid][k];
            gi += v * Wt[k][lane];
            gf += v * Wt[k][50 + lane];
            gg += v * Wt[k][100 + lane];
            go += v * Wt[k][150 + lane];
        }
        float cold = c_t[(size_t)b * 50 + lane];
        float cn = sigm(gf) * cold + sigm(gi) * tanhf(gg);
        float hn = sigm(go) * tanhf(cn);
        c_t[(size_t)b * 50 + lane] = cn;
        h_t[(size_t)b * 50 + lane] = hn;
        a4[(size_t)b * KP4 + lane] = (f16)hn;
    }
}

// ---------------------------------------------------------------------------
// fused down2 + l3 cell for t>=1: wave-per-row, 16 rows per block
// ---------------------------------------------------------------------------
__global__ __launch_bounds__(1024)
void dec_step3(const float* __restrict__ h3prev,       // [B][512] fp32
               const float* __restrict__ w2, const float* __restrict__ b2,
               const float* __restrict__ wih, const float* __restrict__ whh,
               const float* __restrict__ bih, const float* __restrict__ bhh,
               float* __restrict__ h_t, float* __restrict__ c_t,
               f16* __restrict__ a4)
{
    __shared__ float w2s[20][512];     // [n][k]
    __shared__ float W3[70][200];      // [k][gate*50+u]
    __shared__ float xb[16][80];       // [0..19]=outb, [20..69]=h_t
    const int tid  = threadIdx.x;
    const int lane = tid & 63;
    const int w    = tid >> 6;         // 0..15 = row within block
    const int row  = blockIdx.x * 16 + w;

    for (int idx = tid; idx < 20 * 512; idx += 1024)
        w2s[idx >> 9][idx & 511] = w2[idx];
    for (int idx = tid; idx < 200 * 20; idx += 1024) {
        int n = idx / 20, k = idx - n * 20;
        W3[k][n] = wih[idx];
    }
    for (int idx = tid; idx < 200 * 50; idx += 1024) {
        int n = idx / 50, k = idx - n * 50;
        W3[20 + k][n] = whh[idx];
    }
    if (lane < 50) xb[w][20 + lane] = h_t[(size_t)row * 50 + lane];

    // h3 row into registers (coalesced)
    float hreg[8];
    const float* hrow = h3prev + (size_t)row * 512;
    #pragma unroll
    for (int c = 0; c < 8; ++c) hreg[c] = hrow[lane + 64 * c];
    __syncthreads();

    // down2: 20 outputs per row, lane-parallel over k + wave reduce
    #pragma unroll 4
    for (int n = 0; n < 20; ++n) {
        float s = 0.f;
        #pragma unroll
        for (int c = 0; c < 8; ++c) s += hreg[c] * w2s[n][lane + 64 * c];
        #pragma unroll
        for (int o = 32; o; o >>= 1) s += __shfl_xor(s, o);
        if (lane == 0) xb[w][n] = s + b2[n];
    }
    __syncthreads();

    // l3 cell: lanes 0..49
    if (lane < 50) {
        const int u = lane;
        float gi = bih[u] + bhh[u];
        float gf = bih[50 + u] + bhh[50 + u];
        float gg = bih[100 + u] + bhh[100 + u];
        float go = bih[150 + u] + bhh[150 + u];
        for (int k = 0; k < 70; ++k) {
            float v = xb[w][k];
            gi += v * W3[k][u];
            gf += v * W3[k][50 + u];
            gg += v * W3[k][100 + u];
            go += v * W3[k][150 + u];
        }
        size_t ci = (size_t)row * 50 + u;
        float cn = sigm(gf) * c_t[ci] + sigm(gi) * tanhf(gg);
        float hn = sigm(go) * tanhf(cn);
        c_t[ci] = cn;
        h_t[ci] = hn;
        a4[(size_t)row * KP4 + u] = (f16)hn;
    }
}

// ---------------------------------------------------------------------------
extern "C" void kernel_launch(void* const* d_in, const int* in_sizes, int n_in,
                              void* d_out_v, int out_size, void* d_ws, size_t ws_size,
                              hipStream_t stream)
{
    const float* x        = (const float*)d_in[0];
    const float* fc1_wih  = (const float*)d_in[1];
    const float* fc1_whh  = (const float*)d_in[2];
    const float* fc1_bih  = (const float*)d_in[3];
    const float* fc1_bhh  = (const float*)d_in[4];
    const float* fc21_wih = (const float*)d_in[5];
    const float* fc21_whh = (const float*)d_in[6];
    const float* fc21_bih = (const float*)d_in[7];
    const float* fc21_bhh = (const float*)d_in[8];
    const float* lin1_w   = (const float*)d_in[9];
    const float* lin1_b   = (const float*)d_in[10];
    const float* lin2_w   = (const float*)d_in[11];
    const float* lin2_b   = (const float*)d_in[12];
    const float* idlin_w  = (const float*)d_in[13];
    const float* idlin_b  = (const float*)d_in[14];
    const float* down1_w  = (const float*)d_in[15];
    const float* down1_b  = (const float*)d_in[16];
    const float* down2_w  = (const float*)d_in[17];
    const float* down2_b  = (const float*)d_in[18];
    const float* l3_wih   = (const float*)d_in[19];
    const float* l3_whh   = (const float*)d_in[20];
    const float* l3_bih   = (const float*)d_in[21];
    const float* l3_bhh   = (const float*)d_in[22];
    const float* l4_wih   = (const float*)d_in[23];
    const float* l4_whh   = (const float*)d_in[24];
    const float* l4_bih   = (const float*)d_in[25];
    const float* l4_bhh   = (const float*)d_in[26];
    const float* l5_wih   = (const float*)d_in[27];
    const float* l5_whh   = (const float*)d_in[28];
    const float* l5_bih   = (const float*)d_in[29];
    const float* l5_bhh   = (const float*)d_in[30];
    float* out = (float*)d_out_v;

    char* base = (char*)d_ws;
    size_t off = 0;
    auto alloc = [&](size_t bytes) -> void* {
        off = (off + 255) & ~(size_t)255;
        void* p = base + off;
        off += bytes;
        return p;
    };

    // --- zero-init 16-bit region ---
    size_t us_begin = (off + 255) & ~(size_t)255;
    f16* W4h = (f16*)alloc((size_t)3200 * KP4 * 2);
    f16* W5h = (f16*)alloc((size_t)2048 * KP5 * 2);
    unsigned short* L1h = (unsigned short*)alloc((size_t)896 * KPL1 * 2);
    unsigned short* L1l = (unsigned short*)alloc((size_t)896 * KPL1 * 2);
    unsigned short* Fh  = (unsigned short*)alloc((size_t)BATCH * KPL1 * 2);
    unsigned short* Fl  = (unsigned short*)alloc((size_t)BATCH * KPL1 * 2);
    f16* A4[2]; f16* A5[2];
    for (int p = 0; p < 2; ++p) {
        A4[p] = (f16*)alloc((size_t)BATCH * KP4 * 2);
        A5[p] = (f16*)alloc((size_t)BATCH * KP5 * 2);
    }
    size_t us_end = off;

    // --- zero-init fp32 region ---
    size_t fz_begin = (off + 255) & ~(size_t)255;
    float* c2   = (float*)alloc((size_t)BATCH * MID_O * 4);
    float* c3   = (float*)alloc((size_t)BATCH * OUT_DIM * 4);
    float* hb1  = (float*)alloc((size_t)BATCH * MID_I * 4);
    float* cb1  = (float*)alloc((size_t)BATCH * MID_I * 4);
    float* hb21 = (float*)alloc((size_t)BATCH * LATENT * 4);
    float* cb21 = (float*)alloc((size_t)BATCH * LATENT * 4);
    size_t fz_end = off;

    // --- no-init buffers ---
    float* bp4   = (float*)alloc((size_t)4 * MID_O * 4);
    float* bp5   = (float*)alloc((size_t)4 * OUT_DIM * 4);
    float* mu1   = (float*)alloc((size_t)BATCH * V_MID * 4);
    float* mu    = (float*)alloc((size_t)BATCH * V_LAT * 4);
    float* h_t   = (float*)alloc((size_t)BATCH * V_LAT * 4);
    float* c_t   = (float*)alloc((size_t)BATCH * V_LAT * 4);
    float* outb  = (float*)alloc((size_t)BATCH * LATENT * 4);
    const int CH = 20;
    float* xp1c  = (float*)alloc((size_t)CH * BATCH * 4 * MID_I * 4);
    float* h1rc  = (float*)alloc((size_t)CH * BATCH * MID_I * 4);
    float* xp21c = (float*)alloc((size_t)CH * BATCH * 4 * LATENT * 4);

    hipMemsetAsync(base + us_begin, 0, us_end - us_begin, stream);
    hipMemsetAsync(base + fz_begin, 0, fz_end - fz_begin, stream);

    // --- weight/bias packing ---
    pack_f16<<<(3200 * 50  + 255) / 256, 256, 0, stream>>>(l4_wih, 3200 * 50,  50,  KP4, 0,   800, W4h);
    pack_f16<<<(3200 * 800 + 255) / 256, 256, 0, stream>>>(l4_whh, 3200 * 800, 800, KP4, 64,  800, W4h);
    pack_f16<<<(2048 * 800 + 255) / 256, 256, 0, stream>>>(l5_wih, 2048 * 800, 800, KP5, 0,   512, W5h);
    pack_f16<<<(2048 * 512 + 255) / 256, 256, 0, stream>>>(l5_whh, 2048 * 512, 512, KP5, 832, 512, W5h);
    split_pack_lin1<<<(V_MID * LATENT * SEQ + 255) / 256, 256, 0, stream>>>(lin1_w, L1h, L1l);
    bias_pack<<<(4 * MID_O   + 255) / 256, 256, 0, stream>>>(l4_bih, l4_bhh, MID_O,   bp4);
    bias_pack<<<(4 * OUT_DIM + 255) / 256, 256, 0, stream>>>(l5_bih, l5_bhh, OUT_DIM, bp5);

    // ---------------- encoder ----------------
    for (int c0 = 0; c0 < SEQ; c0 += CH) {
        {
            dim3 g((4 * MID_I + BN - 1) / BN, CH * BATCH / BM);
            gemm2k<false, false><<<g, 256, 0, stream>>>(
                x + (size_t)c0 * BATCH * IN_DIM, IN_DIM, nullptr, 0,
                fc1_wih, nullptr, fc1_bih, fc1_bhh, xp1c, CH * BATCH, 4 * MID_I);
        }
        enc_rec1<<<BATCH / 4, 256, 0, stream>>>(xp1c, CH, fc1_whh, hb1, cb1, h1rc);
        {
            dim3 g((4 * LATENT + BN - 1) / BN, CH * BATCH / BM);
            gemm2k<false, false><<<g, 256, 0, stream>>>(
                h1rc, MID_I, nullptr, 0,
                fc21_wih, nullptr, fc21_bih, fc21_bhh, xp21c, CH * BATCH, 4 * LATENT);
        }
        enc_rec21<<<BATCH / 4, 256, 0, stream>>>(xp21c, CH, c0, fc21_whh, hb21, cb21, Fh, Fl);
    }

    // lin1 (bf16 3-term MFMA) + lin2 (fp32)
    {
        dim3 g(7, 16);
        gemm_lin1<<<g, 256, 0, stream>>>(Fh, Fl, L1h, L1l, KPL1, V_MID, lin1_b, mu1);
    }
    {
        dim3 g((V_LAT + BN - 1) / BN, BATCH / BM);
        gemm2k<false, true><<<g, 256, 0, stream>>>(mu1, V_MID, nullptr, 0,
            lin2_w, nullptr, lin2_b, nullptr, mu, BATCH, V_LAT);
    }

    // ---------------- decoder init ----------------
    hipMemcpyAsync(h_t, mu, (size_t)BATCH * V_LAT * 4, hipMemcpyDeviceToDevice, stream);
    {
        dim3 g(1, BATCH / BM);
        gemm2k<false, false><<<g, 256, 0, stream>>>(mu, V_LAT, nullptr, 0,
            idlin_w, nullptr, idlin_b, nullptr, c_t, BATCH, V_LAT);
        gemm2k<false, false><<<g, 256, 0, stream>>>(mu, V_LAT, nullptr, 0,
            down1_w, nullptr, down1_b, nullptr, outb, BATCH, LATENT);
    }

    // ---------------- decoder scan ----------------
    for (int t = 0; t < SEQ; ++t) {
        const int p = t & 1;
        if (t == 0) {
            dec_l3<<<BATCH / 4, 256, 0, stream>>>(outb, l3_wih, l3_whh, l3_bih, l3_bhh,
                                                  h_t, c_t, A4[0]);
        } else {
            dec_step3<<<BATCH / 16, 1024, 0, stream>>>(
                out + (size_t)(t - 1) * BATCH * OUT_DIM,
                down2_w, down2_b, l3_wih, l3_whh, l3_bih, l3_bhh,
                h_t, c_t, A4[p]);
        }
        {
            // N=3200 -> 25 col-tiles x 16 row-tiles = 400 blocks
            gemm_dec<1><<<dim3(400), 256, 0, stream>>>(
                A4[p], W4h, KP4, KP4 / 32, MID_O, 25, bp4, c2,
                A4[p ^ 1], KP4, 64,
                A5[p], KP5, 0,
                nullptr);
        }
        {
            // N=2048 -> 16 col-tiles x 16 row-tiles = 256 blocks
            gemm_dec<2><<<dim3(256), 256, 0, stream>>>(
                A5[p], W5h, KP5, KP5 / 32, OUT_DIM, 16, bp5, c3,
                A5[p ^ 1], KP5, 832,
                nullptr, 0, 0,
                out + (size_t)t * BATCH * OUT_DIM);
        }
    }

    hipMemcpyAsync(out + (size_t)SEQ * BATCH * OUT_DIM, mu,
                   (size_t)BATCH * V_LAT * 4, hipMemcpyDeviceToDevice, stream);
}

// Round 7
// 7671.051 us; speedup vs baseline: 9.4832x; 1.1581x over previous
//
#include <hip/hip_runtime.h>
#include <cstdint>
#include <cstddef>

#define SEQ     100
#define BATCH   2048
#define IN_DIM  64
#define MID_I   60
#define LATENT  20
#define V_MID   800
#define V_LAT   50
#define MID_O   800
#define OUT_DIM 512

#define KP4  896    // [h_t pad 64 | h2 800 | pad to 896]
#define KP5  1344   // [h2 800 pad 832 | h3 512]
#define KPL1 2048   // latent*seq 2000 padded

using f32x4  = __attribute__((ext_vector_type(4))) float;
using u16x8  = __attribute__((ext_vector_type(8))) unsigned short;
using bf16x8 = __attribute__((ext_vector_type(8))) __bf16;
typedef _Float16 f16;
typedef _Float16 f16x8 __attribute__((ext_vector_type(8)));

__device__ __forceinline__ unsigned short f2bf(float x){
    unsigned u = __builtin_bit_cast(unsigned, x);
    u += 0x7FFFu + ((u >> 16) & 1u);
    return (unsigned short)(u >> 16);
}
__device__ __forceinline__ float bf2f(unsigned short b){
    unsigned u = ((unsigned)b) << 16; return __builtin_bit_cast(float, u);
}
__device__ __forceinline__ float sigm(float x){ return 1.f/(1.f+__expf(-x)); }
__device__ __forceinline__ float tanh_f(float x){ return 1.f - 2.f/(__expf(2.f*x)+1.f); }

typedef const __attribute__((address_space(1))) unsigned int* gas_ptr;
typedef __attribute__((address_space(3))) unsigned int* las_ptr;
__device__ __forceinline__ void gld16(const void* g, char* l) {
    __builtin_amdgcn_global_load_lds((gas_ptr)g, (las_ptr)l, 16, 0, 0);
}

// ---------------------------------------------------------------------------
// fp32 tiled GEMM (encoder x-projections, lin2, decoder init)
// ---------------------------------------------------------------------------
constexpr int BM = 64, BN = 64, BK = 16;
template<bool RELU_A1, bool RELU_OUT>
__global__ __launch_bounds__(256)
void gemm2k(const float* __restrict__ A1, int K1,
            const float* __restrict__ A2, int K2,
            const float* __restrict__ W1, const float* __restrict__ W2,
            const float* __restrict__ b1, const float* __restrict__ b2,
            float* __restrict__ C, int M, int N)
{
    __shared__ float As[BK][BM + 1];
    __shared__ float Bs[BK][BN + 1];
    const int tx = threadIdx.x & 15;
    const int ty = threadIdx.x >> 4;
    const int n0 = blockIdx.x * BN;
    const int m0 = blockIdx.y * BM;

    float acc[4][4] = {};

    for (int src = 0; src < 2; ++src) {
        const float* A = src ? A2 : A1;
        const float* W = src ? W2 : W1;
        const int    K = src ? K2 : K1;
        if (A == nullptr || K == 0) continue;
        for (int k0 = 0; k0 < K; k0 += BK) {
            #pragma unroll
            for (int i = 0; i < 4; ++i) {
                int idx = threadIdx.x + i * 256;
                int k = idx & 15, m = idx >> 4;
                int gm = m0 + m, gk = k0 + k;
                float v = 0.f;
                if (gm < M && gk < K) v = A[(size_t)gm * K + gk];
                if (RELU_A1 && src == 0) v = fmaxf(v, 0.f);
                As[k][m] = v;
            }
            #pragma unroll
            for (int i = 0; i < 4; ++i) {
                int idx = threadIdx.x + i * 256;
                int k = idx & 15, n = idx >> 4;
                int gn = n0 + n, gk = k0 + k;
                float v = 0.f;
                if (gn < N && gk < K) v = W[(size_t)gn * K + gk];
                Bs[k][n] = v;
            }
            __syncthreads();
            #pragma unroll
            for (int kk = 0; kk < BK; ++kk) {
                float a[4], b[4];
                #pragma unroll
                for (int i = 0; i < 4; ++i) a[i] = As[kk][ty + i * 16];
                #pragma unroll
                for (int j = 0; j < 4; ++j) b[j] = Bs[kk][tx + j * 16];
                #pragma unroll
                for (int i = 0; i < 4; ++i)
                    #pragma unroll
                    for (int j = 0; j < 4; ++j)
                        acc[i][j] += a[i] * b[j];
            }
            __syncthreads();
        }
    }

    #pragma unroll
    for (int i = 0; i < 4; ++i) {
        int gm = m0 + ty + i * 16;
        if (gm >= M) continue;
        #pragma unroll
        for (int j = 0; j < 4; ++j) {
            int gn = n0 + tx + j * 16;
            if (gn >= N) continue;
            float v = acc[i][j];
            if (b1) v += b1[gn];
            if (b2) v += b2[gn];
            if (RELU_OUT) v = fmaxf(v, 0.f);
            C[(size_t)gm * N + gn] = v;
        }
    }
}

// ---------------------------------------------------------------------------
// lin1: split-bf16 3-term MFMA GEMM, 128x128 tile, plain store + relu
// ---------------------------------------------------------------------------
__global__ __launch_bounds__(256, 2)
void gemm_lin1(const unsigned short* __restrict__ Ah, const unsigned short* __restrict__ Al,
               const unsigned short* __restrict__ Bh, const unsigned short* __restrict__ Bl,
               int Kp, int Nstore, const float* __restrict__ bi, float* __restrict__ Cout)
{
    __shared__ __align__(16) char smem[32768];
    const int tid  = threadIdx.x;
    const int lane = tid & 63;
    const int wid  = tid >> 6;
    const int m0   = blockIdx.y * 128;
    const int n0   = blockIdx.x * 128;
    const int wr   = (wid >> 1) << 6;
    const int wc   = (wid & 1) << 6;
    const int fr   = lane & 15;
    const int fg   = lane >> 4;
    const int slotR = ((fg ^ (fr & 3)) << 4);

    const int r0 = 32 * wid + (lane >> 2);
    const int sl = (((lane & 3) ^ ((lane >> 2) & 3)) << 3);
    const unsigned short* gA0h = Ah + (size_t)(m0 + r0)      * Kp + sl;
    const unsigned short* gA1h = Ah + (size_t)(m0 + r0 + 16) * Kp + sl;
    const unsigned short* gA0l = Al + (size_t)(m0 + r0)      * Kp + sl;
    const unsigned short* gA1l = Al + (size_t)(m0 + r0 + 16) * Kp + sl;
    const unsigned short* gB0h = Bh + (size_t)(n0 + r0)      * Kp + sl;
    const unsigned short* gB1h = Bh + (size_t)(n0 + r0 + 16) * Kp + sl;
    const unsigned short* gB0l = Bl + (size_t)(n0 + r0)      * Kp + sl;
    const unsigned short* gB1l = Bl + (size_t)(n0 + r0 + 16) * Kp + sl;
    char* lA0h = smem +     0 + (2 * wid    ) * 1024;
    char* lA1h = smem +     0 + (2 * wid + 1) * 1024;
    char* lA0l = smem +  8192 + (2 * wid    ) * 1024;
    char* lA1l = smem +  8192 + (2 * wid + 1) * 1024;
    char* lB0h = smem + 16384 + (2 * wid    ) * 1024;
    char* lB1h = smem + 16384 + (2 * wid + 1) * 1024;
    char* lB0l = smem + 24576 + (2 * wid    ) * 1024;
    char* lB1l = smem + 24576 + (2 * wid + 1) * 1024;

    f32x4 acc[4][4];
    #pragma unroll
    for (int i = 0; i < 4; ++i)
        #pragma unroll
        for (int j = 0; j < 4; ++j) acc[i][j] = (f32x4){0.f, 0.f, 0.f, 0.f};

    for (int k0 = 0; k0 < Kp; k0 += 32) {
        __syncthreads();
        gld16(gA0h + k0, lA0h); gld16(gA1h + k0, lA1h);
        gld16(gA0l + k0, lA0l); gld16(gA1l + k0, lA1l);
        gld16(gB0h + k0, lB0h); gld16(gB1h + k0, lB1h);
        gld16(gB0l + k0, lB0l); gld16(gB1l + k0, lB1l);
        __syncthreads();

        bf16x8 ah[4], al[4];
        #pragma unroll
        for (int i = 0; i < 4; ++i) {
            int ro = (wr + i * 16 + fr) * 64 + slotR;
            ah[i] = *(const bf16x8*)(smem +        ro);
            al[i] = *(const bf16x8*)(smem + 8192 + ro);
        }
        #pragma unroll
        for (int j = 0; j < 4; ++j) {
            int ro = (wc + j * 16 + fr) * 64 + slotR;
            bf16x8 fbh = *(const bf16x8*)(smem + 16384 + ro);
            bf16x8 fbl = *(const bf16x8*)(smem + 24576 + ro);
            #pragma unroll
            for (int i = 0; i < 4; ++i) {
                acc[i][j] = __builtin_amdgcn_mfma_f32_16x16x32_bf16(ah[i], fbh, acc[i][j], 0, 0, 0);
                acc[i][j] = __builtin_amdgcn_mfma_f32_16x16x32_bf16(ah[i], fbl, acc[i][j], 0, 0, 0);
                acc[i][j] = __builtin_amdgcn_mfma_f32_16x16x32_bf16(al[i], fbh, acc[i][j], 0, 0, 0);
            }
        }
    }

    #pragma unroll
    for (int j = 0; j < 4; ++j) {
        int gc = n0 + wc + j * 16 + fr;
        if (gc >= Nstore) continue;
        float badd = bi[gc];
        #pragma unroll
        for (int i = 0; i < 4; ++i)
            #pragma unroll
            for (int r = 0; r < 4; ++r) {
                int gr = m0 + wr + i * 16 + fg * 4 + r;
                float v = fmaxf(acc[i][j][r] + badd, 0.f);
                Cout[(size_t)gr * Nstore + gc] = v;
            }
    }
}

// ---------------------------------------------------------------------------
// decoder GEMM: fp16 MFMA, 128x128 tile, 4 waves, 3-buffer counted-vmcnt
// pipeline, LDS-transposed coalesced LSTM epilogue, XCD-chunked swizzle.
// Weights gate-interleaved (row p = (n%H)*4 + n/H).
// Grid = NBX*16 blocks (1-D). MODE 1 = l4, MODE 2 = l5.
// ---------------------------------------------------------------------------
template<int MODE>
__global__ __launch_bounds__(256, 3)
void gemm_dec(const f16* __restrict__ A, const f16* __restrict__ W,
              int Kp, int NK, int H, int NBX,
              const float* __restrict__ bp,     // permuted combined bias [H*4]
              float* __restrict__ cstate,
              f16* __restrict__ wr1, int st1, int off1,
              f16* __restrict__ wr2, int st2, int off2,
              float* __restrict__ out_t)
{
    __shared__ __align__(16) char smem[49152];   // 3 buffers x (A 8K + W 8K)
    const int qq      = NBX * 2;                 // blocks per XCD
    const int logical = (blockIdx.x & 7) * qq + (blockIdx.x >> 3);
    const int bx = logical >> 4;
    const int by = logical & 15;
    const int m0 = by * 128;
    const int n0 = bx * 128;

    const int tid  = threadIdx.x;
    const int lane = tid & 63;
    const int wid  = tid >> 6;         // 0..3
    const int wm   = wid >> 1;         // 0..1
    const int wn   = wid & 1;          // 0..1
    const int fr   = lane & 15;
    const int fg   = lane >> 4;
    const int swz  = (fg ^ (fr & 3) ^ ((fr >> 2) & 1)) * 16;

    const int rbase = 32 * wid;
    const int lrow  = lane >> 2;
    const int chnk  = (lane & 3) ^ ((lane >> 2) & 3) ^ ((lane >> 4) & 1);
    const f16* sA0 = A + (size_t)(m0 + rbase + lrow)      * Kp + chnk * 8;
    const f16* sA1 = A + (size_t)(m0 + rbase + 16 + lrow) * Kp + chnk * 8;
    const f16* sW0 = W + (size_t)(n0 + rbase + lrow)      * Kp + chnk * 8;
    const f16* sW1 = W + (size_t)(n0 + rbase + 16 + lrow) * Kp + chnk * 8;

    f32x4 acc[4][4];
    #pragma unroll
    for (int i = 0; i < 4; ++i)
        #pragma unroll
        for (int j = 0; j < 4; ++j) acc[i][j] = (f32x4){0.f, 0.f, 0.f, 0.f};

    auto stage = [&](int t, int buf) {
        const int kb = t * 32;
        char* bb = smem + buf * 16384;
        gld16(sA0 + kb, bb + rbase * 64);
        gld16(sA1 + kb, bb + (rbase + 16) * 64);
        gld16(sW0 + kb, bb + 8192 + rbase * 64);
        gld16(sW1 + kb, bb + 8192 + (rbase + 16) * 64);
    };

    stage(0, 0);
    stage(1, 1);

    int buf = 0;
    for (int t = 0; t < NK; ++t) {
        if (t + 1 < NK) asm volatile("s_waitcnt vmcnt(4)" ::: "memory");
        else            asm volatile("s_waitcnt vmcnt(0)" ::: "memory");
        __builtin_amdgcn_s_barrier();
        if (t + 2 < NK) stage(t + 2, (buf + 2) % 3);
        const char* bb = smem + buf * 16384;
        f16x8 af[4];
        #pragma unroll
        for (int i = 0; i < 4; ++i)
            af[i] = *(const f16x8*)(bb + (64 * wm + 16 * i + fr) * 64 + swz);
        #pragma unroll
        for (int j = 0; j < 4; ++j) {
            f16x8 vw = *(const f16x8*)(bb + 8192 + (64 * wn + 16 * j + fr) * 64 + swz);
            #pragma unroll
            for (int i = 0; i < 4; ++i)
                acc[i][j] = __builtin_amdgcn_mfma_f32_16x16x32_f16(af[i], vw, acc[i][j], 0, 0, 0);
        }
        buf = (buf + 1) % 3;
    }

    // -------- epilogue: LDS gate transpose -> coalesced LSTM pointwise ----
    float* gt = (float*)smem;              // [64][132]
    const int u32 = tid & 31;              // unit within tile
    const int r8  = tid >> 5;              // 0..7
    const int unit = (n0 >> 2) + u32;
    const f32x4* bp4 = (const f32x4*)bp;
    const f32x4 bv = bp4[unit];

    #pragma unroll
    for (int half = 0; half < 2; ++half) {
        __syncthreads();
        if (wm == half) {
            #pragma unroll
            for (int i = 0; i < 4; ++i)
                #pragma unroll
                for (int j = 0; j < 4; ++j)
                    #pragma unroll
                    for (int r = 0; r < 4; ++r)
                        gt[(16*i + 4*fg + r) * 132 + 64*wn + 16*j + fr] = acc[i][j][r];
        }
        __syncthreads();
        #pragma unroll
        for (int kk = 0; kk < 8; ++kk) {
            const int lr  = 8 * kk + r8;
            const int row = m0 + 64 * half + lr;
            f32x4 g = *(const f32x4*)(gt + lr * 132 + u32 * 4);
            float gi = g[0] + bv[0], gf = g[1] + bv[1];
            float gg = g[2] + bv[2], go = g[3] + bv[3];
            size_t ci = (size_t)row * H + unit;
            float cn = sigm(gf) * cstate[ci] + sigm(gi) * tanh_f(gg);
            float hn = sigm(go) * tanh_f(cn);
            cstate[ci] = cn;
            f16 hh = (f16)hn;
            wr1[(size_t)row * st1 + off1 + unit] = hh;
            if (MODE == 1) wr2[(size_t)row * st2 + off2 + unit] = hh;
            if (MODE == 2) out_t[(size_t)row * H + unit] = hn;
        }
    }
}

// ---------------------------------------------------------------------------
// packing kernels
// ---------------------------------------------------------------------------
__global__ void split_pack_lin1(const float* __restrict__ src,
                                unsigned short* __restrict__ dh, unsigned short* __restrict__ dl)
{
    int idx = blockIdx.x * blockDim.x + threadIdx.x;
    if (idx >= V_MID * LATENT * SEQ) return;
    int n = idx / (LATENT * SEQ), c = idx - n * (LATENT * SEQ);
    int l = c / SEQ, s = c - l * SEQ;
    float x = src[idx];
    unsigned short h = f2bf(x);
    size_t d = (size_t)n * KPL1 + s * LATENT + l;
    dh[d] = h;
    dl[d] = f2bf(x - bf2f(h));
}

// fp16 weight pack, gate-interleaved rows p=(n%HU)*4+n/HU
__global__ void pack_f16(const float* __restrict__ src, int total, int K, int Kp,
                         int coff, int HU, f16* __restrict__ dh)
{
    int idx = blockIdx.x * blockDim.x + threadIdx.x;
    if (idx >= total) return;
    int n = idx / K, k = idx - n * K;
    int p = (n % HU) * 4 + n / HU;
    dh[(size_t)p * Kp + coff + k] = (f16)src[idx];
}

// permuted combined bias: bp[u*4+g] = bih[g*H+u] + bhh[g*H+u]
__global__ void bias_pack(const float* __restrict__ bih, const float* __restrict__ bhh,
                          int H, float* __restrict__ bp)
{
    int idx = blockIdx.x * blockDim.x + threadIdx.x;
    if (idx >= 4 * H) return;
    int g = idx / H, u = idx - g * H;
    bp[u * 4 + g] = bih[idx] + bhh[idx];
}

// ---------------------------------------------------------------------------
// encoder recurrences
// ---------------------------------------------------------------------------
__global__ __launch_bounds__(256)
void enc_rec1(const float* __restrict__ xp, int T,
              const float* __restrict__ whh,           // [240][60]
              float* __restrict__ hbuf, float* __restrict__ cbuf,
              float* __restrict__ h1relu)
{
    __shared__ float Wt[60][240];
    __shared__ float hs[4][60];
    for (int idx = threadIdx.x; idx < 240 * 60; idx += 256) {
        int n = idx / 60, k = idx % 60;
        Wt[k][n] = whh[idx];
    }
    int wid = threadIdx.x >> 6, lane = threadIdx.x & 63;
    int b = blockIdx.x * 4 + wid;
    float h = 0.f, c = 0.f;
    if (lane < 60) {
        h = hbuf[(size_t)b * 60 + lane];
        c = cbuf[(size_t)b * 60 + lane];
        hs[wid][lane] = h;
    }
    __syncthreads();
    for (int t = 0; t < T; ++t) {
        if (lane < 60) {
            const float* xr = xp + ((size_t)t * BATCH + b) * 240;
            float gi = xr[lane], gf = xr[60 + lane], gg = xr[120 + lane], go = xr[180 + lane];
            for (int k = 0; k < 60; ++k) {
                float v = hs[wid][k];
                gi += v * Wt[k][lane];
                gf += v * Wt[k][60 + lane];
                gg += v * Wt[k][120 + lane];
                go += v * Wt[k][180 + lane];
            }
            float cn = sigm(gf) * c + sigm(gi) * tanh_f(gg);
            float hn = sigm(go) * tanh_f(cn);
            c = cn; h = hn;
            h1relu[((size_t)t * BATCH + b) * 60 + lane] = fmaxf(hn, 0.f);
        }
        __syncthreads();
        if (lane < 60) hs[wid][lane] = h;
        __syncthreads();
    }
    if (lane < 60) {
        hbuf[(size_t)b * 60 + lane] = h;
        cbuf[(size_t)b * 60 + lane] = c;
    }
}

__global__ __launch_bounds__(256)
void enc_rec21(const float* __restrict__ xp, int T, int t0,
               const float* __restrict__ whh,          // [80][20]
               float* __restrict__ hbuf, float* __restrict__ cbuf,
               unsigned short* __restrict__ fh, unsigned short* __restrict__ fl)
{
    __shared__ float Wt[20][80];
    __shared__ float hs[4][20];
    for (int idx = threadIdx.x; idx < 80 * 20; idx += 256) {
        int n = idx / 20, k = idx % 20;
        Wt[k][n] = whh[idx];
    }
    int wid = threadIdx.x >> 6, lane = threadIdx.x & 63;
    int b = blockIdx.x * 4 + wid;
    float h = 0.f, c = 0.f;
    if (lane < 20) {
        h = hbuf[(size_t)b * 20 + lane];
        c = cbuf[(size_t)b * 20 + lane];
        hs[wid][lane] = h;
    }
    __syncthreads();
    for (int t = 0; t < T; ++t) {
        if (lane < 20) {
            const float* xr = xp + ((size_t)t * BATCH + b) * 80;
            float gi = xr[lane], gf = xr[20 + lane], gg = xr[40 + lane], go = xr[60 + lane];
            for (int k = 0; k < 20; ++k) {
                float v = hs[wid][k];
                gi += v * Wt[k][lane];
                gf += v * Wt[k][20 + lane];
                gg += v * Wt[k][40 + lane];
                go += v * Wt[k][60 + lane];
            }
            float cn = sigm(gf) * c + sigm(gi) * tanh_f(gg);
            float hn = sigm(go) * tanh_f(cn);
            c = cn; h = hn;
            int col = (t0 + t) * 20 + lane;
            unsigned short hh = f2bf(hn);
            fh[(size_t)b * KPL1 + col] = hh;
            fl[(size_t)b * KPL1 + col] = f2bf(hn - bf2f(hh));
        }
        __syncthreads();
        if (lane < 20) hs[wid][lane] = h;
        __syncthreads();
    }
    if (lane < 20) {
        hbuf[(size_t)b * 20 + lane] = h;
        cbuf[(size_t)b * 20 + lane] = c;
    }
}

// ---------------------------------------------------------------------------
// decoder l3 cell for t=0
// ---------------------------------------------------------------------------
__global__ __launch_bounds__(256)
void dec_l3(const float* __restrict__ outb,
            const float* __restrict__ wih,   // [200][20]
            const float* __restrict__ whh,   // [200][50]
            const float* __restrict__ bih, const float* __restrict__ bhh,
            float* __restrict__ h_t, float* __restrict__ c_t,
            f16* __restrict__ a4)
{
    __shared__ float Wt[70][200];
    __shared__ float xin[4][70];
    for (int idx = threadIdx.x; idx < 200 * 20; idx += 256) {
        int n = idx / 20, k = idx % 20;
        Wt[k][n] = wih[idx];
    }
    for (int idx = threadIdx.x; idx < 200 * 50; idx += 256) {
        int n = idx / 50, k = idx % 50;
        Wt[20 + k][n] = whh[idx];
    }
    int wid = threadIdx.x >> 6, lane = threadIdx.x & 63;
    int b = blockIdx.x * 4 + wid;
    if (lane < 20) xin[wid][lane]      = outb[(size_t)b * 20 + lane];
    if (lane < 50) xin[wid][20 + lane] = h_t[(size_t)b * 50 + lane];
    __syncthreads();
    if (lane < 50) {
        float gi = bih[lane] + bhh[lane];
        float gf = bih[50 + lane] + bhh[50 + lane];
        float gg = bih[100 + lane] + bhh[100 + lane];
        float go = bih[150 + lane] + bhh[150 + lane];
        for (int k = 0; k < 70; ++k) {
            float v = xin[wid][k];
            gi += v * Wt[k][lane];
            gf += v * Wt[k][50 + lane];
            gg += v * Wt[k][100 + lane];
            go += v * Wt[k][150 + lane];
        }
        float cold = c_t[(size_t)b * 50 + lane];
        float cn = sigm(gf) * cold + sigm(gi) * tanh_f(gg);
        float hn = sigm(go) * tanh_f(cn);
        c_t[(size_t)b * 50 + lane] = cn;
        h_t[(size_t)b * 50 + lane] = hn;
        a4[(size_t)b * KP4 + lane] = (f16)hn;
    }
}

// ---------------------------------------------------------------------------
// fused down2 + l3 cell for t>=1: wave-per-row, 8 rows per block, 256 blocks
// ---------------------------------------------------------------------------
__global__ __launch_bounds__(512)
void dec_step3(const float* __restrict__ h3prev,       // [B][512] fp32
               const float* __restrict__ w2, const float* __restrict__ b2,
               const float* __restrict__ wih, const float* __restrict__ whh,
               const float* __restrict__ bih, const float* __restrict__ bhh,
               float* __restrict__ h_t, float* __restrict__ c_t,
               f16* __restrict__ a4)
{
    __shared__ float w2s[20][512];     // [n][k]
    __shared__ float W3[70][200];      // [k][gate*50+u]
    __shared__ float xb[8][80];        // [0..19]=outb, [20..69]=h_t
    const int tid  = threadIdx.x;
    const int lane = tid & 63;
    const int w    = tid >> 6;         // 0..7 = row within block
    const int row  = blockIdx.x * 8 + w;

    for (int idx = tid; idx < 20 * 512; idx += 512)
        w2s[idx >> 9][idx & 511] = w2[idx];
    for (int idx = tid; idx < 200 * 20; idx += 512) {
        int n = idx / 20, k = idx - n * 20;
        W3[k][n] = wih[idx];
    }
    for (int idx = tid; idx < 200 * 50; idx += 512) {
        int n = idx / 50, k = idx - n * 50;
        W3[20 + k][n] = whh[idx];
    }
    if (lane < 50) xb[w][20 + lane] = h_t[(size_t)row * 50 + lane];

    float hreg[8];
    const float* hrow = h3prev + (size_t)row * 512;
    #pragma unroll
    for (int c = 0; c < 8; ++c) hreg[c] = hrow[lane + 64 * c];
    __syncthreads();

    #pragma unroll 4
    for (int n = 0; n < 20; ++n) {
        float s = 0.f;
        #pragma unroll
        for (int c = 0; c < 8; ++c) s += hreg[c] * w2s[n][lane + 64 * c];
        #pragma unroll
        for (int o = 32; o; o >>= 1) s += __shfl_xor(s, o);
        if (lane == 0) xb[w][n] = s + b2[n];
    }
    __syncthreads();

    if (lane < 50) {
        const int u = lane;
        float gi = bih[u] + bhh[u];
        float gf = bih[50 + u] + bhh[50 + u];
        float gg = bih[100 + u] + bhh[100 + u];
        float go = bih[150 + u] + bhh[150 + u];
        for (int k = 0; k < 70; ++k) {
            float v = xb[w][k];
            gi += v * W3[k][u];
            gf += v * W3[k][50 + u];
            gg += v * W3[k][100 + u];
            go += v * W3[k][150 + u];
        }
        size_t ci = (size_t)row * 50 + u;
        float cn = sigm(gf) * c_t[ci] + sigm(gi) * tanh_f(gg);
        float hn = sigm(go) * tanh_f(cn);
        c_t[ci] = cn;
        h_t[ci] = hn;
        a4[(size_t)row * KP4 + u] = (f16)hn;
    }
}

// ---------------------------------------------------------------------------
extern "C" void kernel_launch(void* const* d_in, const int* in_sizes, int n_in,
                              void* d_out_v, int out_size, void* d_ws, size_t ws_size,
                              hipStream_t stream)
{
    const float* x        = (const float*)d_in[0];
    const float* fc1_wih  = (const float*)d_in[1];
    const float* fc1_whh  = (const float*)d_in[2];
    const float* fc1_bih  = (const float*)d_in[3];
    const float* fc1_bhh  = (const float*)d_in[4];
    const float* fc21_wih = (const float*)d_in[5];
    const float* fc21_whh = (const float*)d_in[6];
    const float* fc21_bih = (const float*)d_in[7];
    const float* fc21_bhh = (const float*)d_in[8];
    const float* lin1_w   = (const float*)d_in[9];
    const float* lin1_b   = (const float*)d_in[10];
    const float* lin2_w   = (const float*)d_in[11];
    const float* lin2_b   = (const float*)d_in[12];
    const float* idlin_w  = (const float*)d_in[13];
    const float* idlin_b  = (const float*)d_in[14];
    const float* down1_w  = (const float*)d_in[15];
    const float* down1_b  = (const float*)d_in[16];
    const float* down2_w  = (const float*)d_in[17];
    const float* down2_b  = (const float*)d_in[18];
    const float* l3_wih   = (const float*)d_in[19];
    const float* l3_whh   = (const float*)d_in[20];
    const float* l3_bih   = (const float*)d_in[21];
    const float* l3_bhh   = (const float*)d_in[22];
    const float* l4_wih   = (const float*)d_in[23];
    const float* l4_whh   = (const float*)d_in[24];
    const float* l4_bih   = (const float*)d_in[25];
    const float* l4_bhh   = (const float*)d_in[26];
    const float* l5_wih   = (const float*)d_in[27];
    const float* l5_whh   = (const float*)d_in[28];
    const float* l5_bih   = (const float*)d_in[29];
    const float* l5_bhh   = (const float*)d_in[30];
    float* out = (float*)d_out_v;

    char* base = (char*)d_ws;
    size_t off = 0;
    auto alloc = [&](size_t bytes) -> void* {
        off = (off + 255) & ~(size_t)255;
        void* p = base + off;
        off += bytes;
        return p;
    };

    // --- zero-init 16-bit region ---
    size_t us_begin = (off + 255) & ~(size_t)255;
    f16* W4h = (f16*)alloc((size_t)3200 * KP4 * 2);
    f16* W5h = (f16*)alloc((size_t)2048 * KP5 * 2);
    unsigned short* L1h = (unsigned short*)alloc((size_t)896 * KPL1 * 2);
    unsigned short* L1l = (unsigned short*)alloc((size_t)896 * KPL1 * 2);
    unsigned short* Fh  = (unsigned short*)alloc((size_t)BATCH * KPL1 * 2);
    unsigned short* Fl  = (unsigned short*)alloc((size_t)BATCH * KPL1 * 2);
    f16* A4[2]; f16* A5[2];
    for (int p = 0; p < 2; ++p) {
        A4[p] = (f16*)alloc((size_t)BATCH * KP4 * 2);
        A5[p] = (f16*)alloc((size_t)BATCH * KP5 * 2);
    }
    size_t us_end = off;

    // --- zero-init fp32 region ---
    size_t fz_begin = (off + 255) & ~(size_t)255;
    float* c2   = (float*)alloc((size_t)BATCH * MID_O * 4);
    float* c3   = (float*)alloc((size_t)BATCH * OUT_DIM * 4);
    float* hb1  = (float*)alloc((size_t)BATCH * MID_I * 4);
    float* cb1  = (float*)alloc((size_t)BATCH * MID_I * 4);
    float* hb21 = (float*)alloc((size_t)BATCH * LATENT * 4);
    float* cb21 = (float*)alloc((size_t)BATCH * LATENT * 4);
    size_t fz_end = off;

    // --- no-init buffers ---
    float* bp4   = (float*)alloc((size_t)4 * MID_O * 4);
    float* bp5   = (float*)alloc((size_t)4 * OUT_DIM * 4);
    float* mu1   = (float*)alloc((size_t)BATCH * V_MID * 4);
    float* mu    = (float*)alloc((size_t)BATCH * V_LAT * 4);
    float* h_t   = (float*)alloc((size_t)BATCH * V_LAT * 4);
    float* c_t   = (float*)alloc((size_t)BATCH * V_LAT * 4);
    float* outb  = (float*)alloc((size_t)BATCH * LATENT * 4);
    const int CH = 20;
    float* xp1c  = (float*)alloc((size_t)CH * BATCH * 4 * MID_I * 4);
    float* h1rc  = (float*)alloc((size_t)CH * BATCH * MID_I * 4);
    float* xp21c = (float*)alloc((size_t)CH * BATCH * 4 * LATENT * 4);

    hipMemsetAsync(base + us_begin, 0, us_end - us_begin, stream);
    hipMemsetAsync(base + fz_begin, 0, fz_end - fz_begin, stream);

    // --- weight/bias packing ---
    pack_f16<<<(3200 * 50  + 255) / 256, 256, 0, stream>>>(l4_wih, 3200 * 50,  50,  KP4, 0,   800, W4h);
    pack_f16<<<(3200 * 800 + 255) / 256, 256, 0, stream>>>(l4_whh, 3200 * 800, 800, KP4, 64,  800, W4h);
    pack_f16<<<(2048 * 800 + 255) / 256, 256, 0, stream>>>(l5_wih, 2048 * 800, 800, KP5, 0,   512, W5h);
    pack_f16<<<(2048 * 512 + 255) / 256, 256, 0, stream>>>(l5_whh, 2048 * 512, 512, KP5, 832, 512, W5h);
    split_pack_lin1<<<(V_MID * LATENT * SEQ + 255) / 256, 256, 0, stream>>>(lin1_w, L1h, L1l);
    bias_pack<<<(4 * MID_O   + 255) / 256, 256, 0, stream>>>(l4_bih, l4_bhh, MID_O,   bp4);
    bias_pack<<<(4 * OUT_DIM + 255) / 256, 256, 0, stream>>>(l5_bih, l5_bhh, OUT_DIM, bp5);

    // ---------------- encoder ----------------
    for (int c0 = 0; c0 < SEQ; c0 += CH) {
        {
            dim3 g((4 * MID_I + BN - 1) / BN, CH * BATCH / BM);
            gemm2k<false, false><<<g, 256, 0, stream>>>(
                x + (size_t)c0 * BATCH * IN_DIM, IN_DIM, nullptr, 0,
                fc1_wih, nullptr, fc1_bih, fc1_bhh, xp1c, CH * BATCH, 4 * MID_I);
        }
        enc_rec1<<<BATCH / 4, 256, 0, stream>>>(xp1c, CH, fc1_whh, hb1, cb1, h1rc);
        {
            dim3 g((4 * LATENT + BN - 1) / BN, CH * BATCH / BM);
            gemm2k<false, false><<<g, 256, 0, stream>>>(
                h1rc, MID_I, nullptr, 0,
                fc21_wih, nullptr, fc21_bih, fc21_bhh, xp21c, CH * BATCH, 4 * LATENT);
        }
        enc_rec21<<<BATCH / 4, 256, 0, stream>>>(xp21c, CH, c0, fc21_whh, hb21, cb21, Fh, Fl);
    }

    // lin1 (bf16 3-term MFMA) + lin2 (fp32)
    {
        dim3 g(7, 16);
        gemm_lin1<<<g, 256, 0, stream>>>(Fh, Fl, L1h, L1l, KPL1, V_MID, lin1_b, mu1);
    }
    {
        dim3 g((V_LAT + BN - 1) / BN, BATCH / BM);
        gemm2k<false, true><<<g, 256, 0, stream>>>(mu1, V_MID, nullptr, 0,
            lin2_w, nullptr, lin2_b, nullptr, mu, BATCH, V_LAT);
    }

    // ---------------- decoder init ----------------
    hipMemcpyAsync(h_t, mu, (size_t)BATCH * V_LAT * 4, hipMemcpyDeviceToDevice, stream);
    {
        dim3 g(1, BATCH / BM);
        gemm2k<false, false><<<g, 256, 0, stream>>>(mu, V_LAT, nullptr, 0,
            idlin_w, nullptr, idlin_b, nullptr, c_t, BATCH, V_LAT);
        gemm2k<false, false><<<g, 256, 0, stream>>>(mu, V_LAT, nullptr, 0,
            down1_w, nullptr, down1_b, nullptr, outb, BATCH, LATENT);
    }

    // ---------------- decoder scan ----------------
    for (int t = 0; t < SEQ; ++t) {
        const int p = t & 1;
        if (t == 0) {
            dec_l3<<<BATCH / 4, 256, 0, stream>>>(outb, l3_wih, l3_whh, l3_bih, l3_bhh,
                                                  h_t, c_t, A4[0]);
        } else {
            dec_step3<<<BATCH / 8, 512, 0, stream>>>(
                out + (size_t)(t - 1) * BATCH * OUT_DIM,
                down2_w, down2_b, l3_wih, l3_whh, l3_bih, l3_bhh,
                h_t, c_t, A4[p]);
        }
        {
            // N=3200 -> 25 col-tiles x 16 row-tiles = 400 blocks
            gemm_dec<1><<<dim3(400), 256, 0, stream>>>(
                A4[p], W4h, KP4, KP4 / 32, MID_O, 25, bp4, c2,
                A4[p ^ 1], KP4, 64,
                A5[p], KP5, 0,
                nullptr);
        }
        {
            // N=2048 -> 16 col-tiles x 16 row-tiles = 256 blocks
            gemm_dec<2><<<dim3(256), 256, 0, stream>>>(
                A5[p], W5h, KP5, KP5 / 32, OUT_DIM, 16, bp5, c3,
                A5[p ^ 1], KP5, 832,
                nullptr, 0, 0,
                out + (size_t)t * BATCH * OUT_DIM);
        }
    }

    hipMemcpyAsync(out + (size_t)SEQ * BATCH * OUT_DIM, mu,
                   (size_t)BATCH * V_LAT * 4, hipMemcpyDeviceToDevice, stream);
}

// Round 8
// 7555.441 us; speedup vs baseline: 9.6283x; 1.0153x over previous
//
#include <hip/hip_runtime.h>
#include <cstdint>
#include <cstddef>

#define SEQ     100
#define BATCH   2048
#define IN_DIM  64
#define MID_I   60
#define LATENT  20
#define V_MID   800
#define V_LAT   50
#define MID_O   800
#define OUT_DIM 512

#define KP4  896    // [h_t pad 64 | h2 800 | pad to 896]
#define KP5  1344   // [h2 800 pad 832 | h3 512]
#define KPL1 2048   // latent*seq 2000 padded

using f32x4  = __attribute__((ext_vector_type(4))) float;
using u16x8  = __attribute__((ext_vector_type(8))) unsigned short;
using bf16x8 = __attribute__((ext_vector_type(8))) __bf16;
typedef _Float16 f16;
typedef _Float16 f16x8 __attribute__((ext_vector_type(8)));

__device__ __forceinline__ unsigned short f2bf(float x){
    unsigned u = __builtin_bit_cast(unsigned, x);
    u += 0x7FFFu + ((u >> 16) & 1u);
    return (unsigned short)(u >> 16);
}
__device__ __forceinline__ float bf2f(unsigned short b){
    unsigned u = ((unsigned)b) << 16; return __builtin_bit_cast(float, u);
}
__device__ __forceinline__ float sigm(float x){ return 1.f/(1.f+__expf(-x)); }
__device__ __forceinline__ float tanh_f(float x){ return 1.f - 2.f/(__expf(2.f*x)+1.f); }

typedef const __attribute__((address_space(1))) unsigned int* gas_ptr;
typedef __attribute__((address_space(3))) unsigned int* las_ptr;
__device__ __forceinline__ void gld16(const void* g, char* l) {
    __builtin_amdgcn_global_load_lds((gas_ptr)g, (las_ptr)l, 16, 0, 0);
}

// ---------------------------------------------------------------------------
// fp32 tiled GEMM (lin2, decoder init only)
// ---------------------------------------------------------------------------
constexpr int BM = 64, BN = 64, BK = 16;
template<bool RELU_A1, bool RELU_OUT>
__global__ __launch_bounds__(256)
void gemm2k(const float* __restrict__ A1, int K1,
            const float* __restrict__ A2, int K2,
            const float* __restrict__ W1, const float* __restrict__ W2,
            const float* __restrict__ b1, const float* __restrict__ b2,
            float* __restrict__ C, int M, int N)
{
    __shared__ float As[BK][BM + 1];
    __shared__ float Bs[BK][BN + 1];
    const int tx = threadIdx.x & 15;
    const int ty = threadIdx.x >> 4;
    const int n0 = blockIdx.x * BN;
    const int m0 = blockIdx.y * BM;

    float acc[4][4] = {};

    for (int src = 0; src < 2; ++src) {
        const float* A = src ? A2 : A1;
        const float* W = src ? W2 : W1;
        const int    K = src ? K2 : K1;
        if (A == nullptr || K == 0) continue;
        for (int k0 = 0; k0 < K; k0 += BK) {
            #pragma unroll
            for (int i = 0; i < 4; ++i) {
                int idx = threadIdx.x + i * 256;
                int k = idx & 15, m = idx >> 4;
                int gm = m0 + m, gk = k0 + k;
                float v = 0.f;
                if (gm < M && gk < K) v = A[(size_t)gm * K + gk];
                if (RELU_A1 && src == 0) v = fmaxf(v, 0.f);
                As[k][m] = v;
            }
            #pragma unroll
            for (int i = 0; i < 4; ++i) {
                int idx = threadIdx.x + i * 256;
                int k = idx & 15, n = idx >> 4;
                int gn = n0 + n, gk = k0 + k;
                float v = 0.f;
                if (gn < N && gk < K) v = W[(size_t)gn * K + gk];
                Bs[k][n] = v;
            }
            __syncthreads();
            #pragma unroll
            for (int kk = 0; kk < BK; ++kk) {
                float a[4], b[4];
                #pragma unroll
                for (int i = 0; i < 4; ++i) a[i] = As[kk][ty + i * 16];
                #pragma unroll
                for (int j = 0; j < 4; ++j) b[j] = Bs[kk][tx + j * 16];
                #pragma unroll
                for (int i = 0; i < 4; ++i)
                    #pragma unroll
                    for (int j = 0; j < 4; ++j)
                        acc[i][j] += a[i] * b[j];
            }
            __syncthreads();
        }
    }

    #pragma unroll
    for (int i = 0; i < 4; ++i) {
        int gm = m0 + ty + i * 16;
        if (gm >= M) continue;
        #pragma unroll
        for (int j = 0; j < 4; ++j) {
            int gn = n0 + tx + j * 16;
            if (gn >= N) continue;
            float v = acc[i][j];
            if (b1) v += b1[gn];
            if (b2) v += b2[gn];
            if (RELU_OUT) v = fmaxf(v, 0.f);
            C[(size_t)gm * N + gn] = v;
        }
    }
}

// ---------------------------------------------------------------------------
// split-bf16 3-term MFMA GEMM, 128x128 tile, plain fp32 store (+opt relu).
// Used for lin1 and the encoder projections.
// ---------------------------------------------------------------------------
template<bool RELU>
__global__ __launch_bounds__(256, 2)
void gemm_mfma0(const unsigned short* __restrict__ Ah, const unsigned short* __restrict__ Al,
                const unsigned short* __restrict__ Bh, const unsigned short* __restrict__ Bl,
                int Kp, int Nstore, const float* __restrict__ bi, float* __restrict__ Cout)
{
    __shared__ __align__(16) char smem[32768];
    const int tid  = threadIdx.x;
    const int lane = tid & 63;
    const int wid  = tid >> 6;
    const int m0   = blockIdx.y * 128;
    const int n0   = blockIdx.x * 128;
    const int wr   = (wid >> 1) << 6;
    const int wc   = (wid & 1) << 6;
    const int fr   = lane & 15;
    const int fg   = lane >> 4;
    const int slotR = ((fg ^ (fr & 3)) << 4);

    const int r0 = 32 * wid + (lane >> 2);
    const int sl = (((lane & 3) ^ ((lane >> 2) & 3)) << 3);
    const unsigned short* gA0h = Ah + (size_t)(m0 + r0)      * Kp + sl;
    const unsigned short* gA1h = Ah + (size_t)(m0 + r0 + 16) * Kp + sl;
    const unsigned short* gA0l = Al + (size_t)(m0 + r0)      * Kp + sl;
    const unsigned short* gA1l = Al + (size_t)(m0 + r0 + 16) * Kp + sl;
    const unsigned short* gB0h = Bh + (size_t)(n0 + r0)      * Kp + sl;
    const unsigned short* gB1h = Bh + (size_t)(n0 + r0 + 16) * Kp + sl;
    const unsigned short* gB0l = Bl + (size_t)(n0 + r0)      * Kp + sl;
    const unsigned short* gB1l = Bl + (size_t)(n0 + r0 + 16) * Kp + sl;
    char* lA0h = smem +     0 + (2 * wid    ) * 1024;
    char* lA1h = smem +     0 + (2 * wid + 1) * 1024;
    char* lA0l = smem +  8192 + (2 * wid    ) * 1024;
    char* lA1l = smem +  8192 + (2 * wid + 1) * 1024;
    char* lB0h = smem + 16384 + (2 * wid    ) * 1024;
    char* lB1h = smem + 16384 + (2 * wid + 1) * 1024;
    char* lB0l = smem + 24576 + (2 * wid    ) * 1024;
    char* lB1l = smem + 24576 + (2 * wid + 1) * 1024;

    f32x4 acc[4][4];
    #pragma unroll
    for (int i = 0; i < 4; ++i)
        #pragma unroll
        for (int j = 0; j < 4; ++j) acc[i][j] = (f32x4){0.f, 0.f, 0.f, 0.f};

    for (int k0 = 0; k0 < Kp; k0 += 32) {
        __syncthreads();
        gld16(gA0h + k0, lA0h); gld16(gA1h + k0, lA1h);
        gld16(gA0l + k0, lA0l); gld16(gA1l + k0, lA1l);
        gld16(gB0h + k0, lB0h); gld16(gB1h + k0, lB1h);
        gld16(gB0l + k0, lB0l); gld16(gB1l + k0, lB1l);
        __syncthreads();

        bf16x8 ah[4], al[4];
        #pragma unroll
        for (int i = 0; i < 4; ++i) {
            int ro = (wr + i * 16 + fr) * 64 + slotR;
            ah[i] = *(const bf16x8*)(smem +        ro);
            al[i] = *(const bf16x8*)(smem + 8192 + ro);
        }
        #pragma unroll
        for (int j = 0; j < 4; ++j) {
            int ro = (wc + j * 16 + fr) * 64 + slotR;
            bf16x8 fbh = *(const bf16x8*)(smem + 16384 + ro);
            bf16x8 fbl = *(const bf16x8*)(smem + 24576 + ro);
            #pragma unroll
            for (int i = 0; i < 4; ++i) {
                acc[i][j] = __builtin_amdgcn_mfma_f32_16x16x32_bf16(ah[i], fbh, acc[i][j], 0, 0, 0);
                acc[i][j] = __builtin_amdgcn_mfma_f32_16x16x32_bf16(ah[i], fbl, acc[i][j], 0, 0, 0);
                acc[i][j] = __builtin_amdgcn_mfma_f32_16x16x32_bf16(al[i], fbh, acc[i][j], 0, 0, 0);
            }
        }
    }

    #pragma unroll
    for (int j = 0; j < 4; ++j) {
        int gc = n0 + wc + j * 16 + fr;
        if (gc >= Nstore) continue;
        float badd = bi[gc];
        #pragma unroll
        for (int i = 0; i < 4; ++i)
            #pragma unroll
            for (int r = 0; r < 4; ++r) {
                int gr = m0 + wr + i * 16 + fg * 4 + r;
                float v = acc[i][j][r] + badd;
                if (RELU) v = fmaxf(v, 0.f);
                Cout[(size_t)gr * Nstore + gc] = v;
            }
    }
}

// ---------------------------------------------------------------------------
// l4 GEMM: fp16 MFMA, 256x128 tile, 8 waves, 3-buffer counted-vmcnt pipeline,
// LDS-transposed coalesced LSTM epilogue, XCD-chunked swizzle.
// Grid = NBX*8 blocks. Writes h -> wr1[st1,off1] and wr2[st2,off2].
// ---------------------------------------------------------------------------
__global__ __launch_bounds__(512, 2)
void gemm_dec4(const f16* __restrict__ A, const f16* __restrict__ W,
               int Kp, int NK, int H, int NBX,
               const float* __restrict__ bp, float* __restrict__ cstate,
               f16* __restrict__ wr1, int st1, int off1,
               f16* __restrict__ wr2, int st2, int off2)
{
    __shared__ __align__(16) char smem[73728];   // 3 x (A 16K + W 8K)
    const int qq      = NBX;                     // blocks per XCD (200/8=25)
    const int logical = (blockIdx.x & 7) * qq + (blockIdx.x >> 3);
    const int bx = logical >> 3;
    const int by = logical & 7;
    const int m0 = by * 256;
    const int n0 = bx * 128;

    const int tid  = threadIdx.x;
    const int lane = tid & 63;
    const int wid  = tid >> 6;         // 0..7
    const int wm   = wid >> 1;         // 0..3
    const int wn   = wid & 1;          // 0..1
    const int fr   = lane & 15;
    const int fg   = lane >> 4;
    const int swz  = (fg ^ (fr & 3) ^ ((fr >> 2) & 1)) * 16;

    const int rbase = 32 * wid;        // A rows per wave (0..255)
    const int rbW   = 16 * wid;        // W rows per wave (0..127)
    const int lrow  = lane >> 2;
    const int chnk  = (lane & 3) ^ ((lane >> 2) & 3) ^ ((lane >> 4) & 1);
    const f16* sA0 = A + (size_t)(m0 + rbase + lrow)      * Kp + chnk * 8;
    const f16* sA1 = A + (size_t)(m0 + rbase + 16 + lrow) * Kp + chnk * 8;
    const f16* sW  = W + (size_t)(n0 + rbW + lrow)        * Kp + chnk * 8;

    f32x4 acc[4][4];
    #pragma unroll
    for (int i = 0; i < 4; ++i)
        #pragma unroll
        for (int j = 0; j < 4; ++j) acc[i][j] = (f32x4){0.f, 0.f, 0.f, 0.f};

    auto stage = [&](int t, int buf) {
        const int kb = t * 32;
        char* bb = smem + buf * 24576;
        gld16(sA0 + kb, bb + rbase * 64);
        gld16(sA1 + kb, bb + (rbase + 16) * 64);
        gld16(sW  + kb, bb + 16384 + rbW * 64);
    };

    stage(0, 0);
    stage(1, 1);

    int buf = 0;
    for (int t = 0; t < NK; ++t) {
        if (t + 1 < NK) asm volatile("s_waitcnt vmcnt(3)" ::: "memory");
        else            asm volatile("s_waitcnt vmcnt(0)" ::: "memory");
        __builtin_amdgcn_s_barrier();
        if (t + 2 < NK) stage(t + 2, (buf + 2) % 3);
        const char* bb = smem + buf * 24576;
        f16x8 af[4];
        #pragma unroll
        for (int i = 0; i < 4; ++i)
            af[i] = *(const f16x8*)(bb + (64 * wm + 16 * i + fr) * 64 + swz);
        #pragma unroll
        for (int j = 0; j < 4; ++j) {
            f16x8 vw = *(const f16x8*)(bb + 16384 + (64 * wn + 16 * j + fr) * 64 + swz);
            #pragma unroll
            for (int i = 0; i < 4; ++i)
                acc[i][j] = __builtin_amdgcn_mfma_f32_16x16x32_f16(af[i], vw, acc[i][j], 0, 0, 0);
        }
        buf = (buf + 1) % 3;
    }

    // epilogue: 4 quarter-passes of LDS transpose -> coalesced LSTM pointwise
    float* gt = (float*)smem;              // [64][132]
    const int u32 = tid & 31;
    const int rr  = tid >> 5;              // 0..15
    const int unit = (n0 >> 2) + u32;
    const f32x4 bv = ((const f32x4*)bp)[unit];

    #pragma unroll
    for (int qp = 0; qp < 4; ++qp) {
        __syncthreads();
        if (wm == qp) {
            #pragma unroll
            for (int i = 0; i < 4; ++i)
                #pragma unroll
                for (int j = 0; j < 4; ++j)
                    #pragma unroll
                    for (int r = 0; r < 4; ++r)
                        gt[(16*i + 4*fg + r) * 132 + 64*wn + 16*j + fr] = acc[i][j][r];
        }
        __syncthreads();
        #pragma unroll
        for (int kk = 0; kk < 4; ++kk) {
            const int lr  = 16 * kk + rr;
            const int row = m0 + 64 * qp + lr;
            f32x4 g = *(const f32x4*)(gt + lr * 132 + u32 * 4);
            float gi = g[0] + bv[0], gf = g[1] + bv[1];
            float gg = g[2] + bv[2], go = g[3] + bv[3];
            size_t ci = (size_t)row * H + unit;
            float cn = sigm(gf) * cstate[ci] + sigm(gi) * tanh_f(gg);
            float hn = sigm(go) * tanh_f(cn);
            cstate[ci] = cn;
            f16 hh = (f16)hn;
            wr1[(size_t)row * st1 + off1 + unit] = hh;
            wr2[(size_t)row * st2 + off2 + unit] = hh;
        }
    }
}

// ---------------------------------------------------------------------------
// l5 GEMM: fp16 MFMA, 128x128 tile, 4 waves, 3-buffer counted-vmcnt pipeline,
// LDS-transposed coalesced LSTM epilogue, XCD-chunked swizzle.
// ---------------------------------------------------------------------------
__global__ __launch_bounds__(256, 3)
void gemm_dec5(const f16* __restrict__ A, const f16* __restrict__ W,
               int Kp, int NK, int H, int NBX,
               const float* __restrict__ bp, float* __restrict__ cstate,
               f16* __restrict__ wr1, int st1, int off1,
               float* __restrict__ out_t)
{
    __shared__ __align__(16) char smem[49152];
    const int qq      = NBX * 2;
    const int logical = (blockIdx.x & 7) * qq + (blockIdx.x >> 3);
    const int bx = logical >> 4;
    const int by = logical & 15;
    const int m0 = by * 128;
    const int n0 = bx * 128;

    const int tid  = threadIdx.x;
    const int lane = tid & 63;
    const int wid  = tid >> 6;
    const int wm   = wid >> 1;
    const int wn   = wid & 1;
    const int fr   = lane & 15;
    const int fg   = lane >> 4;
    const int swz  = (fg ^ (fr & 3) ^ ((fr >> 2) & 1)) * 16;

    const int rbase = 32 * wid;
    const int lrow  = lane >> 2;
    const int chnk  = (lane & 3) ^ ((lane >> 2) & 3) ^ ((lane >> 4) & 1);
    const f16* sA0 = A + (size_t)(m0 + rbase + lrow)      * Kp + chnk * 8;
    const f16* sA1 = A + (size_t)(m0 + rbase + 16 + lrow) * Kp + chnk * 8;
    const f16* sW0 = W + (size_t)(n0 + rbase + lrow)      * Kp + chnk * 8;
    const f16* sW1 = W + (size_t)(n0 + rbase + 16 + lrow) * Kp + chnk * 8;

    f32x4 acc[4][4];
    #pragma unroll
    for (int i = 0; i < 4; ++i)
        #pragma unroll
        for (int j = 0; j < 4; ++j) acc[i][j] = (f32x4){0.f, 0.f, 0.f, 0.f};

    auto stage = [&](int t, int buf) {
        const int kb = t * 32;
        char* bb = smem + buf * 16384;
        gld16(sA0 + kb, bb + rbase * 64);
        gld16(sA1 + kb, bb + (rbase + 16) * 64);
        gld16(sW0 + kb, bb + 8192 + rbase * 64);
        gld16(sW1 + kb, bb + 8192 + (rbase + 16) * 64);
    };

    stage(0, 0);
    stage(1, 1);

    int buf = 0;
    for (int t = 0; t < NK; ++t) {
        if (t + 1 < NK) asm volatile("s_waitcnt vmcnt(4)" ::: "memory");
        else            asm volatile("s_waitcnt vmcnt(0)" ::: "memory");
        __builtin_amdgcn_s_barrier();
        if (t + 2 < NK) stage(t + 2, (buf + 2) % 3);
        const char* bb = smem + buf * 16384;
        f16x8 af[4];
        #pragma unroll
        for (int i = 0; i < 4; ++i)
            af[i] = *(const f16x8*)(bb + (64 * wm + 16 * i + fr) * 64 + swz);
        #pragma unroll
        for (int j = 0; j < 4; ++j) {
            f16x8 vw = *(const f16x8*)(bb + 8192 + (64 * wn + 16 * j + fr) * 64 + swz);
            #pragma unroll
            for (int i = 0; i < 4; ++i)
                acc[i][j] = __builtin_amdgcn_mfma_f32_16x16x32_f16(af[i], vw, acc[i][j], 0, 0, 0);
        }
        buf = (buf + 1) % 3;
    }

    float* gt = (float*)smem;              // [64][132]
    const int u32 = tid & 31;
    const int r8  = tid >> 5;              // 0..7
    const int unit = (n0 >> 2) + u32;
    const f32x4 bv = ((const f32x4*)bp)[unit];

    #pragma unroll
    for (int half = 0; half < 2; ++half) {
        __syncthreads();
        if (wm == half) {
            #pragma unroll
            for (int i = 0; i < 4; ++i)
                #pragma unroll
                for (int j = 0; j < 4; ++j)
                    #pragma unroll
                    for (int r = 0; r < 4; ++r)
                        gt[(16*i + 4*fg + r) * 132 + 64*wn + 16*j + fr] = acc[i][j][r];
        }
        __syncthreads();
        #pragma unroll
        for (int kk = 0; kk < 8; ++kk) {
            const int lr  = 8 * kk + r8;
            const int row = m0 + 64 * half + lr;
            f32x4 g = *(const f32x4*)(gt + lr * 132 + u32 * 4);
            float gi = g[0] + bv[0], gf = g[1] + bv[1];
            float gg = g[2] + bv[2], go = g[3] + bv[3];
            size_t ci = (size_t)row * H + unit;
            float cn = sigm(gf) * cstate[ci] + sigm(gi) * tanh_f(gg);
            float hn = sigm(go) * tanh_f(cn);
            cstate[ci] = cn;
            wr1[(size_t)row * st1 + off1 + unit] = (f16)hn;
            out_t[(size_t)row * H + unit] = hn;
        }
    }
}

// ---------------------------------------------------------------------------
// packing kernels
// ---------------------------------------------------------------------------
__global__ void split_pack_lin1(const float* __restrict__ src,
                                unsigned short* __restrict__ dh, unsigned short* __restrict__ dl)
{
    int idx = blockIdx.x * blockDim.x + threadIdx.x;
    if (idx >= V_MID * LATENT * SEQ) return;
    int n = idx / (LATENT * SEQ), c = idx - n * (LATENT * SEQ);
    int l = c / SEQ, s = c - l * SEQ;
    float x = src[idx];
    unsigned short h = f2bf(x);
    size_t d = (size_t)n * KPL1 + s * LATENT + l;
    dh[d] = h;
    dl[d] = f2bf(x - bf2f(h));
}

// generic fp32 -> bf16 hi/lo, row-major [N][K] -> [N][Kp]
__global__ void split_pack_rows(const float* __restrict__ src, int total, int K, int Kp,
                                unsigned short* __restrict__ dh, unsigned short* __restrict__ dl)
{
    int idx = blockIdx.x * blockDim.x + threadIdx.x;
    if (idx >= total) return;
    int n = idx / K, k = idx - n * K;
    float x = src[idx];
    unsigned short h = f2bf(x);
    size_t d = (size_t)n * Kp + k;
    dh[d] = h;
    dl[d] = f2bf(x - bf2f(h));
}

// fp16 weight pack, gate-interleaved rows p=(n%HU)*4+n/HU
__global__ void pack_f16(const float* __restrict__ src, int total, int K, int Kp,
                         int coff, int HU, f16* __restrict__ dh)
{
    int idx = blockIdx.x * blockDim.x + threadIdx.x;
    if (idx >= total) return;
    int n = idx / K, k = idx - n * K;
    int p = (n % HU) * 4 + n / HU;
    dh[(size_t)p * Kp + coff + k] = (f16)src[idx];
}

// flat fp32 -> fp16
__global__ void pack_flat_f16(const float* __restrict__ src, int total, f16* __restrict__ d)
{
    int idx = blockIdx.x * blockDim.x + threadIdx.x;
    if (idx < total) d[idx] = (f16)src[idx];
}

// permuted combined bias: bp[u*4+g] = bih[g*H+u] + bhh[g*H+u]
__global__ void bias_pack(const float* __restrict__ bih, const float* __restrict__ bhh,
                          int H, float* __restrict__ bp)
{
    int idx = blockIdx.x * blockDim.x + threadIdx.x;
    if (idx >= 4 * H) return;
    int g = idx / H, u = idx - g * H;
    bp[u * 4 + g] = bih[idx] + bhh[idx];
}

// plain bias sum
__global__ void bias_sum(const float* __restrict__ a, const float* __restrict__ b,
                         int n, float* __restrict__ d)
{
    int idx = blockIdx.x * blockDim.x + threadIdx.x;
    if (idx < n) d[idx] = a[idx] + b[idx];
}

// ---------------------------------------------------------------------------
// encoder recurrences
// ---------------------------------------------------------------------------
__global__ __launch_bounds__(256)
void enc_rec1(const float* __restrict__ xp, int T,
              const float* __restrict__ whh,           // [240][60]
              float* __restrict__ hbuf, float* __restrict__ cbuf,
              unsigned short* __restrict__ h1h, unsigned short* __restrict__ h1l)
{
    __shared__ float Wt[60][240];
    __shared__ float hs[4][60];
    for (int idx = threadIdx.x; idx < 240 * 60; idx += 256) {
        int n = idx / 60, k = idx % 60;
        Wt[k][n] = whh[idx];
    }
    int wid = threadIdx.x >> 6, lane = threadIdx.x & 63;
    int b = blockIdx.x * 4 + wid;
    float h = 0.f, c = 0.f;
    if (lane < 60) {
        h = hbuf[(size_t)b * 60 + lane];
        c = cbuf[(size_t)b * 60 + lane];
        hs[wid][lane] = h;
    }
    __syncthreads();
    for (int t = 0; t < T; ++t) {
        if (lane < 60) {
            const float* xr = xp + ((size_t)t * BATCH + b) * 240;
            float gi = xr[lane], gf = xr[60 + lane], gg = xr[120 + lane], go = xr[180 + lane];
            for (int k = 0; k < 60; ++k) {
                float v = hs[wid][k];
                gi += v * Wt[k][lane];
                gf += v * Wt[k][60 + lane];
                gg += v * Wt[k][120 + lane];
                go += v * Wt[k][180 + lane];
            }
            float cn = sigm(gf) * c + sigm(gi) * tanh_f(gg);
            float hn = sigm(go) * tanh_f(cn);
            c = cn; h = hn;
            float rh = fmaxf(hn, 0.f);
            unsigned short hh = f2bf(rh);
            size_t d = ((size_t)t * BATCH + b) * 64 + lane;
            h1h[d] = hh;
            h1l[d] = f2bf(rh - bf2f(hh));
        }
        __syncthreads();
        if (lane < 60) hs[wid][lane] = h;
        __syncthreads();
    }
    if (lane < 60) {
        hbuf[(size_t)b * 60 + lane] = h;
        cbuf[(size_t)b * 60 + lane] = c;
    }
}

__global__ __launch_bounds__(256)
void enc_rec21(const float* __restrict__ xp, int T, int t0,
               const float* __restrict__ whh,          // [80][20]
               float* __restrict__ hbuf, float* __restrict__ cbuf,
               unsigned short* __restrict__ fh, unsigned short* __restrict__ fl)
{
    __shared__ float Wt[20][80];
    __shared__ float hs[4][20];
    for (int idx = threadIdx.x; idx < 80 * 20; idx += 256) {
        int n = idx / 20, k = idx % 20;
        Wt[k][n] = whh[idx];
    }
    int wid = threadIdx.x >> 6, lane = threadIdx.x & 63;
    int b = blockIdx.x * 4 + wid;
    float h = 0.f, c = 0.f;
    if (lane < 20) {
        h = hbuf[(size_t)b * 20 + lane];
        c = cbuf[(size_t)b * 20 + lane];
        hs[wid][lane] = h;
    }
    __syncthreads();
    for (int t = 0; t < T; ++t) {
        if (lane < 20) {
            const float* xr = xp + ((size_t)t * BATCH + b) * 80;
            float gi = xr[lane], gf = xr[20 + lane], gg = xr[40 + lane], go = xr[60 + lane];
            for (int k = 0; k < 20; ++k) {
                float v = hs[wid][k];
                gi += v * Wt[k][lane];
                gf += v * Wt[k][20 + lane];
                gg += v * Wt[k][40 + lane];
                go += v * Wt[k][60 + lane];
            }
            float cn = sigm(gf) * c + sigm(gi) * tanh_f(gg);
            float hn = sigm(go) * tanh_f(cn);
            c = cn; h = hn;
            int col = (t0 + t) * 20 + lane;
            unsigned short hh = f2bf(hn);
            fh[(size_t)b * KPL1 + col] = hh;
            fl[(size_t)b * KPL1 + col] = f2bf(hn - bf2f(hh));
        }
        __syncthreads();
        if (lane < 20) hs[wid][lane] = h;
        __syncthreads();
    }
    if (lane < 20) {
        hbuf[(size_t)b * 20 + lane] = h;
        cbuf[(size_t)b * 20 + lane] = c;
    }
}

// ---------------------------------------------------------------------------
// decoder l3 cell for t=0
// ---------------------------------------------------------------------------
__global__ __launch_bounds__(256)
void dec_l3(const float* __restrict__ outb,
            const float* __restrict__ wih,
            const float* __restrict__ whh,
            const float* __restrict__ bih, const float* __restrict__ bhh,
            float* __restrict__ h_t, float* __restrict__ c_t,
            f16* __restrict__ a4)
{
    __shared__ float Wt[70][200];
    __shared__ float xin[4][70];
    for (int idx = threadIdx.x; idx < 200 * 20; idx += 256) {
        int n = idx / 20, k = idx % 20;
        Wt[k][n] = wih[idx];
    }
    for (int idx = threadIdx.x; idx < 200 * 50; idx += 256) {
        int n = idx / 50, k = idx % 50;
        Wt[20 + k][n] = whh[idx];
    }
    int wid = threadIdx.x >> 6, lane = threadIdx.x & 63;
    int b = blockIdx.x * 4 + wid;
    if (lane < 20) xin[wid][lane]      = outb[(size_t)b * 20 + lane];
    if (lane < 50) xin[wid][20 + lane] = h_t[(size_t)b * 50 + lane];
    __syncthreads();
    if (lane < 50) {
        float gi = bih[lane] + bhh[lane];
        float gf = bih[50 + lane] + bhh[50 + lane];
        float gg = bih[100 + lane] + bhh[100 + lane];
        float go = bih[150 + lane] + bhh[150 + lane];
        for (int k = 0; k < 70; ++k) {
            float v = xin[wid][k];
            gi += v * Wt[k][lane];
            gf += v * Wt[k][50 + lane];
            gg += v * Wt[k][100 + lane];
            go += v * Wt[k][150 + lane];
        }
        float cold = c_t[(size_t)b * 50 + lane];
        float cn = sigm(gf) * cold + sigm(gi) * tanh_f(gg);
        float hn = sigm(go) * tanh_f(cn);
        c_t[(size_t)b * 50 + lane] = cn;
        h_t[(size_t)b * 50 + lane] = hn;
        a4[(size_t)b * KP4 + lane] = (f16)hn;
    }
}

// ---------------------------------------------------------------------------
// fused down2 + l3 cell for t>=1: wave-per-row, 8 rows per block, 256 blocks
// ---------------------------------------------------------------------------
__global__ __launch_bounds__(512)
void dec_step3(const float* __restrict__ h3prev,
               const f16* __restrict__ w2p, const float* __restrict__ b2,
               const float* __restrict__ wih, const float* __restrict__ whh,
               const float* __restrict__ bih, const float* __restrict__ bhh,
               float* __restrict__ h_t, float* __restrict__ c_t,
               f16* __restrict__ a4)
{
    __shared__ f16   w2s[20][512];
    __shared__ float W3[70][200];
    __shared__ float xb[8][80];
    const int tid  = threadIdx.x;
    const int lane = tid & 63;
    const int w    = tid >> 6;
    const int row  = blockIdx.x * 8 + w;

    for (int idx = tid; idx < 20 * 512; idx += 512)
        w2s[idx >> 9][idx & 511] = w2p[idx];
    for (int idx = tid; idx < 200 * 20; idx += 512) {
        int n = idx / 20, k = idx - n * 20;
        W3[k][n] = wih[idx];
    }
    for (int idx = tid; idx < 200 * 50; idx += 512) {
        int n = idx / 50, k = idx - n * 50;
        W3[20 + k][n] = whh[idx];
    }
    if (lane < 50) xb[w][20 + lane] = h_t[(size_t)row * 50 + lane];

    float hreg[8];
    const float* hrow = h3prev + (size_t)row * 512;
    #pragma unroll
    for (int c = 0; c < 8; ++c) hreg[c] = hrow[lane + 64 * c];
    __syncthreads();

    #pragma unroll 4
    for (int n = 0; n < 20; ++n) {
        float s = 0.f;
        #pragma unroll
        for (int c = 0; c < 8; ++c) s += hreg[c] * (float)w2s[n][lane + 64 * c];
        #pragma unroll
        for (int o = 32; o; o >>= 1) s += __shfl_xor(s, o);
        if (lane == 0) xb[w][n] = s + b2[n];
    }
    __syncthreads();

    if (lane < 50) {
        const int u = lane;
        float gi = bih[u] + bhh[u];
        float gf = bih[50 + u] + bhh[50 + u];
        float gg = bih[100 + u] + bhh[100 + u];
        float go = bih[150 + u] + bhh[150 + u];
        for (int k = 0; k < 70; ++k) {
            float v = xb[w][k];
            gi += v * W3[k][u];
            gf += v * W3[k][50 + u];
            gg += v * W3[k][100 + u];
            go += v * W3[k][150 + u];
        }
        size_t ci = (size_t)row * 50 + u;
        float cn = sigm(gf) * c_t[ci] + sigm(gi) * tanh_f(gg);
        float hn = sigm(go) * tanh_f(cn);
        c_t[ci] = cn;
        h_t[ci] = hn;
        a4[(size_t)row * KP4 + u] = (f16)hn;
    }
}

// ---------------------------------------------------------------------------
extern "C" void kernel_launch(void* const* d_in, const int* in_sizes, int n_in,
                              void* d_out_v, int out_size, void* d_ws, size_t ws_size,
                              hipStream_t stream)
{
    const float* x        = (const float*)d_in[0];
    const float* fc1_wih  = (const float*)d_in[1];
    const float* fc1_whh  = (const float*)d_in[2];
    const float* fc1_bih  = (const float*)d_in[3];
    const float* fc1_bhh  = (const float*)d_in[4];
    const float* fc21_wih = (const float*)d_in[5];
    const float* fc21_whh = (const float*)d_in[6];
    const float* fc21_bih = (const float*)d_in[7];
    const float* fc21_bhh = (const float*)d_in[8];
    const float* lin1_w   = (const float*)d_in[9];
    const float* lin1_b   = (const float*)d_in[10];
    const float* lin2_w   = (const float*)d_in[11];
    const float* lin2_b   = (const float*)d_in[12];
    const float* idlin_w  = (const float*)d_in[13];
    const float* idlin_b  = (const float*)d_in[14];
    const float* down1_w  = (const float*)d_in[15];
    const float* down1_b  = (const float*)d_in[16];
    const float* down2_w  = (const float*)d_in[17];
    const float* down2_b  = (const float*)d_in[18];
    const float* l3_wih   = (const float*)d_in[19];
    const float* l3_whh   = (const float*)d_in[20];
    const float* l3_bih   = (const float*)d_in[21];
    const float* l3_bhh   = (const float*)d_in[22];
    const float* l4_wih   = (const float*)d_in[23];
    const float* l4_whh   = (const float*)d_in[24];
    const float* l4_bih   = (const float*)d_in[25];
    const float* l4_bhh   = (const float*)d_in[26];
    const float* l5_wih   = (const float*)d_in[27];
    const float* l5_whh   = (const float*)d_in[28];
    const float* l5_bih   = (const float*)d_in[29];
    const float* l5_bhh   = (const float*)d_in[30];
    float* out = (float*)d_out_v;

    char* base = (char*)d_ws;
    size_t off = 0;
    auto alloc = [&](size_t bytes) -> void* {
        off = (off + 255) & ~(size_t)255;
        void* p = base + off;
        off += bytes;
        return p;
    };

    // --- zero-init 16-bit region ---
    size_t us_begin = (off + 255) & ~(size_t)255;
    f16* W4h = (f16*)alloc((size_t)3200 * KP4 * 2);
    f16* W5h = (f16*)alloc((size_t)2048 * KP5 * 2);
    unsigned short* L1h = (unsigned short*)alloc((size_t)896 * KPL1 * 2);
    unsigned short* L1l = (unsigned short*)alloc((size_t)896 * KPL1 * 2);
    unsigned short* Fh  = (unsigned short*)alloc((size_t)BATCH * KPL1 * 2);
    unsigned short* Fl  = (unsigned short*)alloc((size_t)BATCH * KPL1 * 2);
    unsigned short* Fc1h  = (unsigned short*)alloc((size_t)256 * 64 * 2);
    unsigned short* Fc1l  = (unsigned short*)alloc((size_t)256 * 64 * 2);
    unsigned short* Fc21h = (unsigned short*)alloc((size_t)128 * 64 * 2);
    unsigned short* Fc21l = (unsigned short*)alloc((size_t)128 * 64 * 2);
    const int CH = 20;
    unsigned short* H1h = (unsigned short*)alloc((size_t)CH * BATCH * 64 * 2);
    unsigned short* H1l = (unsigned short*)alloc((size_t)CH * BATCH * 64 * 2);
    f16* A4[2]; f16* A5[2];
    for (int p = 0; p < 2; ++p) {
        A4[p] = (f16*)alloc((size_t)BATCH * KP4 * 2);
        A5[p] = (f16*)alloc((size_t)BATCH * KP5 * 2);
    }
    size_t us_end = off;

    // --- zero-init fp32 region ---
    size_t fz_begin = (off + 255) & ~(size_t)255;
    float* c2   = (float*)alloc((size_t)BATCH * MID_O * 4);
    float* c3   = (float*)alloc((size_t)BATCH * OUT_DIM * 4);
    float* hb1  = (float*)alloc((size_t)BATCH * MID_I * 4);
    float* cb1  = (float*)alloc((size_t)BATCH * MID_I * 4);
    float* hb21 = (float*)alloc((size_t)BATCH * LATENT * 4);
    float* cb21 = (float*)alloc((size_t)BATCH * LATENT * 4);
    size_t fz_end = off;

    // --- no-init buffers ---
    float* bp4   = (float*)alloc((size_t)4 * MID_O * 4);
    float* bp5   = (float*)alloc((size_t)4 * OUT_DIM * 4);
    float* bs1   = (float*)alloc((size_t)4 * MID_I * 4);
    float* bs21  = (float*)alloc((size_t)4 * LATENT * 4);
    f16*   w2p   = (f16*)alloc((size_t)LATENT * OUT_DIM * 2);
    float* mu1   = (float*)alloc((size_t)BATCH * V_MID * 4);
    float* mu    = (float*)alloc((size_t)BATCH * V_LAT * 4);
    float* h_t   = (float*)alloc((size_t)BATCH * V_LAT * 4);
    float* c_t   = (float*)alloc((size_t)BATCH * V_LAT * 4);
    float* outb  = (float*)alloc((size_t)BATCH * LATENT * 4);
    unsigned short* Xh = (unsigned short*)alloc((size_t)SEQ * BATCH * 64 * 2);
    unsigned short* Xl = (unsigned short*)alloc((size_t)SEQ * BATCH * 64 * 2);
    float* xp1c  = (float*)alloc((size_t)CH * BATCH * 4 * MID_I * 4);
    float* xp21c = (float*)alloc((size_t)CH * BATCH * 4 * LATENT * 4);

    hipMemsetAsync(base + us_begin, 0, us_end - us_begin, stream);
    hipMemsetAsync(base + fz_begin, 0, fz_end - fz_begin, stream);

    // --- weight/bias packing ---
    pack_f16<<<(3200 * 50  + 255) / 256, 256, 0, stream>>>(l4_wih, 3200 * 50,  50,  KP4, 0,   800, W4h);
    pack_f16<<<(3200 * 800 + 255) / 256, 256, 0, stream>>>(l4_whh, 3200 * 800, 800, KP4, 64,  800, W4h);
    pack_f16<<<(2048 * 800 + 255) / 256, 256, 0, stream>>>(l5_wih, 2048 * 800, 800, KP5, 0,   512, W5h);
    pack_f16<<<(2048 * 512 + 255) / 256, 256, 0, stream>>>(l5_whh, 2048 * 512, 512, KP5, 832, 512, W5h);
    split_pack_lin1<<<(V_MID * LATENT * SEQ + 255) / 256, 256, 0, stream>>>(lin1_w, L1h, L1l);
    split_pack_rows<<<(240 * 64 + 255) / 256, 256, 0, stream>>>(fc1_wih, 240 * 64, 64, 64, Fc1h, Fc1l);
    split_pack_rows<<<(80 * 60 + 255) / 256, 256, 0, stream>>>(fc21_wih, 80 * 60, 60, 64, Fc21h, Fc21l);
    split_pack_rows<<<(SEQ * BATCH * 64 + 255) / 256, 256, 0, stream>>>(x, SEQ * BATCH * 64, 64, 64, Xh, Xl);
    pack_flat_f16<<<(LATENT * OUT_DIM + 255) / 256, 256, 0, stream>>>(down2_w, LATENT * OUT_DIM, w2p);
    bias_pack<<<(4 * MID_O   + 255) / 256, 256, 0, stream>>>(l4_bih, l4_bhh, MID_O,   bp4);
    bias_pack<<<(4 * OUT_DIM + 255) / 256, 256, 0, stream>>>(l5_bih, l5_bhh, OUT_DIM, bp5);
    bias_sum<<<1, 256, 0, stream>>>(fc1_bih, fc1_bhh, 4 * MID_I, bs1);
    bias_sum<<<1, 256, 0, stream>>>(fc21_bih, fc21_bhh, 4 * LATENT, bs21);

    // ---------------- encoder ----------------
    for (int c0 = 0; c0 < SEQ; c0 += CH) {
        {
            dim3 g(2, CH * BATCH / 128);
            gemm_mfma0<false><<<g, 256, 0, stream>>>(
                Xh + (size_t)c0 * BATCH * 64, Xl + (size_t)c0 * BATCH * 64,
                Fc1h, Fc1l, 64, 4 * MID_I, bs1, xp1c);
        }
        enc_rec1<<<BATCH / 4, 256, 0, stream>>>(xp1c, CH, fc1_whh, hb1, cb1, H1h, H1l);
        {
            dim3 g(1, CH * BATCH / 128);
            gemm_mfma0<false><<<g, 256, 0, stream>>>(
                H1h, H1l, Fc21h, Fc21l, 64, 4 * LATENT, bs21, xp21c);
        }
        enc_rec21<<<BATCH / 4, 256, 0, stream>>>(xp21c, CH, c0, fc21_whh, hb21, cb21, Fh, Fl);
    }

    // lin1 (bf16 3-term MFMA) + lin2 (fp32)
    {
        dim3 g(7, 16);
        gemm_mfma0<true><<<g, 256, 0, stream>>>(Fh, Fl, L1h, L1l, KPL1, V_MID, lin1_b, mu1);
    }
    {
        dim3 g((V_LAT + BN - 1) / BN, BATCH / BM);
        gemm2k<false, true><<<g, 256, 0, stream>>>(mu1, V_MID, nullptr, 0,
            lin2_w, nullptr, lin2_b, nullptr, mu, BATCH, V_LAT);
    }

    // ---------------- decoder init ----------------
    hipMemcpyAsync(h_t, mu, (size_t)BATCH * V_LAT * 4, hipMemcpyDeviceToDevice, stream);
    {
        dim3 g(1, BATCH / BM);
        gemm2k<false, false><<<g, 256, 0, stream>>>(mu, V_LAT, nullptr, 0,
            idlin_w, nullptr, idlin_b, nullptr, c_t, BATCH, V_LAT);
        gemm2k<false, false><<<g, 256, 0, stream>>>(mu, V_LAT, nullptr, 0,
            down1_w, nullptr, down1_b, nullptr, outb, BATCH, LATENT);
    }

    // ---------------- decoder scan ----------------
    for (int t = 0; t < SEQ; ++t) {
        const int p = t & 1;
        if (t == 0) {
            dec_l3<<<BATCH / 4, 256, 0, stream>>>(outb, l3_wih, l3_whh, l3_bih, l3_bhh,
                                                  h_t, c_t, A4[0]);
        } else {
            dec_step3<<<BATCH / 8, 512, 0, stream>>>(
                out + (size_t)(t - 1) * BATCH * OUT_DIM,
                w2p, down2_b, l3_wih, l3_whh, l3_bih, l3_bhh,
                h_t, c_t, A4[p]);
        }
        {
            // l4: 25 col-tiles x 8 row-tiles (256-row) = 200 blocks
            gemm_dec4<<<dim3(200), 512, 0, stream>>>(
                A4[p], W4h, KP4, KP4 / 32, MID_O, 25, bp4, c2,
                A4[p ^ 1], KP4, 64,
                A5[p], KP5, 0);
        }
        {
            // l5: 16 col-tiles x 16 row-tiles = 256 blocks
            gemm_dec5<<<dim3(256), 256, 0, stream>>>(
                A5[p], W5h, KP5, KP5 / 32, OUT_DIM, 16, bp5, c3,
                A5[p ^ 1], KP5, 832,
                out + (size_t)t * BATCH * OUT_DIM);
        }
    }

    hipMemcpyAsync(out + (size_t)SEQ * BATCH * OUT_DIM, mu,
                   (size_t)BATCH * V_LAT * 4, hipMemcpyDeviceToDevice, stream);
}

// Round 9
// 7517.924 us; speedup vs baseline: 9.6764x; 1.0050x over previous
//
#include <hip/hip_runtime.h>
#include <cstdint>
#include <cstddef>

#define SEQ     100
#define BATCH   2048
#define IN_DIM  64
#define MID_I   60
#define LATENT  20
#define V_MID   800
#define V_LAT   50
#define MID_O   800
#define OUT_DIM 512

#define KP4  896    // [h_t pad 64 | h2 800 | pad to 896]
#define KP5  1344   // [h2 800 pad 832 | h3 512]
#define KPL1 2048   // latent*seq 2000 padded

using f32x4  = __attribute__((ext_vector_type(4))) float;
using u16x8  = __attribute__((ext_vector_type(8))) unsigned short;
using bf16x8 = __attribute__((ext_vector_type(8))) __bf16;
typedef _Float16 f16;
typedef _Float16 f16x8 __attribute__((ext_vector_type(8)));

__device__ __forceinline__ unsigned short f2bf(float x){
    unsigned u = __builtin_bit_cast(unsigned, x);
    u += 0x7FFFu + ((u >> 16) & 1u);
    return (unsigned short)(u >> 16);
}
__device__ __forceinline__ float bf2f(unsigned short b){
    unsigned u = ((unsigned)b) << 16; return __builtin_bit_cast(float, u);
}
__device__ __forceinline__ float sigm(float x){ return 1.f/(1.f+__expf(-x)); }
__device__ __forceinline__ float tanh_f(float x){ return 1.f - 2.f/(__expf(2.f*x)+1.f); }

typedef const __attribute__((address_space(1))) unsigned int* gas_ptr;
typedef __attribute__((address_space(3))) unsigned int* las_ptr;
__device__ __forceinline__ void gld16(const void* g, char* l) {
    __builtin_amdgcn_global_load_lds((gas_ptr)g, (las_ptr)l, 16, 0, 0);
}

// ---------------------------------------------------------------------------
// fp32 tiled GEMM (lin2, decoder init only)
// ---------------------------------------------------------------------------
constexpr int BM = 64, BN = 64, BK = 16;
template<bool RELU_A1, bool RELU_OUT>
__global__ __launch_bounds__(256)
void gemm2k(const float* __restrict__ A1, int K1,
            const float* __restrict__ A2, int K2,
            const float* __restrict__ W1, const float* __restrict__ W2,
            const float* __restrict__ b1, const float* __restrict__ b2,
            float* __restrict__ C, int M, int N)
{
    __shared__ float As[BK][BM + 1];
    __shared__ float Bs[BK][BN + 1];
    const int tx = threadIdx.x & 15;
    const int ty = threadIdx.x >> 4;
    const int n0 = blockIdx.x * BN;
    const int m0 = blockIdx.y * BM;

    float acc[4][4] = {};

    for (int src = 0; src < 2; ++src) {
        const float* A = src ? A2 : A1;
        const float* W = src ? W2 : W1;
        const int    K = src ? K2 : K1;
        if (A == nullptr || K == 0) continue;
        for (int k0 = 0; k0 < K; k0 += BK) {
            #pragma unroll
            for (int i = 0; i < 4; ++i) {
                int idx = threadIdx.x + i * 256;
                int k = idx & 15, m = idx >> 4;
                int gm = m0 + m, gk = k0 + k;
                float v = 0.f;
                if (gm < M && gk < K) v = A[(size_t)gm * K + gk];
                if (RELU_A1 && src == 0) v = fmaxf(v, 0.f);
                As[k][m] = v;
            }
            #pragma unroll
            for (int i = 0; i < 4; ++i) {
                int idx = threadIdx.x + i * 256;
                int k = idx & 15, n = idx >> 4;
                int gn = n0 + n, gk = k0 + k;
                float v = 0.f;
                if (gn < N && gk < K) v = W[(size_t)gn * K + gk];
                Bs[k][n] = v;
            }
            __syncthreads();
            #pragma unroll
            for (int kk = 0; kk < BK; ++kk) {
                float a[4], b[4];
                #pragma unroll
                for (int i = 0; i < 4; ++i) a[i] = As[kk][ty + i * 16];
                #pragma unroll
                for (int j = 0; j < 4; ++j) b[j] = Bs[kk][tx + j * 16];
                #pragma unroll
                for (int i = 0; i < 4; ++i)
                    #pragma unroll
                    for (int j = 0; j < 4; ++j)
                        acc[i][j] += a[i] * b[j];
            }
            __syncthreads();
        }
    }

    #pragma unroll
    for (int i = 0; i < 4; ++i) {
        int gm = m0 + ty + i * 16;
        if (gm >= M) continue;
        #pragma unroll
        for (int j = 0; j < 4; ++j) {
            int gn = n0 + tx + j * 16;
            if (gn >= N) continue;
            float v = acc[i][j];
            if (b1) v += b1[gn];
            if (b2) v += b2[gn];
            if (RELU_OUT) v = fmaxf(v, 0.f);
            C[(size_t)gm * N + gn] = v;
        }
    }
}

// ---------------------------------------------------------------------------
// split-bf16 3-term MFMA GEMM, 128x128 tile, plain fp32 store (+opt relu).
// Used for lin1 and the encoder projections.
// ---------------------------------------------------------------------------
template<bool RELU>
__global__ __launch_bounds__(256, 2)
void gemm_mfma0(const unsigned short* __restrict__ Ah, const unsigned short* __restrict__ Al,
                const unsigned short* __restrict__ Bh, const unsigned short* __restrict__ Bl,
                int Kp, int Nstore, const float* __restrict__ bi, float* __restrict__ Cout)
{
    __shared__ __align__(16) char smem[32768];
    const int tid  = threadIdx.x;
    const int lane = tid & 63;
    const int wid  = tid >> 6;
    const int m0   = blockIdx.y * 128;
    const int n0   = blockIdx.x * 128;
    const int wr   = (wid >> 1) << 6;
    const int wc   = (wid & 1) << 6;
    const int fr   = lane & 15;
    const int fg   = lane >> 4;
    const int slotR = ((fg ^ (fr & 3)) << 4);

    const int r0 = 32 * wid + (lane >> 2);
    const int sl = (((lane & 3) ^ ((lane >> 2) & 3)) << 3);
    const unsigned short* gA0h = Ah + (size_t)(m0 + r0)      * Kp + sl;
    const unsigned short* gA1h = Ah + (size_t)(m0 + r0 + 16) * Kp + sl;
    const unsigned short* gA0l = Al + (size_t)(m0 + r0)      * Kp + sl;
    const unsigned short* gA1l = Al + (size_t)(m0 + r0 + 16) * Kp + sl;
    const unsigned short* gB0h = Bh + (size_t)(n0 + r0)      * Kp + sl;
    const unsigned short* gB1h = Bh + (size_t)(n0 + r0 + 16) * Kp + sl;
    const unsigned short* gB0l = Bl + (size_t)(n0 + r0)      * Kp + sl;
    const unsigned short* gB1l = Bl + (size_t)(n0 + r0 + 16) * Kp + sl;
    char* lA0h = smem +     0 + (2 * wid    ) * 1024;
    char* lA1h = smem +     0 + (2 * wid + 1) * 1024;
    char* lA0l = smem +  8192 + (2 * wid    ) * 1024;
    char* lA1l = smem +  8192 + (2 * wid + 1) * 1024;
    char* lB0h = smem + 16384 + (2 * wid    ) * 1024;
    char* lB1h = smem + 16384 + (2 * wid + 1) * 1024;
    char* lB0l = smem + 24576 + (2 * wid    ) * 1024;
    char* lB1l = smem + 24576 + (2 * wid + 1) * 1024;

    f32x4 acc[4][4];
    #pragma unroll
    for (int i = 0; i < 4; ++i)
        #pragma unroll
        for (int j = 0; j < 4; ++j) acc[i][j] = (f32x4){0.f, 0.f, 0.f, 0.f};

    for (int k0 = 0; k0 < Kp; k0 += 32) {
        __syncthreads();
        gld16(gA0h + k0, lA0h); gld16(gA1h + k0, lA1h);
        gld16(gA0l + k0, lA0l); gld16(gA1l + k0, lA1l);
        gld16(gB0h + k0, lB0h); gld16(gB1h + k0, lB1h);
        gld16(gB0l + k0, lB0l); gld16(gB1l + k0, lB1l);
        __syncthreads();

        bf16x8 ah[4], al[4];
        #pragma unroll
        for (int i = 0; i < 4; ++i) {
            int ro = (wr + i * 16 + fr) * 64 + slotR;
            ah[i] = *(const bf16x8*)(smem +        ro);
            al[i] = *(const bf16x8*)(smem + 8192 + ro);
        }
        #pragma unroll
        for (int j = 0; j < 4; ++j) {
            int ro = (wc + j * 16 + fr) * 64 + slotR;
            bf16x8 fbh = *(const bf16x8*)(smem + 16384 + ro);
            bf16x8 fbl = *(const bf16x8*)(smem + 24576 + ro);
            #pragma unroll
            for (int i = 0; i < 4; ++i) {
                acc[i][j] = __builtin_amdgcn_mfma_f32_16x16x32_bf16(ah[i], fbh, acc[i][j], 0, 0, 0);
                acc[i][j] = __builtin_amdgcn_mfma_f32_16x16x32_bf16(ah[i], fbl, acc[i][j], 0, 0, 0);
                acc[i][j] = __builtin_amdgcn_mfma_f32_16x16x32_bf16(al[i], fbh, acc[i][j], 0, 0, 0);
            }
        }
    }

    #pragma unroll
    for (int j = 0; j < 4; ++j) {
        int gc = n0 + wc + j * 16 + fr;
        if (gc >= Nstore) continue;
        float badd = bi[gc];
        #pragma unroll
        for (int i = 0; i < 4; ++i)
            #pragma unroll
            for (int r = 0; r < 4; ++r) {
                int gr = m0 + wr + i * 16 + fg * 4 + r;
                float v = acc[i][j][r] + badd;
                if (RELU) v = fmaxf(v, 0.f);
                Cout[(size_t)gr * Nstore + gc] = v;
            }
    }
}

// ---------------------------------------------------------------------------
// decoder GEMM: fp16 MFMA, 128x128 tile, 4 waves, 3-buffer counted-vmcnt
// pipeline, LDS-transposed coalesced LSTM epilogue.
// XCD chunking over ROWS: xcd owns NBYX row-tiles (A stays L2-resident),
// weights stream through once per XCD.
// Grid = NBX*NBYX*8 blocks. MODE 1 = l4, MODE 2 = l5.
// ---------------------------------------------------------------------------
template<int MODE>
__global__ __launch_bounds__(256, 3)
void gemm_dec(const f16* __restrict__ A, const f16* __restrict__ W,
              int Kp, int NK, int H, int NBYX,
              const float* __restrict__ bp,     // permuted combined bias [H*4]
              float* __restrict__ cstate,
              f16* __restrict__ wr1, int st1, int off1,
              f16* __restrict__ wr2, int st2, int off2,
              float* __restrict__ out_t)
{
    __shared__ __align__(16) char smem[49152];   // 3 buffers x (A 8K + W 8K)
    const int xcd = blockIdx.x & 7;
    const int ii  = blockIdx.x >> 3;
    const int by  = xcd * NBYX + (ii % NBYX);    // row-tile: L2-resident per XCD
    const int bx  = ii / NBYX;                   // col-tile: streamed
    const int m0 = by * 128;
    const int n0 = bx * 128;

    const int tid  = threadIdx.x;
    const int lane = tid & 63;
    const int wid  = tid >> 6;         // 0..3
    const int wm   = wid >> 1;         // 0..1
    const int wn   = wid & 1;          // 0..1
    const int fr   = lane & 15;
    const int fg   = lane >> 4;
    const int swz  = (fg ^ (fr & 3) ^ ((fr >> 2) & 1)) * 16;

    const int rbase = 32 * wid;
    const int lrow  = lane >> 2;
    const int chnk  = (lane & 3) ^ ((lane >> 2) & 3) ^ ((lane >> 4) & 1);
    const f16* sA0 = A + (size_t)(m0 + rbase + lrow)      * Kp + chnk * 8;
    const f16* sA1 = A + (size_t)(m0 + rbase + 16 + lrow) * Kp + chnk * 8;
    const f16* sW0 = W + (size_t)(n0 + rbase + lrow)      * Kp + chnk * 8;
    const f16* sW1 = W + (size_t)(n0 + rbase + 16 + lrow) * Kp + chnk * 8;

    f32x4 acc[4][4];
    #pragma unroll
    for (int i = 0; i < 4; ++i)
        #pragma unroll
        for (int j = 0; j < 4; ++j) acc[i][j] = (f32x4){0.f, 0.f, 0.f, 0.f};

    auto stage = [&](int t, int buf) {
        const int kb = t * 32;
        char* bb = smem + buf * 16384;
        gld16(sA0 + kb, bb + rbase * 64);
        gld16(sA1 + kb, bb + (rbase + 16) * 64);
        gld16(sW0 + kb, bb + 8192 + rbase * 64);
        gld16(sW1 + kb, bb + 8192 + (rbase + 16) * 64);
    };

    stage(0, 0);
    stage(1, 1);

    int buf = 0;
    for (int t = 0; t < NK; ++t) {
        if (t + 1 < NK) asm volatile("s_waitcnt vmcnt(4)" ::: "memory");
        else            asm volatile("s_waitcnt vmcnt(0)" ::: "memory");
        __builtin_amdgcn_s_barrier();
        if (t + 2 < NK) stage(t + 2, (buf + 2) % 3);
        const char* bb = smem + buf * 16384;
        f16x8 af[4];
        #pragma unroll
        for (int i = 0; i < 4; ++i)
            af[i] = *(const f16x8*)(bb + (64 * wm + 16 * i + fr) * 64 + swz);
        #pragma unroll
        for (int j = 0; j < 4; ++j) {
            f16x8 vw = *(const f16x8*)(bb + 8192 + (64 * wn + 16 * j + fr) * 64 + swz);
            #pragma unroll
            for (int i = 0; i < 4; ++i)
                acc[i][j] = __builtin_amdgcn_mfma_f32_16x16x32_f16(af[i], vw, acc[i][j], 0, 0, 0);
        }
        buf = (buf + 1) % 3;
    }

    // -------- epilogue: LDS gate transpose -> coalesced LSTM pointwise ----
    float* gt = (float*)smem;              // [64][132]
    const int u32 = tid & 31;              // unit within tile
    const int r8  = tid >> 5;              // 0..7
    const int unit = (n0 >> 2) + u32;
    const f32x4 bv = ((const f32x4*)bp)[unit];

    #pragma unroll
    for (int half = 0; half < 2; ++half) {
        __syncthreads();
        if (wm == half) {
            #pragma unroll
            for (int i = 0; i < 4; ++i)
                #pragma unroll
                for (int j = 0; j < 4; ++j)
                    #pragma unroll
                    for (int r = 0; r < 4; ++r)
                        gt[(16*i + 4*fg + r) * 132 + 64*wn + 16*j + fr] = acc[i][j][r];
        }
        __syncthreads();
        #pragma unroll
        for (int kk = 0; kk < 8; ++kk) {
            const int lr  = 8 * kk + r8;
            const int row = m0 + 64 * half + lr;
            f32x4 g = *(const f32x4*)(gt + lr * 132 + u32 * 4);
            float gi = g[0] + bv[0], gf = g[1] + bv[1];
            float gg = g[2] + bv[2], go = g[3] + bv[3];
            size_t ci = (size_t)row * H + unit;
            float cn = sigm(gf) * cstate[ci] + sigm(gi) * tanh_f(gg);
            float hn = sigm(go) * tanh_f(cn);
            cstate[ci] = cn;
            f16 hh = (f16)hn;
            wr1[(size_t)row * st1 + off1 + unit] = hh;
            if (MODE == 1) wr2[(size_t)row * st2 + off2 + unit] = hh;
            if (MODE == 2) out_t[(size_t)row * H + unit] = hn;
        }
    }
}

// ---------------------------------------------------------------------------
// packing kernels
// ---------------------------------------------------------------------------
__global__ void split_pack_lin1(const float* __restrict__ src,
                                unsigned short* __restrict__ dh, unsigned short* __restrict__ dl)
{
    int idx = blockIdx.x * blockDim.x + threadIdx.x;
    if (idx >= V_MID * LATENT * SEQ) return;
    int n = idx / (LATENT * SEQ), c = idx - n * (LATENT * SEQ);
    int l = c / SEQ, s = c - l * SEQ;
    float x = src[idx];
    unsigned short h = f2bf(x);
    size_t d = (size_t)n * KPL1 + s * LATENT + l;
    dh[d] = h;
    dl[d] = f2bf(x - bf2f(h));
}

// generic fp32 -> bf16 hi/lo, row-major [N][K] -> [N][Kp]
__global__ void split_pack_rows(const float* __restrict__ src, int total, int K, int Kp,
                                unsigned short* __restrict__ dh, unsigned short* __restrict__ dl)
{
    int idx = blockIdx.x * blockDim.x + threadIdx.x;
    if (idx >= total) return;
    int n = idx / K, k = idx - n * K;
    float x = src[idx];
    unsigned short h = f2bf(x);
    size_t d = (size_t)n * Kp + k;
    dh[d] = h;
    dl[d] = f2bf(x - bf2f(h));
}

// fp16 weight pack, gate-interleaved rows p=(n%HU)*4+n/HU
__global__ void pack_f16(const float* __restrict__ src, int total, int K, int Kp,
                         int coff, int HU, f16* __restrict__ dh)
{
    int idx = blockIdx.x * blockDim.x + threadIdx.x;
    if (idx >= total) return;
    int n = idx / K, k = idx - n * K;
    int p = (n % HU) * 4 + n / HU;
    dh[(size_t)p * Kp + coff + k] = (f16)src[idx];
}

// flat fp32 -> fp16
__global__ void pack_flat_f16(const float* __restrict__ src, int total, f16* __restrict__ d)
{
    int idx = blockIdx.x * blockDim.x + threadIdx.x;
    if (idx < total) d[idx] = (f16)src[idx];
}

// permuted combined bias: bp[u*4+g] = bih[g*H+u] + bhh[g*H+u]
__global__ void bias_pack(const float* __restrict__ bih, const float* __restrict__ bhh,
                          int H, float* __restrict__ bp)
{
    int idx = blockIdx.x * blockDim.x + threadIdx.x;
    if (idx >= 4 * H) return;
    int g = idx / H, u = idx - g * H;
    bp[u * 4 + g] = bih[idx] + bhh[idx];
}

// plain bias sum
__global__ void bias_sum(const float* __restrict__ a, const float* __restrict__ b,
                         int n, float* __restrict__ d)
{
    int idx = blockIdx.x * blockDim.x + threadIdx.x;
    if (idx < n) d[idx] = a[idx] + b[idx];
}

// ---------------------------------------------------------------------------
// encoder recurrences
// ---------------------------------------------------------------------------
__global__ __launch_bounds__(256)
void enc_rec1(const float* __restrict__ xp, int T,
              const float* __restrict__ whh,           // [240][60]
              float* __restrict__ hbuf, float* __restrict__ cbuf,
              unsigned short* __restrict__ h1h, unsigned short* __restrict__ h1l)
{
    __shared__ float Wt[60][240];
    __shared__ float hs[4][60];
    for (int idx = threadIdx.x; idx < 240 * 60; idx += 256) {
        int n = idx / 60, k = idx % 60;
        Wt[k][n] = whh[idx];
    }
    int wid = threadIdx.x >> 6, lane = threadIdx.x & 63;
    int b = blockIdx.x * 4 + wid;
    float h = 0.f, c = 0.f;
    if (lane < 60) {
        h = hbuf[(size_t)b * 60 + lane];
        c = cbuf[(size_t)b * 60 + lane];
        hs[wid][lane] = h;
    }
    __syncthreads();
    for (int t = 0; t < T; ++t) {
        if (lane < 60) {
            const float* xr = xp + ((size_t)t * BATCH + b) * 240;
            float gi = xr[lane], gf = xr[60 + lane], gg = xr[120 + lane], go = xr[180 + lane];
            for (int k = 0; k < 60; ++k) {
                float v = hs[wid][k];
                gi += v * Wt[k][lane];
                gf += v * Wt[k][60 + lane];
                gg += v * Wt[k][120 + lane];
                go += v * Wt[k][180 + lane];
            }
            float cn = sigm(gf) * c + sigm(gi) * tanh_f(gg);
            float hn = sigm(go) * tanh_f(cn);
            c = cn; h = hn;
            float rh = fmaxf(hn, 0.f);
            unsigned short hh = f2bf(rh);
            size_t d = ((size_t)t * BATCH + b) * 64 + lane;
            h1h[d] = hh;
            h1l[d] = f2bf(rh - bf2f(hh));
        }
        __syncthreads();
        if (lane < 60) hs[wid][lane] = h;
        __syncthreads();
    }
    if (lane < 60) {
        hbuf[(size_t)b * 60 + lane] = h;
        cbuf[(size_t)b * 60 + lane] = c;
    }
}

__global__ __launch_bounds__(256)
void enc_rec21(const float* __restrict__ xp, int T, int t0,
               const float* __restrict__ whh,          // [80][20]
               float* __restrict__ hbuf, float* __restrict__ cbuf,
               unsigned short* __restrict__ fh, unsigned short* __restrict__ fl)
{
    __shared__ float Wt[20][80];
    __shared__ float hs[4][20];
    for (int idx = threadIdx.x; idx < 80 * 20; idx += 256) {
        int n = idx / 20, k = idx % 20;
        Wt[k][n] = whh[idx];
    }
    int wid = threadIdx.x >> 6, lane = threadIdx.x & 63;
    int b = blockIdx.x * 4 + wid;
    float h = 0.f, c = 0.f;
    if (lane < 20) {
        h = hbuf[(size_t)b * 20 + lane];
        c = cbuf[(size_t)b * 20 + lane];
        hs[wid][lane] = h;
    }
    __syncthreads();
    for (int t = 0; t < T; ++t) {
        if (lane < 20) {
            const float* xr = xp + ((size_t)t * BATCH + b) * 80;
            float gi = xr[lane], gf = xr[20 + lane], gg = xr[40 + lane], go = xr[60 + lane];
            for (int k = 0; k < 20; ++k) {
                float v = hs[wid][k];
                gi += v * Wt[k][lane];
                gf += v * Wt[k][20 + lane];
                gg += v * Wt[k][40 + lane];
                go += v * Wt[k][60 + lane];
            }
            float cn = sigm(gf) * c + sigm(gi) * tanh_f(gg);
            float hn = sigm(go) * tanh_f(cn);
            c = cn; h = hn;
            int col = (t0 + t) * 20 + lane;
            unsigned short hh = f2bf(hn);
            fh[(size_t)b * KPL1 + col] = hh;
            fl[(size_t)b * KPL1 + col] = f2bf(hn - bf2f(hh));
        }
        __syncthreads();
        if (lane < 20) hs[wid][lane] = h;
        __syncthreads();
    }
    if (lane < 20) {
        hbuf[(size_t)b * 20 + lane] = h;
        cbuf[(size_t)b * 20 + lane] = c;
    }
}

// ---------------------------------------------------------------------------
// decoder l3 cell for t=0
// ---------------------------------------------------------------------------
__global__ __launch_bounds__(256)
void dec_l3(const float* __restrict__ outb,
            const float* __restrict__ wih,
            const float* __restrict__ whh,
            const float* __restrict__ bih, const float* __restrict__ bhh,
            float* __restrict__ h_t, float* __restrict__ c_t,
            f16* __restrict__ a4)
{
    __shared__ float Wt[70][200];
    __shared__ float xin[4][70];
    for (int idx = threadIdx.x; idx < 200 * 20; idx += 256) {
        int n = idx / 20, k = idx % 20;
        Wt[k][n] = wih[idx];
    }
    for (int idx = threadIdx.x; idx < 200 * 50; idx += 256) {
        int n = idx / 50, k = idx % 50;
        Wt[20 + k][n] = whh[idx];
    }
    int wid = threadIdx.x >> 6, lane = threadIdx.x & 63;
    int b = blockIdx.x * 4 + wid;
    if (lane < 20) xin[wid][lane]      = outb[(size_t)b * 20 + lane];
    if (lane < 50) xin[wid][20 + lane] = h_t[(size_t)b * 50 + lane];
    __syncthreads();
    if (lane < 50) {
        float gi = bih[lane] + bhh[lane];
        float gf = bih[50 + lane] + bhh[50 + lane];
        float gg = bih[100 + lane] + bhh[100 + lane];
        float go = bih[150 + lane] + bhh[150 + lane];
        for (int k = 0; k < 70; ++k) {
            float v = xin[wid][k];
            gi += v * Wt[k][lane];
            gf += v * Wt[k][50 + lane];
            gg += v * Wt[k][100 + lane];
            go += v * Wt[k][150 + lane];
        }
        float cold = c_t[(size_t)b * 50 + lane];
        float cn = sigm(gf) * cold + sigm(gi) * tanh_f(gg);
        float hn = sigm(go) * tanh_f(cn);
        c_t[(size_t)b * 50 + lane] = cn;
        h_t[(size_t)b * 50 + lane] = hn;
        a4[(size_t)b * KP4 + lane] = (f16)hn;
    }
}

// ---------------------------------------------------------------------------
// fused down2 + l3 cell for t>=1: wave-per-row, 8 rows per block, 256 blocks
// ---------------------------------------------------------------------------
__global__ __launch_bounds__(512)
void dec_step3(const float* __restrict__ h3prev,
               const f16* __restrict__ w2p, const float* __restrict__ b2,
               const float* __restrict__ wih, const float* __restrict__ whh,
               const float* __restrict__ bih, const float* __restrict__ bhh,
               float* __restrict__ h_t, float* __restrict__ c_t,
               f16* __restrict__ a4)
{
    __shared__ f16   w2s[20][512];
    __shared__ float W3[70][200];
    __shared__ float xb[8][80];
    const int tid  = threadIdx.x;
    const int lane = tid & 63;
    const int w    = tid >> 6;
    const int row  = blockIdx.x * 8 + w;

    for (int idx = tid; idx < 20 * 512; idx += 512)
        w2s[idx >> 9][idx & 511] = w2p[idx];
    for (int idx = tid; idx < 200 * 20; idx += 512) {
        int n = idx / 20, k = idx - n * 20;
        W3[k][n] = wih[idx];
    }
    for (int idx = tid; idx < 200 * 50; idx += 512) {
        int n = idx / 50, k = idx - n * 50;
        W3[20 + k][n] = whh[idx];
    }
    if (lane < 50) xb[w][20 + lane] = h_t[(size_t)row * 50 + lane];

    float hreg[8];
    const float* hrow = h3prev + (size_t)row * 512;
    #pragma unroll
    for (int c = 0; c < 8; ++c) hreg[c] = hrow[lane + 64 * c];
    __syncthreads();

    #pragma unroll 4
    for (int n = 0; n < 20; ++n) {
        float s = 0.f;
        #pragma unroll
        for (int c = 0; c < 8; ++c) s += hreg[c] * (float)w2s[n][lane + 64 * c];
        #pragma unroll
        for (int o = 32; o; o >>= 1) s += __shfl_xor(s, o);
        if (lane == 0) xb[w][n] = s + b2[n];
    }
    __syncthreads();

    if (lane < 50) {
        const int u = lane;
        float gi = bih[u] + bhh[u];
        float gf = bih[50 + u] + bhh[50 + u];
        float gg = bih[100 + u] + bhh[100 + u];
        float go = bih[150 + u] + bhh[150 + u];
        for (int k = 0; k < 70; ++k) {
            float v = xb[w][k];
            gi += v * W3[k][u];
            gf += v * W3[k][50 + u];
            gg += v * W3[k][100 + u];
            go += v * W3[k][150 + u];
        }
        size_t ci = (size_t)row * 50 + u;
        float cn = sigm(gf) * c_t[ci] + sigm(gi) * tanh_f(gg);
        float hn = sigm(go) * tanh_f(cn);
        c_t[ci] = cn;
        h_t[ci] = hn;
        a4[(size_t)row * KP4 + u] = (f16)hn;
    }
}

// ---------------------------------------------------------------------------
extern "C" void kernel_launch(void* const* d_in, const int* in_sizes, int n_in,
                              void* d_out_v, int out_size, void* d_ws, size_t ws_size,
                              hipStream_t stream)
{
    const float* x        = (const float*)d_in[0];
    const float* fc1_wih  = (const float*)d_in[1];
    const float* fc1_whh  = (const float*)d_in[2];
    const float* fc1_bih  = (const float*)d_in[3];
    const float* fc1_bhh  = (const float*)d_in[4];
    const float* fc21_wih = (const float*)d_in[5];
    const float* fc21_whh = (const float*)d_in[6];
    const float* fc21_bih = (const float*)d_in[7];
    const float* fc21_bhh = (const float*)d_in[8];
    const float* lin1_w   = (const float*)d_in[9];
    const float* lin1_b   = (const float*)d_in[10];
    const float* lin2_w   = (const float*)d_in[11];
    const float* lin2_b   = (const float*)d_in[12];
    const float* idlin_w  = (const float*)d_in[13];
    const float* idlin_b  = (const float*)d_in[14];
    const float* down1_w  = (const float*)d_in[15];
    const float* down1_b  = (const float*)d_in[16];
    const float* down2_w  = (const float*)d_in[17];
    const float* down2_b  = (const float*)d_in[18];
    const float* l3_wih   = (const float*)d_in[19];
    const float* l3_whh   = (const float*)d_in[20];
    const float* l3_bih   = (const float*)d_in[21];
    const float* l3_bhh   = (const float*)d_in[22];
    const float* l4_wih   = (const float*)d_in[23];
    const float* l4_whh   = (const float*)d_in[24];
    const float* l4_bih   = (const float*)d_in[25];
    const float* l4_bhh   = (const float*)d_in[26];
    const float* l5_wih   = (const float*)d_in[27];
    const float* l5_whh   = (const float*)d_in[28];
    const float* l5_bih   = (const float*)d_in[29];
    const float* l5_bhh   = (const float*)d_in[30];
    float* out = (float*)d_out_v;

    char* base = (char*)d_ws;
    size_t off = 0;
    auto alloc = [&](size_t bytes) -> void* {
        off = (off + 255) & ~(size_t)255;
        void* p = base + off;
        off += bytes;
        return p;
    };

    // --- zero-init 16-bit region ---
    size_t us_begin = (off + 255) & ~(size_t)255;
    f16* W4h = (f16*)alloc((size_t)3200 * KP4 * 2);
    f16* W5h = (f16*)alloc((size_t)2048 * KP5 * 2);
    unsigned short* L1h = (unsigned short*)alloc((size_t)896 * KPL1 * 2);
    unsigned short* L1l = (unsigned short*)alloc((size_t)896 * KPL1 * 2);
    unsigned short* Fh  = (unsigned short*)alloc((size_t)BATCH * KPL1 * 2);
    unsigned short* Fl  = (unsigned short*)alloc((size_t)BATCH * KPL1 * 2);
    unsigned short* Fc1h  = (unsigned short*)alloc((size_t)256 * 64 * 2);
    unsigned short* Fc1l  = (unsigned short*)alloc((size_t)256 * 64 * 2);
    unsigned short* Fc21h = (unsigned short*)alloc((size_t)128 * 64 * 2);
    unsigned short* Fc21l = (unsigned short*)alloc((size_t)128 * 64 * 2);
    const int CH = 20;
    unsigned short* H1h = (unsigned short*)alloc((size_t)CH * BATCH * 64 * 2);
    unsigned short* H1l = (unsigned short*)alloc((size_t)CH * BATCH * 64 * 2);
    f16* A4[2]; f16* A5[2];
    for (int p = 0; p < 2; ++p) {
        A4[p] = (f16*)alloc((size_t)BATCH * KP4 * 2);
        A5[p] = (f16*)alloc((size_t)BATCH * KP5 * 2);
    }
    size_t us_end = off;

    // --- zero-init fp32 region ---
    size_t fz_begin = (off + 255) & ~(size_t)255;
    float* c2   = (float*)alloc((size_t)BATCH * MID_O * 4);
    float* c3   = (float*)alloc((size_t)BATCH * OUT_DIM * 4);
    float* hb1  = (float*)alloc((size_t)BATCH * MID_I * 4);
    float* cb1  = (float*)alloc((size_t)BATCH * MID_I * 4);
    float* hb21 = (float*)alloc((size_t)BATCH * LATENT * 4);
    float* cb21 = (float*)alloc((size_t)BATCH * LATENT * 4);
    size_t fz_end = off;

    // --- no-init buffers ---
    float* bp4   = (float*)alloc((size_t)4 * MID_O * 4);
    float* bp5   = (float*)alloc((size_t)4 * OUT_DIM * 4);
    float* bs1   = (float*)alloc((size_t)4 * MID_I * 4);
    float* bs21  = (float*)alloc((size_t)4 * LATENT * 4);
    f16*   w2p   = (f16*)alloc((size_t)LATENT * OUT_DIM * 2);
    float* mu1   = (float*)alloc((size_t)BATCH * V_MID * 4);
    float* mu    = (float*)alloc((size_t)BATCH * V_LAT * 4);
    float* h_t   = (float*)alloc((size_t)BATCH * V_LAT * 4);
    float* c_t   = (float*)alloc((size_t)BATCH * V_LAT * 4);
    float* outb  = (float*)alloc((size_t)BATCH * LATENT * 4);
    unsigned short* Xh = (unsigned short*)alloc((size_t)SEQ * BATCH * 64 * 2);
    unsigned short* Xl = (unsigned short*)alloc((size_t)SEQ * BATCH * 64 * 2);
    float* xp1c  = (float*)alloc((size_t)CH * BATCH * 4 * MID_I * 4);
    float* xp21c = (float*)alloc((size_t)CH * BATCH * 4 * LATENT * 4);

    hipMemsetAsync(base + us_begin, 0, us_end - us_begin, stream);
    hipMemsetAsync(base + fz_begin, 0, fz_end - fz_begin, stream);

    // --- weight/bias packing ---
    pack_f16<<<(3200 * 50  + 255) / 256, 256, 0, stream>>>(l4_wih, 3200 * 50,  50,  KP4, 0,   800, W4h);
    pack_f16<<<(3200 * 800 + 255) / 256, 256, 0, stream>>>(l4_whh, 3200 * 800, 800, KP4, 64,  800, W4h);
    pack_f16<<<(2048 * 800 + 255) / 256, 256, 0, stream>>>(l5_wih, 2048 * 800, 800, KP5, 0,   512, W5h);
    pack_f16<<<(2048 * 512 + 255) / 256, 256, 0, stream>>>(l5_whh, 2048 * 512, 512, KP5, 832, 512, W5h);
    split_pack_lin1<<<(V_MID * LATENT * SEQ + 255) / 256, 256, 0, stream>>>(lin1_w, L1h, L1l);
    split_pack_rows<<<(240 * 64 + 255) / 256, 256, 0, stream>>>(fc1_wih, 240 * 64, 64, 64, Fc1h, Fc1l);
    split_pack_rows<<<(80 * 60 + 255) / 256, 256, 0, stream>>>(fc21_wih, 80 * 60, 60, 64, Fc21h, Fc21l);
    split_pack_rows<<<(SEQ * BATCH * 64 + 255) / 256, 256, 0, stream>>>(x, SEQ * BATCH * 64, 64, 64, Xh, Xl);
    pack_flat_f16<<<(LATENT * OUT_DIM + 255) / 256, 256, 0, stream>>>(down2_w, LATENT * OUT_DIM, w2p);
    bias_pack<<<(4 * MID_O   + 255) / 256, 256, 0, stream>>>(l4_bih, l4_bhh, MID_O,   bp4);
    bias_pack<<<(4 * OUT_DIM + 255) / 256, 256, 0, stream>>>(l5_bih, l5_bhh, OUT_DIM, bp5);
    bias_sum<<<1, 256, 0, stream>>>(fc1_bih, fc1_bhh, 4 * MID_I, bs1);
    bias_sum<<<1, 256, 0, stream>>>(fc21_bih, fc21_bhh, 4 * LATENT, bs21);

    // ---------------- encoder ----------------
    for (int c0 = 0; c0 < SEQ; c0 += CH) {
        {
            dim3 g(2, CH * BATCH / 128);
            gemm_mfma0<false><<<g, 256, 0, stream>>>(
                Xh + (size_t)c0 * BATCH * 64, Xl + (size_t)c0 * BATCH * 64,
                Fc1h, Fc1l, 64, 4 * MID_I, bs1, xp1c);
        }
        enc_rec1<<<BATCH / 4, 256, 0, stream>>>(xp1c, CH, fc1_whh, hb1, cb1, H1h, H1l);
        {
            dim3 g(1, CH * BATCH / 128);
            gemm_mfma0<false><<<g, 256, 0, stream>>>(
                H1h, H1l, Fc21h, Fc21l, 64, 4 * LATENT, bs21, xp21c);
        }
        enc_rec21<<<BATCH / 4, 256, 0, stream>>>(xp21c, CH, c0, fc21_whh, hb21, cb21, Fh, Fl);
    }

    // lin1 (bf16 3-term MFMA) + lin2 (fp32)
    {
        dim3 g(7, 16);
        gemm_mfma0<true><<<g, 256, 0, stream>>>(Fh, Fl, L1h, L1l, KPL1, V_MID, lin1_b, mu1);
    }
    {
        dim3 g((V_LAT + BN - 1) / BN, BATCH / BM);
        gemm2k<false, true><<<g, 256, 0, stream>>>(mu1, V_MID, nullptr, 0,
            lin2_w, nullptr, lin2_b, nullptr, mu, BATCH, V_LAT);
    }

    // ---------------- decoder init ----------------
    hipMemcpyAsync(h_t, mu, (size_t)BATCH * V_LAT * 4, hipMemcpyDeviceToDevice, stream);
    {
        dim3 g(1, BATCH / BM);
        gemm2k<false, false><<<g, 256, 0, stream>>>(mu, V_LAT, nullptr, 0,
            idlin_w, nullptr, idlin_b, nullptr, c_t, BATCH, V_LAT);
        gemm2k<false, false><<<g, 256, 0, stream>>>(mu, V_LAT, nullptr, 0,
            down1_w, nullptr, down1_b, nullptr, outb, BATCH, LATENT);
    }

    // ---------------- decoder scan ----------------
    for (int t = 0; t < SEQ; ++t) {
        const int p = t & 1;
        if (t == 0) {
            dec_l3<<<BATCH / 4, 256, 0, stream>>>(outb, l3_wih, l3_whh, l3_bih, l3_bhh,
                                                  h_t, c_t, A4[0]);
        } else {
            dec_step3<<<BATCH / 8, 512, 0, stream>>>(
                out + (size_t)(t - 1) * BATCH * OUT_DIM,
                w2p, down2_b, l3_wih, l3_whh, l3_bih, l3_bhh,
                h_t, c_t, A4[p]);
        }
        {
            // l4: 25 col x 16 row tiles = 400 blocks; each XCD owns 2 row-tiles
            gemm_dec<1><<<dim3(400), 256, 0, stream>>>(
                A4[p], W4h, KP4, KP4 / 32, MID_O, 2, bp4, c2,
                A4[p ^ 1], KP4, 64,
                A5[p], KP5, 0,
                nullptr);
        }
        {
            // l5: 16 col x 16 row tiles = 256 blocks; each XCD owns 2 row-tiles
            gemm_dec<2><<<dim3(256), 256, 0, stream>>>(
                A5[p], W5h, KP5, KP5 / 32, OUT_DIM, 2, bp5, c3,
                A5[p ^ 1], KP5, 832,
                nullptr, 0, 0,
                out + (size_t)t * BATCH * OUT_DIM);
        }
    }

    hipMemcpyAsync(out + (size_t)SEQ * BATCH * OUT_DIM, mu,
                   (size_t)BATCH * V_LAT * 4, hipMemcpyDeviceToDevice, stream);
}